// Round 1
// baseline (552.596 us; speedup 1.0000x reference)
//
#include <hip/hip_runtime.h>
#include <math.h>

// ---------------------------------------------------------------------------
// GATNet (3x GATConv + final linear + MLP), fp32, MI355X.
// Strategy: per-launch CSR build by dst (no cross-launch state), wave-per-node
// online-softmax aggregation (no atomics in the hot path), tiled fp32 GEMMs.
// ---------------------------------------------------------------------------

__global__ void zero_i32(int* p, int n) {
    int i = blockIdx.x * blockDim.x + threadIdx.x;
    if (i < n) p[i] = 0;
}

__global__ void count_edges(const int* __restrict__ ei, int E, int Nn,
                            int* __restrict__ counts) {
    int e = blockIdx.x * blockDim.x + threadIdx.x;
    if (e >= E + Nn) return;
    int dst = (e < E) ? ei[E + e] : (e - E);   // self-loops appended
    atomicAdd(&counts[dst], 1);
}

__global__ __launch_bounds__(1024) void scan_rowptr(const int* __restrict__ counts,
                                                    int* __restrict__ rowptr, int n) {
    __shared__ int sd[1024];
    __shared__ int s_run;
    int t = threadIdx.x;
    if (t == 0) s_run = 0;
    __syncthreads();
    for (int base = 0; base < n; base += 1024) {
        int v = (base + t < n) ? counts[base + t] : 0;
        sd[t] = v;
        __syncthreads();
        for (int off = 1; off < 1024; off <<= 1) {
            int tmp = (t >= off) ? sd[t - off] : 0;
            __syncthreads();
            sd[t] += tmp;
            __syncthreads();
        }
        int incl = sd[t];
        int run = s_run;
        if (base + t < n) rowptr[base + t] = run + incl - v;   // exclusive
        __syncthreads();
        if (t == 1023) s_run = run + sd[1023];
        __syncthreads();
    }
    if (t == 0) rowptr[n] = s_run;
}

__global__ void fill_edges(const int* __restrict__ ei, int E, int Nn,
                           const int* __restrict__ rowptr, int* __restrict__ cursor,
                           int* __restrict__ edge_src) {
    int e = blockIdx.x * blockDim.x + threadIdx.x;
    if (e >= E + Nn) return;
    int src, dst;
    if (e < E) { src = ei[e]; dst = ei[E + e]; }
    else       { src = e - E; dst = src; }
    int pos = atomicAdd(&cursor[dst], 1);
    edge_src[rowptr[dst] + pos] = src;
}

// ---------------------------------------------------------------------------
// Tiled fp32 GEMM: C[M,Nc] = A[M,K] @ B[K,Nc].  BM=BN=64, BK=16, 256 thr, 4x4.
// K % 16 == 0, Nc % 64 == 0 (true for all layers here). M guarded.
// ---------------------------------------------------------------------------
__global__ __launch_bounds__(256) void gemm_f32(const float* __restrict__ A,
                                                const float* __restrict__ B,
                                                float* __restrict__ Cm,
                                                int M, int K, int Nc) {
    __shared__ float As[16][64];   // [k][m]
    __shared__ float Bs[16][64];   // [k][n]
    int t  = threadIdx.x;
    int tx = t & 15, ty = t >> 4;
    int row0 = blockIdx.y * 64, col0 = blockIdx.x * 64;

    int a_r = t >> 2;          // 0..63 (tile row)
    int a_c = (t & 3) * 4;     // 0,4,8,12 (k offset)
    int b_r = t >> 4;          // 0..15 (k)
    int b_c = (t & 15) * 4;    // 0..60 (n)

    float acc[4][4];
#pragma unroll
    for (int i = 0; i < 4; i++)
#pragma unroll
        for (int j = 0; j < 4; j++) acc[i][j] = 0.f;

    for (int kt = 0; kt < K; kt += 16) {
        float4 av = make_float4(0.f, 0.f, 0.f, 0.f);
        int gr = row0 + a_r;
        if (gr < M) av = *(const float4*)(A + (size_t)gr * K + kt + a_c);
        As[a_c + 0][a_r] = av.x;
        As[a_c + 1][a_r] = av.y;
        As[a_c + 2][a_r] = av.z;
        As[a_c + 3][a_r] = av.w;
        float4 bv = *(const float4*)(B + (size_t)(kt + b_r) * Nc + col0 + b_c);
        *(float4*)&Bs[b_r][b_c] = bv;
        __syncthreads();
#pragma unroll
        for (int k = 0; k < 16; k++) {
            float4 a4 = *(const float4*)&As[k][ty * 4];
            float4 b4 = *(const float4*)&Bs[k][tx * 4];
            float aa[4] = {a4.x, a4.y, a4.z, a4.w};
            float bb[4] = {b4.x, b4.y, b4.z, b4.w};
#pragma unroll
            for (int i = 0; i < 4; i++)
#pragma unroll
                for (int j = 0; j < 4; j++) acc[i][j] += aa[i] * bb[j];
        }
        __syncthreads();
    }
#pragma unroll
    for (int i = 0; i < 4; i++) {
        int gr = row0 + ty * 4 + i;
        if (gr < M) {
            float4 v = make_float4(acc[i][0], acc[i][1], acc[i][2], acc[i][3]);
            *(float4*)(Cm + (size_t)gr * Nc + col0 + tx * 4) = v;
        }
    }
}

// ---------------------------------------------------------------------------
// Per-(node,head) attention scores: al = <h, a_s>, ar = <h, a_d>
// ---------------------------------------------------------------------------
template <int H, int C>
__global__ void gat_scores(const float* __restrict__ hbuf, const float* __restrict__ a_s,
                           const float* __restrict__ a_d, float* __restrict__ al,
                           float* __restrict__ ar, int n) {
    int i = blockIdx.x * blockDim.x + threadIdx.x;
    if (i >= n * H) return;
    int node = i / H, h = i % H;
    const float* hr  = hbuf + (size_t)node * (H * C) + h * C;
    const float* as_ = a_s + h * C;
    const float* ad_ = a_d + h * C;
    float sa = 0.f, sd = 0.f;
#pragma unroll 8
    for (int c = 0; c < C; c++) {
        float v = hr[c];
        sa += v * as_[c];
        sd += v * ad_[c];
    }
    al[i] = sa;
    ar[i] = sd;
}

// ---------------------------------------------------------------------------
// Wave-per-dst-node online-softmax aggregation + bias + relu.
// Lane owns CPL = H*C/64 contiguous channels, spanning at most 2 heads.
// ---------------------------------------------------------------------------
template <int H, int C>
__global__ __launch_bounds__(256) void gat_aggregate(
    const float* __restrict__ hbuf, const float* __restrict__ al,
    const float* __restrict__ ar, const int* __restrict__ rowptr,
    const int* __restrict__ edge_src, const float* __restrict__ bias,
    float* __restrict__ out, int n) {
    constexpr int HC  = H * C;
    constexpr int CPL = HC / 64;
    int gw   = (blockIdx.x * blockDim.x + threadIdx.x) >> 6;
    int lane = threadIdx.x & 63;
    if (gw >= n) return;

    int ch0   = lane * CPL;
    int hA    = ch0 / C;
    int hB    = (ch0 + CPL - 1) / C;
    int split = (hA + 1) * C - ch0;   // channels [0,split) belong to head A

    float arA = ar[gw * H + hA];
    float arB = ar[gw * H + hB];
    float mA = -INFINITY, sA = 0.f, mB = -INFINITY, sB = 0.f;
    float acc[CPL];
#pragma unroll
    for (int i = 0; i < CPL; i++) acc[i] = 0.f;

    int beg = rowptr[gw], end = rowptr[gw + 1];
    for (int j = beg; j < end; j++) {
        int s = edge_src[j];
        float eA = al[s * H + hA] + arA;
        eA = (eA > 0.f) ? eA : 0.2f * eA;
        float eB = al[s * H + hB] + arB;
        eB = (eB > 0.f) ? eB : 0.2f * eB;

        float mnA = fmaxf(mA, eA);
        float scA = __expf(mA - mnA);
        float pA  = __expf(eA - mnA);
        sA = sA * scA + pA;  mA = mnA;

        float mnB = fmaxf(mB, eB);
        float scB = __expf(mB - mnB);
        float pB  = __expf(eB - mnB);
        sB = sB * scB + pB;  mB = mnB;

        const float* hr = hbuf + (size_t)s * HC + ch0;
#pragma unroll
        for (int i = 0; i < CPL; i++) {
            float sc = (i < split) ? scA : scB;
            float pp = (i < split) ? pA : pB;
            acc[i] = acc[i] * sc + pp * hr[i];
        }
    }
#pragma unroll
    for (int i = 0; i < CPL; i++) {
        float den = (i < split) ? sA : sB;
        float v   = acc[i] / den + bias[ch0 + i];
        out[(size_t)gw * HC + ch0 + i] = fmaxf(v, 0.f);
    }
}

// ---------------------------------------------------------------------------
// out1[node] = sigmoid(concat(x1,x2,x3) . Wf + bf) — wave per node.
// ---------------------------------------------------------------------------
__global__ __launch_bounds__(256) void final_linear(
    const float* __restrict__ x1, const float* __restrict__ x2,
    const float* __restrict__ x3, const float* __restrict__ Wf,
    const float* __restrict__ bf, float* __restrict__ out1, int n) {
    int gw   = (blockIdx.x * blockDim.x + threadIdx.x) >> 6;
    int lane = threadIdx.x & 63;
    if (gw >= n) return;
    float s = 0.f;
    const float* r1 = x1 + (size_t)gw * 256;
#pragma unroll
    for (int i = 0; i < 4; i++) { int k = lane + 64 * i; s += r1[k] * Wf[k]; }
    const float* r2 = x2 + (size_t)gw * 256;
#pragma unroll
    for (int i = 0; i < 4; i++) { int k = lane + 64 * i; s += r2[k] * Wf[256 + k]; }
    const float* r3 = x3 + (size_t)gw * 768;
#pragma unroll
    for (int i = 0; i < 12; i++) { int k = lane + 64 * i; s += r3[k] * Wf[512 + k]; }
#pragma unroll
    for (int off = 32; off > 0; off >>= 1) s += __shfl_xor(s, off, 64);
    if (lane == 0) out1[gw] = 1.f / (1.f + __expf(-(s + bf[0])));
}

// ---------------------------------------------------------------------------
// MLP: xm=[x,out1] (17) -> 128 relu -> 64 relu -> 1 sigmoid.  Wave per node.
// ---------------------------------------------------------------------------
__global__ __launch_bounds__(256) void mlp_kernel(
    const float* __restrict__ x, const float* __restrict__ out1,
    const float* __restrict__ M1w, const float* __restrict__ M1b,
    const float* __restrict__ M2w, const float* __restrict__ M2b,
    const float* __restrict__ M3w, const float* __restrict__ M3b,
    float* __restrict__ out2, int n) {
    __shared__ float h1s[4][128];
    int w    = threadIdx.x >> 6;
    int lane = threadIdx.x & 63;
    int node = blockIdx.x * 4 + w;
    bool valid = node < n;
    int nd = valid ? node : 0;

    float xm[17];
#pragma unroll
    for (int k = 0; k < 16; k++) xm[k] = x[nd * 16 + k];
    xm[16] = out1[nd];

    float a0 = M1b[lane], a1 = M1b[lane + 64];
#pragma unroll
    for (int k = 0; k < 17; k++) {
        a0 += xm[k] * M1w[k * 128 + lane];
        a1 += xm[k] * M1w[k * 128 + lane + 64];
    }
    h1s[w][lane]      = fmaxf(a0, 0.f);
    h1s[w][lane + 64] = fmaxf(a1, 0.f);
    __syncthreads();

    float b0 = M2b[lane];
#pragma unroll 16
    for (int k = 0; k < 128; k++) b0 += h1s[w][k] * M2w[k * 64 + lane];
    b0 = fmaxf(b0, 0.f);

    float p = b0 * M3w[lane];
#pragma unroll
    for (int off = 32; off > 0; off >>= 1) p += __shfl_xor(p, off, 64);
    if (lane == 0 && valid) out2[node] = 1.f / (1.f + __expf(-(p + M3b[0])));
}

// ---------------------------------------------------------------------------
extern "C" void kernel_launch(void* const* d_in, const int* in_sizes, int n_in,
                              void* d_out, int out_size, void* d_ws, size_t ws_size,
                              hipStream_t stream) {
    const float* x   = (const float*)d_in[0];
    const int*   ei  = (const int*)d_in[1];
    // d_in[2] JetRawPt unused by the reference graph
    const float* W1  = (const float*)d_in[3];
    const float* a1s = (const float*)d_in[4];
    const float* a1d = (const float*)d_in[5];
    const float* b1  = (const float*)d_in[6];
    const float* W2  = (const float*)d_in[7];
    const float* a2s = (const float*)d_in[8];
    const float* a2d = (const float*)d_in[9];
    const float* b2  = (const float*)d_in[10];
    const float* W3  = (const float*)d_in[11];
    const float* a3s = (const float*)d_in[12];
    const float* a3d = (const float*)d_in[13];
    const float* b3  = (const float*)d_in[14];
    const float* Wf  = (const float*)d_in[15];
    const float* bf  = (const float*)d_in[16];
    const float* M1w = (const float*)d_in[17];
    const float* M1b = (const float*)d_in[18];
    const float* M2w = (const float*)d_in[19];
    const float* M2b = (const float*)d_in[20];
    const float* M3w = (const float*)d_in[21];
    const float* M3b = (const float*)d_in[22];

    const int N = in_sizes[0] / 16;        // 10000
    const int E = in_sizes[1] / 2;         // 320000
    const int Etot = E + N;

    // workspace carve-up (256B aligned)
    char* base = (char*)d_ws;
    size_t off = 0;
    auto carve = [&](size_t bytes) {
        char* p = base + off;
        off = (off + bytes + 255) & ~(size_t)255;
        return p;
    };
    float* hbuf   = (float*)carve((size_t)N * 768 * 4);
    float* x1     = (float*)carve((size_t)N * 256 * 4);
    float* x2     = (float*)carve((size_t)N * 256 * 4);
    float* x3     = (float*)carve((size_t)N * 768 * 4);
    float* al     = (float*)carve((size_t)N * 12 * 4);
    float* ar     = (float*)carve((size_t)N * 12 * 4);
    int*   rowptr = (int*)carve((size_t)(N + 1) * 4);
    int*   counts = (int*)carve((size_t)N * 4);
    int*   cursor = (int*)carve((size_t)N * 4);
    int*   edge_src = (int*)carve((size_t)Etot * 4);
    (void)ws_size;

    float* out1 = (float*)d_out;
    float* out2 = (float*)d_out + N;

    const int TB = 256;
    int eb = (Etot + TB - 1) / TB;
    int nb = (N + TB - 1) / TB;

    // --- CSR by dst ---
    zero_i32<<<nb, TB, 0, stream>>>(counts, N);
    zero_i32<<<nb, TB, 0, stream>>>(cursor, N);
    count_edges<<<eb, TB, 0, stream>>>(ei, E, N, counts);
    scan_rowptr<<<1, 1024, 0, stream>>>(counts, rowptr, N);
    fill_edges<<<eb, TB, 0, stream>>>(ei, E, N, rowptr, cursor, edge_src);

    int waveblocks = (N * 64 + TB - 1) / TB;   // wave per node

    // --- layer 1: 16 -> 8x32 ---
    gemm_f32<<<dim3(256 / 64, (N + 63) / 64), TB, 0, stream>>>(x, W1, hbuf, N, 16, 256);
    gat_scores<8, 32><<<(N * 8 + TB - 1) / TB, TB, 0, stream>>>(hbuf, a1s, a1d, al, ar, N);
    gat_aggregate<8, 32><<<waveblocks, TB, 0, stream>>>(hbuf, al, ar, rowptr, edge_src, b1, x1, N);

    // --- layer 2: 256 -> 8x32 ---
    gemm_f32<<<dim3(256 / 64, (N + 63) / 64), TB, 0, stream>>>(x1, W2, hbuf, N, 256, 256);
    gat_scores<8, 32><<<(N * 8 + TB - 1) / TB, TB, 0, stream>>>(hbuf, a2s, a2d, al, ar, N);
    gat_aggregate<8, 32><<<waveblocks, TB, 0, stream>>>(hbuf, al, ar, rowptr, edge_src, b2, x2, N);

    // --- layer 3: 256 -> 12x64 ---
    gemm_f32<<<dim3(768 / 64, (N + 63) / 64), TB, 0, stream>>>(x2, W3, hbuf, N, 256, 768);
    gat_scores<12, 64><<<(N * 12 + TB - 1) / TB, TB, 0, stream>>>(hbuf, a3s, a3d, al, ar, N);
    gat_aggregate<12, 64><<<waveblocks, TB, 0, stream>>>(hbuf, al, ar, rowptr, edge_src, b3, x3, N);

    // --- final linear + MLP ---
    final_linear<<<waveblocks, TB, 0, stream>>>(x1, x2, x3, Wf, bf, out1, N);
    mlp_kernel<<<(N + 3) / 4, TB, 0, stream>>>(x, out1, M1w, M1b, M2w, M2b, M3w, M3b, out2, N);
}

// Round 2
// 505.279 us; speedup vs baseline: 1.0936x; 1.0936x over previous
//
#include <hip/hip_runtime.h>
#include <math.h>

// ---------------------------------------------------------------------------
// GATNet (3x GATConv + final linear + MLP), MI355X.
// R1: aggregation restructured: precomputed normalized alpha (no exp in hot
// loop), bf16 hbuf (halves gather bytes), head-pure lane mapping, 4x-unrolled
// independent gathers. GEMMs still fp32 (next target).
// ---------------------------------------------------------------------------

typedef unsigned short bf16_t;

__device__ inline float bf2f(bf16_t u) {
    union { unsigned int i; float f; } v; v.i = ((unsigned int)u) << 16; return v.f;
}
__device__ inline bf16_t f2bf(float f) {
    union { float f; unsigned int i; } v; v.f = f;
    unsigned int r = v.i + 0x7FFF + ((v.i >> 16) & 1);   // round-nearest-even
    return (bf16_t)(r >> 16);
}

// ------------------------------ CSR build ----------------------------------

__global__ void zero_i32(int* p, int n) {
    int i = blockIdx.x * blockDim.x + threadIdx.x;
    if (i < n) p[i] = 0;
}

__global__ void count_edges(const int* __restrict__ ei, int E, int Nn,
                            int* __restrict__ counts) {
    int e = blockIdx.x * blockDim.x + threadIdx.x;
    if (e >= E + Nn) return;
    int dst = (e < E) ? ei[E + e] : (e - E);   // self-loops appended
    atomicAdd(&counts[dst], 1);
}

__global__ __launch_bounds__(1024) void scan_rowptr(const int* __restrict__ counts,
                                                    int* __restrict__ rowptr, int n) {
    __shared__ int sd[1024];
    __shared__ int s_run;
    int t = threadIdx.x;
    if (t == 0) s_run = 0;
    __syncthreads();
    for (int base = 0; base < n; base += 1024) {
        int v = (base + t < n) ? counts[base + t] : 0;
        sd[t] = v;
        __syncthreads();
        for (int off = 1; off < 1024; off <<= 1) {
            int tmp = (t >= off) ? sd[t - off] : 0;
            __syncthreads();
            sd[t] += tmp;
            __syncthreads();
        }
        int incl = sd[t];
        int run = s_run;
        if (base + t < n) rowptr[base + t] = run + incl - v;   // exclusive
        __syncthreads();
        if (t == 1023) s_run = run + sd[1023];
        __syncthreads();
    }
    if (t == 0) rowptr[n] = s_run;
}

__global__ void fill_edges(const int* __restrict__ ei, int E, int Nn,
                           const int* __restrict__ rowptr, int* __restrict__ cursor,
                           int* __restrict__ edge_src) {
    int e = blockIdx.x * blockDim.x + threadIdx.x;
    if (e >= E + Nn) return;
    int src, dst;
    if (e < E) { src = ei[e]; dst = ei[E + e]; }
    else       { src = e - E; dst = src; }
    int pos = atomicAdd(&cursor[dst], 1);
    edge_src[rowptr[dst] + pos] = src;
}

// ---------------------------------------------------------------------------
// Tiled fp32 GEMM, bf16 output: C[M,Nc] = bf16(A[M,K] @ B[K,Nc]).
// BM=BN=64, BK=16, 256 thr, 4x4/thread. K%16==0, Nc%64==0 here; M guarded.
// ---------------------------------------------------------------------------
__global__ __launch_bounds__(256) void gemm_f32_bf16(const float* __restrict__ A,
                                                     const float* __restrict__ B,
                                                     bf16_t* __restrict__ Cm,
                                                     int M, int K, int Nc) {
    __shared__ float As[16][64];   // [k][m]
    __shared__ float Bs[16][64];   // [k][n]
    int t  = threadIdx.x;
    int tx = t & 15, ty = t >> 4;
    int row0 = blockIdx.y * 64, col0 = blockIdx.x * 64;

    int a_r = t >> 2;          // 0..63 (tile row)
    int a_c = (t & 3) * 4;     // k offset
    int b_r = t >> 4;          // k
    int b_c = (t & 15) * 4;    // n

    float acc[4][4];
#pragma unroll
    for (int i = 0; i < 4; i++)
#pragma unroll
        for (int j = 0; j < 4; j++) acc[i][j] = 0.f;

    for (int kt = 0; kt < K; kt += 16) {
        float4 av = make_float4(0.f, 0.f, 0.f, 0.f);
        int gr = row0 + a_r;
        if (gr < M) av = *(const float4*)(A + (size_t)gr * K + kt + a_c);
        As[a_c + 0][a_r] = av.x;
        As[a_c + 1][a_r] = av.y;
        As[a_c + 2][a_r] = av.z;
        As[a_c + 3][a_r] = av.w;
        float4 bv = *(const float4*)(B + (size_t)(kt + b_r) * Nc + col0 + b_c);
        *(float4*)&Bs[b_r][b_c] = bv;
        __syncthreads();
#pragma unroll
        for (int k = 0; k < 16; k++) {
            float4 a4 = *(const float4*)&As[k][ty * 4];
            float4 b4 = *(const float4*)&Bs[k][tx * 4];
            float aa[4] = {a4.x, a4.y, a4.z, a4.w};
            float bb[4] = {b4.x, b4.y, b4.z, b4.w};
#pragma unroll
            for (int i = 0; i < 4; i++)
#pragma unroll
                for (int j = 0; j < 4; j++) acc[i][j] += aa[i] * bb[j];
        }
        __syncthreads();
    }
#pragma unroll
    for (int i = 0; i < 4; i++) {
        int gr = row0 + ty * 4 + i;
        if (gr < M) {
            ushort4 v;
            v.x = f2bf(acc[i][0]); v.y = f2bf(acc[i][1]);
            v.z = f2bf(acc[i][2]); v.w = f2bf(acc[i][3]);
            *(ushort4*)(Cm + (size_t)gr * Nc + col0 + tx * 4) = v;
        }
    }
}

// ---------------------------------------------------------------------------
// Per-(node,head) attention scores from bf16 h: al = <h,a_s>, ar = <h,a_d>
// ---------------------------------------------------------------------------
template <int H, int C>
__global__ void gat_scores(const bf16_t* __restrict__ hbuf, const float* __restrict__ a_s,
                           const float* __restrict__ a_d, float* __restrict__ al,
                           float* __restrict__ ar, int n) {
    int i = blockIdx.x * blockDim.x + threadIdx.x;
    if (i >= n * H) return;
    int node = i / H, h = i - node * H;
    const bf16_t* hr = hbuf + (size_t)node * (H * C) + h * C;
    const float* as_ = a_s + h * C;
    const float* ad_ = a_d + h * C;
    float sa = 0.f, sd = 0.f;
#pragma unroll
    for (int c = 0; c < C; c += 4) {
        ushort4 u = *(const ushort4*)(hr + c);
        float v0 = bf2f(u.x), v1 = bf2f(u.y), v2 = bf2f(u.z), v3 = bf2f(u.w);
        sa += v0 * as_[c] + v1 * as_[c + 1] + v2 * as_[c + 2] + v3 * as_[c + 3];
        sd += v0 * ad_[c] + v1 * ad_[c + 1] + v2 * ad_[c + 2] + v3 * ad_[c + 3];
    }
    al[i] = sa;
    ar[i] = sd;
}

// ---------------------------------------------------------------------------
// Per-(node,head) softmax stats + normalized per-edge alpha (CSR order).
// Thread per (node,head); two passes over the node's incoming edges.
// ---------------------------------------------------------------------------
template <int H>
__global__ void ms_alpha(const float* __restrict__ al, const float* __restrict__ ar,
                         const int* __restrict__ rowptr, const int* __restrict__ esrc,
                         float* __restrict__ alpha, int n) {
    int idx = blockIdx.x * blockDim.x + threadIdx.x;
    if (idx >= n * H) return;
    int node = idx / H, h = idx - node * H;
    float arv = ar[idx];
    int beg = rowptr[node], end = rowptr[node + 1];
    float m = -INFINITY, s = 0.f;
    for (int j = beg; j < end; j++) {
        float e = al[esrc[j] * H + h] + arv;
        e = (e > 0.f) ? e : 0.2f * e;
        float mn = fmaxf(m, e);
        s = s * __expf(m - mn) + __expf(e - mn);
        m = mn;
    }
    float inv = 1.f / s;
    for (int j = beg; j < end; j++) {
        float e = al[esrc[j] * H + h] + arv;
        e = (e > 0.f) ? e : 0.2f * e;
        alpha[j * H + h] = __expf(e - m) * inv;
    }
}

// ---------------------------------------------------------------------------
// Aggregation: out[node] = relu( sum_e alpha_e * h[src_e] + bias ).
// Head-pure lanes: LPH = C/4 lanes per head, 4 channels (one ushort4) each.
// Edge loop unrolled x4 with independent gathers in flight.
// ---------------------------------------------------------------------------
template <int H, int C>
__global__ __launch_bounds__(256) void gat_agg(
    const bf16_t* __restrict__ hbuf, const float* __restrict__ alpha,
    const int* __restrict__ rowptr, const int* __restrict__ esrc,
    const float* __restrict__ bias, float* __restrict__ out, int n) {
    constexpr int HC  = H * C;
    constexpr int LPH = C / 4;     // lanes per head
    constexpr int HPW = 64 / LPH;  // heads per wave
    constexpr int WPN = H / HPW;   // waves per node
    int w = (blockIdx.x * blockDim.x + threadIdx.x) >> 6;
    int node = w / WPN, sub = w - node * WPN;
    if (node >= n) return;
    int lane = threadIdx.x & 63;
    int head = sub * HPW + lane / LPH;
    int ch   = (lane % LPH) * 4;
    int off  = head * C + ch;
    const bf16_t* hb = hbuf + off;

    float acc0 = 0.f, acc1 = 0.f, acc2 = 0.f, acc3 = 0.f;
    int beg = rowptr[node], end = rowptr[node + 1];
    int j = beg;
    for (; j + 4 <= end; j += 4) {
        int s0 = esrc[j], s1 = esrc[j + 1], s2 = esrc[j + 2], s3 = esrc[j + 3];
        float a0 = alpha[(size_t)j * H + head];
        float a1 = alpha[(size_t)(j + 1) * H + head];
        float a2 = alpha[(size_t)(j + 2) * H + head];
        float a3 = alpha[(size_t)(j + 3) * H + head];
        ushort4 u0 = *(const ushort4*)(hb + (size_t)s0 * HC);
        ushort4 u1 = *(const ushort4*)(hb + (size_t)s1 * HC);
        ushort4 u2 = *(const ushort4*)(hb + (size_t)s2 * HC);
        ushort4 u3 = *(const ushort4*)(hb + (size_t)s3 * HC);
        acc0 += a0 * bf2f(u0.x) + a1 * bf2f(u1.x) + a2 * bf2f(u2.x) + a3 * bf2f(u3.x);
        acc1 += a0 * bf2f(u0.y) + a1 * bf2f(u1.y) + a2 * bf2f(u2.y) + a3 * bf2f(u3.y);
        acc2 += a0 * bf2f(u0.z) + a1 * bf2f(u1.z) + a2 * bf2f(u2.z) + a3 * bf2f(u3.z);
        acc3 += a0 * bf2f(u0.w) + a1 * bf2f(u1.w) + a2 * bf2f(u2.w) + a3 * bf2f(u3.w);
    }
    for (; j < end; j++) {
        int s0 = esrc[j];
        float a0 = alpha[(size_t)j * H + head];
        ushort4 u0 = *(const ushort4*)(hb + (size_t)s0 * HC);
        acc0 += a0 * bf2f(u0.x);
        acc1 += a0 * bf2f(u0.y);
        acc2 += a0 * bf2f(u0.z);
        acc3 += a0 * bf2f(u0.w);
    }
    float* o = out + (size_t)node * HC + off;
    o[0] = fmaxf(acc0 + bias[off + 0], 0.f);
    o[1] = fmaxf(acc1 + bias[off + 1], 0.f);
    o[2] = fmaxf(acc2 + bias[off + 2], 0.f);
    o[3] = fmaxf(acc3 + bias[off + 3], 0.f);
}

// ---------------------------------------------------------------------------
// out1[node] = sigmoid(concat(x1,x2,x3) . Wf + bf) — wave per node.
// ---------------------------------------------------------------------------
__global__ __launch_bounds__(256) void final_linear(
    const float* __restrict__ x1, const float* __restrict__ x2,
    const float* __restrict__ x3, const float* __restrict__ Wf,
    const float* __restrict__ bf, float* __restrict__ out1, int n) {
    int gw   = (blockIdx.x * blockDim.x + threadIdx.x) >> 6;
    int lane = threadIdx.x & 63;
    if (gw >= n) return;
    float s = 0.f;
    const float* r1 = x1 + (size_t)gw * 256;
#pragma unroll
    for (int i = 0; i < 4; i++) { int k = lane + 64 * i; s += r1[k] * Wf[k]; }
    const float* r2 = x2 + (size_t)gw * 256;
#pragma unroll
    for (int i = 0; i < 4; i++) { int k = lane + 64 * i; s += r2[k] * Wf[256 + k]; }
    const float* r3 = x3 + (size_t)gw * 768;
#pragma unroll
    for (int i = 0; i < 12; i++) { int k = lane + 64 * i; s += r3[k] * Wf[512 + k]; }
#pragma unroll
    for (int off = 32; off > 0; off >>= 1) s += __shfl_xor(s, off, 64);
    if (lane == 0) out1[gw] = 1.f / (1.f + __expf(-(s + bf[0])));
}

// ---------------------------------------------------------------------------
// MLP: xm=[x,out1] (17) -> 128 relu -> 64 relu -> 1 sigmoid.  Wave per node.
// ---------------------------------------------------------------------------
__global__ __launch_bounds__(256) void mlp_kernel(
    const float* __restrict__ x, const float* __restrict__ out1,
    const float* __restrict__ M1w, const float* __restrict__ M1b,
    const float* __restrict__ M2w, const float* __restrict__ M2b,
    const float* __restrict__ M3w, const float* __restrict__ M3b,
    float* __restrict__ out2, int n) {
    __shared__ float h1s[4][128];
    int w    = threadIdx.x >> 6;
    int lane = threadIdx.x & 63;
    int node = blockIdx.x * 4 + w;
    bool valid = node < n;
    int nd = valid ? node : 0;

    float xm[17];
#pragma unroll
    for (int k = 0; k < 16; k++) xm[k] = x[nd * 16 + k];
    xm[16] = out1[nd];

    float a0 = M1b[lane], a1 = M1b[lane + 64];
#pragma unroll
    for (int k = 0; k < 17; k++) {
        a0 += xm[k] * M1w[k * 128 + lane];
        a1 += xm[k] * M1w[k * 128 + lane + 64];
    }
    h1s[w][lane]      = fmaxf(a0, 0.f);
    h1s[w][lane + 64] = fmaxf(a1, 0.f);
    __syncthreads();

    float b0 = M2b[lane];
#pragma unroll 16
    for (int k = 0; k < 128; k++) b0 += h1s[w][k] * M2w[k * 64 + lane];
    b0 = fmaxf(b0, 0.f);

    float p = b0 * M3w[lane];
#pragma unroll
    for (int off = 32; off > 0; off >>= 1) p += __shfl_xor(p, off, 64);
    if (lane == 0 && valid) out2[node] = 1.f / (1.f + __expf(-(p + M3b[0])));
}

// ---------------------------------------------------------------------------
extern "C" void kernel_launch(void* const* d_in, const int* in_sizes, int n_in,
                              void* d_out, int out_size, void* d_ws, size_t ws_size,
                              hipStream_t stream) {
    const float* x   = (const float*)d_in[0];
    const int*   ei  = (const int*)d_in[1];
    const float* W1  = (const float*)d_in[3];
    const float* a1s = (const float*)d_in[4];
    const float* a1d = (const float*)d_in[5];
    const float* b1  = (const float*)d_in[6];
    const float* W2  = (const float*)d_in[7];
    const float* a2s = (const float*)d_in[8];
    const float* a2d = (const float*)d_in[9];
    const float* b2  = (const float*)d_in[10];
    const float* W3  = (const float*)d_in[11];
    const float* a3s = (const float*)d_in[12];
    const float* a3d = (const float*)d_in[13];
    const float* b3  = (const float*)d_in[14];
    const float* Wf  = (const float*)d_in[15];
    const float* bf  = (const float*)d_in[16];
    const float* M1w = (const float*)d_in[17];
    const float* M1b = (const float*)d_in[18];
    const float* M2w = (const float*)d_in[19];
    const float* M2b = (const float*)d_in[20];
    const float* M3w = (const float*)d_in[21];
    const float* M3b = (const float*)d_in[22];

    const int N = in_sizes[0] / 16;        // 10000
    const int E = in_sizes[1] / 2;         // 320000
    const int Etot = E + N;

    char* base = (char*)d_ws;
    size_t off = 0;
    auto carve = [&](size_t bytes) {
        char* p = base + off;
        off = (off + bytes + 255) & ~(size_t)255;
        return p;
    };
    bf16_t* hbuf   = (bf16_t*)carve((size_t)N * 768 * 2);
    float*  x1     = (float*)carve((size_t)N * 256 * 4);
    float*  x2     = (float*)carve((size_t)N * 256 * 4);
    float*  x3     = (float*)carve((size_t)N * 768 * 4);
    float*  al     = (float*)carve((size_t)N * 12 * 4);
    float*  ar     = (float*)carve((size_t)N * 12 * 4);
    float*  alphab = (float*)carve((size_t)Etot * 12 * 4);
    int*    rowptr = (int*)carve((size_t)(N + 1) * 4);
    int*    counts = (int*)carve((size_t)N * 4);
    int*    cursor = (int*)carve((size_t)N * 4);
    int*    esrc   = (int*)carve((size_t)Etot * 4);
    (void)ws_size;

    float* out1 = (float*)d_out;
    float* out2 = (float*)d_out + N;

    const int TB = 256;
    int eb = (Etot + TB - 1) / TB;
    int nb = (N + TB - 1) / TB;

    // --- CSR by dst ---
    zero_i32<<<nb, TB, 0, stream>>>(counts, N);
    zero_i32<<<nb, TB, 0, stream>>>(cursor, N);
    count_edges<<<eb, TB, 0, stream>>>(ei, E, N, counts);
    scan_rowptr<<<1, 1024, 0, stream>>>(counts, rowptr, N);
    fill_edges<<<eb, TB, 0, stream>>>(ei, E, N, rowptr, cursor, esrc);

    // --- layer 1: 16 -> 8x32 ---
    gemm_f32_bf16<<<dim3(4, (N + 63) / 64), TB, 0, stream>>>(x, W1, hbuf, N, 16, 256);
    gat_scores<8, 32><<<(N * 8 + TB - 1) / TB, TB, 0, stream>>>(hbuf, a1s, a1d, al, ar, N);
    ms_alpha<8><<<(N * 8 + TB - 1) / TB, TB, 0, stream>>>(al, ar, rowptr, esrc, alphab, N);
    gat_agg<8, 32><<<(N * 64 + TB - 1) / TB, TB, 0, stream>>>(hbuf, alphab, rowptr, esrc, b1, x1, N);

    // --- layer 2: 256 -> 8x32 ---
    gemm_f32_bf16<<<dim3(4, (N + 63) / 64), TB, 0, stream>>>(x1, W2, hbuf, N, 256, 256);
    gat_scores<8, 32><<<(N * 8 + TB - 1) / TB, TB, 0, stream>>>(hbuf, a2s, a2d, al, ar, N);
    ms_alpha<8><<<(N * 8 + TB - 1) / TB, TB, 0, stream>>>(al, ar, rowptr, esrc, alphab, N);
    gat_agg<8, 32><<<(N * 64 + TB - 1) / TB, TB, 0, stream>>>(hbuf, alphab, rowptr, esrc, b2, x2, N);

    // --- layer 3: 256 -> 12x64 ---
    gemm_f32_bf16<<<dim3(12, (N + 63) / 64), TB, 0, stream>>>(x2, W3, hbuf, N, 256, 768);
    gat_scores<12, 64><<<(N * 12 + TB - 1) / TB, TB, 0, stream>>>(hbuf, a3s, a3d, al, ar, N);
    ms_alpha<12><<<(N * 12 + TB - 1) / TB, TB, 0, stream>>>(al, ar, rowptr, esrc, alphab, N);
    gat_agg<12, 64><<<(N * 3 * 64 + TB - 1) / TB, TB, 0, stream>>>(hbuf, alphab, rowptr, esrc, b3, x3, N);

    // --- final linear + MLP ---
    final_linear<<<(N * 64 + TB - 1) / TB, TB, 0, stream>>>(x1, x2, x3, Wf, bf, out1, N);
    mlp_kernel<<<(N + 3) / 4, TB, 0, stream>>>(x, out1, M1w, M1b, M2w, M2b, M3w, M3b, out2, N);
}

// Round 3
// 436.488 us; speedup vs baseline: 1.2660x; 1.1576x over previous
//
#include <hip/hip_runtime.h>
#include <math.h>

// ---------------------------------------------------------------------------
// GATNet (3x GATConv + final linear + MLP), MI355X.
// R2: MFMA bf16 GEMM (L2/L3), wave-parallel softmax, fast block scan,
// head-split L3 aggregation for L2 locality, unroll-8 gathers.
// ---------------------------------------------------------------------------

typedef unsigned short bf16_t;
typedef __attribute__((ext_vector_type(8))) short bf16x8;
typedef __attribute__((ext_vector_type(4))) float f32x4;

__device__ inline float bf2f(bf16_t u) {
    union { unsigned int i; float f; } v; v.i = ((unsigned int)u) << 16; return v.f;
}
__device__ inline bf16_t f2bf(float f) {
    union { float f; unsigned int i; } v; v.f = f;
    unsigned int r = v.i + 0x7FFF + ((v.i >> 16) & 1);   // round-nearest-even
    return (bf16_t)(r >> 16);
}

// ------------------------------ CSR build ----------------------------------

__global__ void zero_i32(int* p, int n) {
    int i = blockIdx.x * blockDim.x + threadIdx.x;
    if (i < n) p[i] = 0;
}

__global__ void count_edges(const int* __restrict__ ei, int E, int Nn,
                            int* __restrict__ counts) {
    int e = blockIdx.x * blockDim.x + threadIdx.x;
    if (e >= E + Nn) return;
    int dst = (e < E) ? ei[E + e] : (e - E);   // self-loops appended
    atomicAdd(&counts[dst], 1);
}

// single block, 1024 threads: serial-per-thread + shuffle block scan
__global__ __launch_bounds__(1024) void scan_rowptr(const int* __restrict__ counts,
                                                    int* __restrict__ rowptr, int n) {
    const int IPT = (n + 1023) / 1024;   // 10 for n=10000 (<=16)
    int t = threadIdx.x;
    int base = t * IPT;
    int loc[16];
    int run = 0;
#pragma unroll
    for (int i = 0; i < 16; i++) {
        if (i >= IPT) break;
        int idx = base + i;
        int v = (idx < n) ? counts[idx] : 0;
        loc[i] = run;
        run += v;
    }
    int lane = t & 63, wid = t >> 6;
    int v = run;
    for (int off = 1; off < 64; off <<= 1) {
        int u = __shfl_up(v, off, 64);
        if (lane >= off) v += u;
    }
    __shared__ int wsum[16];
    __shared__ int woff[16];
    if (lane == 63) wsum[wid] = v;
    __syncthreads();
    if (t == 0) { int s = 0; for (int i = 0; i < 16; i++) { woff[i] = s; s += wsum[i]; } }
    __syncthreads();
    int excl = v - run + woff[wid];   // exclusive prefix before this thread
#pragma unroll
    for (int i = 0; i < 16; i++) {
        if (i >= IPT) break;
        int idx = base + i;
        if (idx < n) rowptr[idx] = excl + loc[i];
    }
    if (t == 1023) rowptr[n] = excl + run;
}

__global__ void fill_edges(const int* __restrict__ ei, int E, int Nn,
                           const int* __restrict__ rowptr, int* __restrict__ cursor,
                           int* __restrict__ edge_src) {
    int e = blockIdx.x * blockDim.x + threadIdx.x;
    if (e >= E + Nn) return;
    int src, dst;
    if (e < E) { src = ei[e]; dst = ei[E + e]; }
    else       { src = e - E; dst = src; }
    int pos = atomicAdd(&cursor[dst], 1);
    edge_src[rowptr[dst] + pos] = src;
}

// ---------------------------------------------------------------------------
// Transpose + cast fp32 W[K][N] -> bf16 Wt[N][K] (for MFMA B fragments).
// ---------------------------------------------------------------------------
__global__ __launch_bounds__(256) void transpose_cast(const float* __restrict__ W,
                                                      bf16_t* __restrict__ Wt,
                                                      int K, int Nc) {
    __shared__ float tile[16][17];
    int k0 = blockIdx.x * 16, n0 = blockIdx.y * 16;
    int tx = threadIdx.x & 15, ty = threadIdx.x >> 4;
    tile[ty][tx] = W[(size_t)(k0 + ty) * Nc + n0 + tx];
    __syncthreads();
    Wt[(size_t)(n0 + ty) * K + k0 + tx] = f2bf(tile[tx][ty]);
}

// ---------------------------------------------------------------------------
// fp32 GEMM (layer 1 only, K=16), bf16 out.  BM=BN=64, BK=16, 256 thr.
// ---------------------------------------------------------------------------
__global__ __launch_bounds__(256) void gemm_f32_bf16(const float* __restrict__ A,
                                                     const float* __restrict__ B,
                                                     bf16_t* __restrict__ Cm,
                                                     int M, int K, int Nc) {
    __shared__ float As[16][64];
    __shared__ float Bs[16][64];
    int t  = threadIdx.x;
    int tx = t & 15, ty = t >> 4;
    int row0 = blockIdx.y * 64, col0 = blockIdx.x * 64;
    int a_r = t >> 2, a_c = (t & 3) * 4;
    int b_r = t >> 4, b_c = (t & 15) * 4;

    float acc[4][4];
#pragma unroll
    for (int i = 0; i < 4; i++)
#pragma unroll
        for (int j = 0; j < 4; j++) acc[i][j] = 0.f;

    for (int kt = 0; kt < K; kt += 16) {
        float4 av = make_float4(0.f, 0.f, 0.f, 0.f);
        int gr = row0 + a_r;
        if (gr < M) av = *(const float4*)(A + (size_t)gr * K + kt + a_c);
        As[a_c + 0][a_r] = av.x;
        As[a_c + 1][a_r] = av.y;
        As[a_c + 2][a_r] = av.z;
        As[a_c + 3][a_r] = av.w;
        float4 bv = *(const float4*)(B + (size_t)(kt + b_r) * Nc + col0 + b_c);
        *(float4*)&Bs[b_r][b_c] = bv;
        __syncthreads();
#pragma unroll
        for (int k = 0; k < 16; k++) {
            float4 a4 = *(const float4*)&As[k][ty * 4];
            float4 b4 = *(const float4*)&Bs[k][tx * 4];
            float aa[4] = {a4.x, a4.y, a4.z, a4.w};
            float bb[4] = {b4.x, b4.y, b4.z, b4.w};
#pragma unroll
            for (int i = 0; i < 4; i++)
#pragma unroll
                for (int j = 0; j < 4; j++) acc[i][j] += aa[i] * bb[j];
        }
        __syncthreads();
    }
#pragma unroll
    for (int i = 0; i < 4; i++) {
        int gr = row0 + ty * 4 + i;
        if (gr < M) {
            ushort4 v;
            v.x = f2bf(acc[i][0]); v.y = f2bf(acc[i][1]);
            v.z = f2bf(acc[i][2]); v.w = f2bf(acc[i][3]);
            *(ushort4*)(Cm + (size_t)gr * Nc + col0 + tx * 4) = v;
        }
    }
}

// ---------------------------------------------------------------------------
// MFMA bf16 GEMM: C[M,Nc] = A[M,K]bf16 @ Bt[Nc,K]bf16 (B pre-transposed).
// Block 256 thr = 4 waves; BM=128 (wave: 32 rows), BN=64; frags from global
// (L1 serves B reuse within block, L2 serves A/B across blocks).
// A-frag: lane holds A[m=lane&15][k=quad*8+j]; B-frag: B[k=quad*8+j][n=lane&15];
// C/D: col=lane&15, row=quad*4+reg (learn_hip m89/m120 verified layouts).
// ---------------------------------------------------------------------------
__global__ __launch_bounds__(256) void gemm_mfma(const bf16_t* __restrict__ A,
                                                 const bf16_t* __restrict__ Bt,
                                                 bf16_t* __restrict__ Cm,
                                                 int M, int K, int Nc) {
    int wave = threadIdx.x >> 6, lane = threadIdx.x & 63;
    int quad = lane >> 4, l16 = lane & 15;
    int m0 = blockIdx.y * 128 + wave * 32;
    int n0 = blockIdx.x * 64;

    f32x4 acc[2][4];
    f32x4 z = {0.f, 0.f, 0.f, 0.f};
#pragma unroll
    for (int i = 0; i < 2; i++)
#pragma unroll
        for (int j = 0; j < 4; j++) acc[i][j] = z;

    int r0 = m0 + l16;       if (r0 >= M) r0 = M - 1;
    int r1 = m0 + 16 + l16;  if (r1 >= M) r1 = M - 1;
    const bf16_t* Ap0 = A + (size_t)r0 * K + quad * 8;
    const bf16_t* Ap1 = A + (size_t)r1 * K + quad * 8;
    const bf16_t* Bp0 = Bt + (size_t)(n0 + 0  + l16) * K + quad * 8;
    const bf16_t* Bp1 = Bt + (size_t)(n0 + 16 + l16) * K + quad * 8;
    const bf16_t* Bp2 = Bt + (size_t)(n0 + 32 + l16) * K + quad * 8;
    const bf16_t* Bp3 = Bt + (size_t)(n0 + 48 + l16) * K + quad * 8;

    for (int kt = 0; kt < K; kt += 32) {
        bf16x8 a0 = *(const bf16x8*)(Ap0 + kt);
        bf16x8 a1 = *(const bf16x8*)(Ap1 + kt);
        bf16x8 b0 = *(const bf16x8*)(Bp0 + kt);
        bf16x8 b1 = *(const bf16x8*)(Bp1 + kt);
        bf16x8 b2 = *(const bf16x8*)(Bp2 + kt);
        bf16x8 b3 = *(const bf16x8*)(Bp3 + kt);
        acc[0][0] = __builtin_amdgcn_mfma_f32_16x16x32_bf16(a0, b0, acc[0][0], 0, 0, 0);
        acc[1][0] = __builtin_amdgcn_mfma_f32_16x16x32_bf16(a1, b0, acc[1][0], 0, 0, 0);
        acc[0][1] = __builtin_amdgcn_mfma_f32_16x16x32_bf16(a0, b1, acc[0][1], 0, 0, 0);
        acc[1][1] = __builtin_amdgcn_mfma_f32_16x16x32_bf16(a1, b1, acc[1][1], 0, 0, 0);
        acc[0][2] = __builtin_amdgcn_mfma_f32_16x16x32_bf16(a0, b2, acc[0][2], 0, 0, 0);
        acc[1][2] = __builtin_amdgcn_mfma_f32_16x16x32_bf16(a1, b2, acc[1][2], 0, 0, 0);
        acc[0][3] = __builtin_amdgcn_mfma_f32_16x16x32_bf16(a0, b3, acc[0][3], 0, 0, 0);
        acc[1][3] = __builtin_amdgcn_mfma_f32_16x16x32_bf16(a1, b3, acc[1][3], 0, 0, 0);
    }
#pragma unroll
    for (int i = 0; i < 2; i++)
#pragma unroll
        for (int j = 0; j < 4; j++)
#pragma unroll
            for (int r = 0; r < 4; r++) {
                int gr = m0 + i * 16 + quad * 4 + r;
                if (gr < M) Cm[(size_t)gr * Nc + n0 + j * 16 + l16] = f2bf(acc[i][j][r]);
            }
}

// ---------------------------------------------------------------------------
// Per-(node,head) attention scores from bf16 h: al = <h,a_s>, ar = <h,a_d>
// ---------------------------------------------------------------------------
template <int H, int C>
__global__ void gat_scores(const bf16_t* __restrict__ hbuf, const float* __restrict__ a_s,
                           const float* __restrict__ a_d, float* __restrict__ al,
                           float* __restrict__ ar, int n) {
    int i = blockIdx.x * blockDim.x + threadIdx.x;
    if (i >= n * H) return;
    int node = i / H, h = i - node * H;
    const bf16_t* hr = hbuf + (size_t)node * (H * C) + h * C;
    const float* as_ = a_s + h * C;
    const float* ad_ = a_d + h * C;
    float sa = 0.f, sd = 0.f;
#pragma unroll
    for (int c = 0; c < C; c += 4) {
        ushort4 u = *(const ushort4*)(hr + c);
        float v0 = bf2f(u.x), v1 = bf2f(u.y), v2 = bf2f(u.z), v3 = bf2f(u.w);
        sa += v0 * as_[c] + v1 * as_[c + 1] + v2 * as_[c + 2] + v3 * as_[c + 3];
        sd += v0 * ad_[c] + v1 * ad_[c + 1] + v2 * ad_[c + 2] + v3 * ad_[c + 3];
    }
    al[i] = sa;
    ar[i] = sd;
}

// ---------------------------------------------------------------------------
// Wave per (node,head) softmax -> normalized alpha, planar [head][edge].
// Lane-parallel over edges, shuffle reductions; e cached in reg for 1st iter.
// ---------------------------------------------------------------------------
template <int H>
__global__ __launch_bounds__(256) void alpha_wave(const float* __restrict__ al,
                                                  const float* __restrict__ ar,
                                                  const int* __restrict__ rowptr,
                                                  const int* __restrict__ esrc,
                                                  float* __restrict__ alpha,
                                                  int n, int Etot) {
    int w = (blockIdx.x * blockDim.x + threadIdx.x) >> 6;
    if (w >= n * H) return;
    int node = w / H, h = w - node * H;
    int lane = threadIdx.x & 63;
    float arv = ar[node * H + h];
    int beg = rowptr[node], end = rowptr[node + 1];
    int j0 = beg + lane;
    float e0 = -INFINITY;
    if (j0 < end) {
        float e = al[esrc[j0] * H + h] + arv;
        e0 = (e > 0.f) ? e : 0.2f * e;
    }
    float m = e0;
    for (int j = j0 + 64; j < end; j += 64) {
        float e = al[esrc[j] * H + h] + arv;
        e = (e > 0.f) ? e : 0.2f * e;
        m = fmaxf(m, e);
    }
#pragma unroll
    for (int off = 32; off > 0; off >>= 1) m = fmaxf(m, __shfl_xor(m, off, 64));
    float p0 = (j0 < end) ? __expf(e0 - m) : 0.f;
    float s = p0;
    for (int j = j0 + 64; j < end; j += 64) {
        float e = al[esrc[j] * H + h] + arv;
        e = (e > 0.f) ? e : 0.2f * e;
        s += __expf(e - m);
    }
#pragma unroll
    for (int off = 32; off > 0; off >>= 1) s += __shfl_xor(s, off, 64);
    float inv = 1.f / s;
    float* ap = alpha + (size_t)h * Etot;
    if (j0 < end) ap[j0] = p0 * inv;
    for (int j = j0 + 64; j < end; j += 64) {
        float e = al[esrc[j] * H + h] + arv;
        e = (e > 0.f) ? e : 0.2f * e;
        ap[j] = __expf(e - m) * inv;
    }
}

// ---------------------------------------------------------------------------
// Aggregation, wave per node over heads [h0, h0 + 64/(C/4)).
// Lane owns 4 channels of one head; unroll-8 independent gathers.
// Writes fp32 out (+ optional bf16 copy for next GEMM's A).
// ---------------------------------------------------------------------------
template <int C>
__global__ __launch_bounds__(256) void gat_agg(
    const bf16_t* __restrict__ hbuf, const float* __restrict__ alpha,
    const int* __restrict__ rowptr, const int* __restrict__ esrc,
    const float* __restrict__ bias, float* __restrict__ out,
    bf16_t* __restrict__ outb, int n, int h0, int Htot, int Etot) {
    constexpr int LPH = C / 4;
    int node = (blockIdx.x * blockDim.x + threadIdx.x) >> 6;
    if (node >= n) return;
    int lane = threadIdx.x & 63;
    int head = h0 + lane / LPH;
    int ch   = (lane % LPH) * 4;
    int off  = head * C + ch;
    int HC   = Htot * C;
    const bf16_t* hb = hbuf + off;
    const float*  ap = alpha + (size_t)head * Etot;

    float acc0 = 0.f, acc1 = 0.f, acc2 = 0.f, acc3 = 0.f;
    int beg = rowptr[node], end = rowptr[node + 1];
    int j = beg;
    for (; j + 8 <= end; j += 8) {
        int s[8]; float a[8]; ushort4 u[8];
#pragma unroll
        for (int q = 0; q < 8; q++) { s[q] = esrc[j + q]; a[q] = ap[j + q]; }
#pragma unroll
        for (int q = 0; q < 8; q++) u[q] = *(const ushort4*)(hb + (size_t)s[q] * HC);
#pragma unroll
        for (int q = 0; q < 8; q++) {
            acc0 += a[q] * bf2f(u[q].x);
            acc1 += a[q] * bf2f(u[q].y);
            acc2 += a[q] * bf2f(u[q].z);
            acc3 += a[q] * bf2f(u[q].w);
        }
    }
    for (; j < end; j++) {
        int s0 = esrc[j];
        float a0 = ap[j];
        ushort4 u0 = *(const ushort4*)(hb + (size_t)s0 * HC);
        acc0 += a0 * bf2f(u0.x);
        acc1 += a0 * bf2f(u0.y);
        acc2 += a0 * bf2f(u0.z);
        acc3 += a0 * bf2f(u0.w);
    }
    float v0 = fmaxf(acc0 + bias[off + 0], 0.f);
    float v1 = fmaxf(acc1 + bias[off + 1], 0.f);
    float v2 = fmaxf(acc2 + bias[off + 2], 0.f);
    float v3 = fmaxf(acc3 + bias[off + 3], 0.f);
    float* o = out + (size_t)node * HC + off;
    o[0] = v0; o[1] = v1; o[2] = v2; o[3] = v3;
    if (outb) {
        ushort4 ub;
        ub.x = f2bf(v0); ub.y = f2bf(v1); ub.z = f2bf(v2); ub.w = f2bf(v3);
        *(ushort4*)(outb + (size_t)node * HC + off) = ub;
    }
}

// ---------------------------------------------------------------------------
// out1[node] = sigmoid(concat(x1,x2,x3) . Wf + bf) — wave per node.
// ---------------------------------------------------------------------------
__global__ __launch_bounds__(256) void final_linear(
    const float* __restrict__ x1, const float* __restrict__ x2,
    const float* __restrict__ x3, const float* __restrict__ Wf,
    const float* __restrict__ bf, float* __restrict__ out1, int n) {
    int gw   = (blockIdx.x * blockDim.x + threadIdx.x) >> 6;
    int lane = threadIdx.x & 63;
    if (gw >= n) return;
    float s = 0.f;
    const float* r1 = x1 + (size_t)gw * 256;
#pragma unroll
    for (int i = 0; i < 4; i++) { int k = lane + 64 * i; s += r1[k] * Wf[k]; }
    const float* r2 = x2 + (size_t)gw * 256;
#pragma unroll
    for (int i = 0; i < 4; i++) { int k = lane + 64 * i; s += r2[k] * Wf[256 + k]; }
    const float* r3 = x3 + (size_t)gw * 768;
#pragma unroll
    for (int i = 0; i < 12; i++) { int k = lane + 64 * i; s += r3[k] * Wf[512 + k]; }
#pragma unroll
    for (int off = 32; off > 0; off >>= 1) s += __shfl_xor(s, off, 64);
    if (lane == 0) out1[gw] = 1.f / (1.f + __expf(-(s + bf[0])));
}

// ---------------------------------------------------------------------------
// MLP: xm=[x,out1] (17) -> 128 relu -> 64 relu -> 1 sigmoid.  Wave per node.
// ---------------------------------------------------------------------------
__global__ __launch_bounds__(256) void mlp_kernel(
    const float* __restrict__ x, const float* __restrict__ out1,
    const float* __restrict__ M1w, const float* __restrict__ M1b,
    const float* __restrict__ M2w, const float* __restrict__ M2b,
    const float* __restrict__ M3w, const float* __restrict__ M3b,
    float* __restrict__ out2, int n) {
    __shared__ float h1s[4][128];
    int w    = threadIdx.x >> 6;
    int lane = threadIdx.x & 63;
    int node = blockIdx.x * 4 + w;
    bool valid = node < n;
    int nd = valid ? node : 0;

    float xm[17];
#pragma unroll
    for (int k = 0; k < 16; k++) xm[k] = x[nd * 16 + k];
    xm[16] = out1[nd];

    float a0 = M1b[lane], a1 = M1b[lane + 64];
#pragma unroll
    for (int k = 0; k < 17; k++) {
        a0 += xm[k] * M1w[k * 128 + lane];
        a1 += xm[k] * M1w[k * 128 + lane + 64];
    }
    h1s[w][lane]      = fmaxf(a0, 0.f);
    h1s[w][lane + 64] = fmaxf(a1, 0.f);
    __syncthreads();

    float b0 = M2b[lane];
#pragma unroll 16
    for (int k = 0; k < 128; k++) b0 += h1s[w][k] * M2w[k * 64 + lane];
    b0 = fmaxf(b0, 0.f);

    float p = b0 * M3w[lane];
#pragma unroll
    for (int off = 32; off > 0; off >>= 1) p += __shfl_xor(p, off, 64);
    if (lane == 0 && valid) out2[node] = 1.f / (1.f + __expf(-(p + M3b[0])));
}

// ---------------------------------------------------------------------------
extern "C" void kernel_launch(void* const* d_in, const int* in_sizes, int n_in,
                              void* d_out, int out_size, void* d_ws, size_t ws_size,
                              hipStream_t stream) {
    const float* x   = (const float*)d_in[0];
    const int*   ei  = (const int*)d_in[1];
    const float* W1  = (const float*)d_in[3];
    const float* a1s = (const float*)d_in[4];
    const float* a1d = (const float*)d_in[5];
    const float* b1  = (const float*)d_in[6];
    const float* W2  = (const float*)d_in[7];
    const float* a2s = (const float*)d_in[8];
    const float* a2d = (const float*)d_in[9];
    const float* b2  = (const float*)d_in[10];
    const float* W3  = (const float*)d_in[11];
    const float* a3s = (const float*)d_in[12];
    const float* a3d = (const float*)d_in[13];
    const float* b3  = (const float*)d_in[14];
    const float* Wf  = (const float*)d_in[15];
    const float* bf  = (const float*)d_in[16];
    const float* M1w = (const float*)d_in[17];
    const float* M1b = (const float*)d_in[18];
    const float* M2w = (const float*)d_in[19];
    const float* M2b = (const float*)d_in[20];
    const float* M3w = (const float*)d_in[21];
    const float* M3b = (const float*)d_in[22];

    const int N = in_sizes[0] / 16;        // 10000
    const int E = in_sizes[1] / 2;         // 320000
    const int Etot = E + N;

    char* base = (char*)d_ws;
    size_t off = 0;
    auto carve = [&](size_t bytes) {
        char* p = base + off;
        off = (off + bytes + 255) & ~(size_t)255;
        return p;
    };
    bf16_t* hbuf   = (bf16_t*)carve((size_t)N * 768 * 2);
    float*  x1     = (float*)carve((size_t)N * 256 * 4);
    float*  x2     = (float*)carve((size_t)N * 256 * 4);
    float*  x3     = (float*)carve((size_t)N * 768 * 4);
    bf16_t* x1b    = (bf16_t*)carve((size_t)N * 256 * 2);
    bf16_t* x2b    = (bf16_t*)carve((size_t)N * 256 * 2);
    bf16_t* Wt2    = (bf16_t*)carve((size_t)256 * 256 * 2);
    bf16_t* Wt3    = (bf16_t*)carve((size_t)256 * 768 * 2);
    float*  al     = (float*)carve((size_t)N * 12 * 4);
    float*  ar     = (float*)carve((size_t)N * 12 * 4);
    float*  alphab = (float*)carve((size_t)Etot * 12 * 4);
    int*    rowptr = (int*)carve((size_t)(N + 1) * 4);
    int*    counts = (int*)carve((size_t)N * 4);
    int*    cursor = (int*)carve((size_t)N * 4);
    int*    esrc   = (int*)carve((size_t)Etot * 4);
    (void)ws_size;

    float* out1 = (float*)d_out;
    float* out2 = (float*)d_out + N;

    const int TB = 256;
    int eb = (Etot + TB - 1) / TB;
    int nb = (N + TB - 1) / TB;
    int nodewaves = (N * 64 + TB - 1) / TB;

    // --- CSR by dst + weight prep ---
    zero_i32<<<nb, TB, 0, stream>>>(counts, N);
    zero_i32<<<nb, TB, 0, stream>>>(cursor, N);
    count_edges<<<eb, TB, 0, stream>>>(ei, E, N, counts);
    scan_rowptr<<<1, 1024, 0, stream>>>(counts, rowptr, N);
    fill_edges<<<eb, TB, 0, stream>>>(ei, E, N, rowptr, cursor, esrc);
    transpose_cast<<<dim3(16, 16), TB, 0, stream>>>(W2, Wt2, 256, 256);
    transpose_cast<<<dim3(16, 48), TB, 0, stream>>>(W3, Wt3, 256, 768);

    // --- layer 1: 16 -> 8x32 (fp32 gemm, tiny K) ---
    gemm_f32_bf16<<<dim3(4, (N + 63) / 64), TB, 0, stream>>>(x, W1, hbuf, N, 16, 256);
    gat_scores<8, 32><<<(N * 8 + TB - 1) / TB, TB, 0, stream>>>(hbuf, a1s, a1d, al, ar, N);
    alpha_wave<8><<<(N * 8 * 64 + TB - 1) / TB, TB, 0, stream>>>(al, ar, rowptr, esrc, alphab, N, Etot);
    gat_agg<32><<<nodewaves, TB, 0, stream>>>(hbuf, alphab, rowptr, esrc, b1, x1, x1b, N, 0, 8, Etot);

    // --- layer 2: 256 -> 8x32 (MFMA) ---
    gemm_mfma<<<dim3(4, (N + 127) / 128), TB, 0, stream>>>(x1b, Wt2, hbuf, N, 256, 256);
    gat_scores<8, 32><<<(N * 8 + TB - 1) / TB, TB, 0, stream>>>(hbuf, a2s, a2d, al, ar, N);
    alpha_wave<8><<<(N * 8 * 64 + TB - 1) / TB, TB, 0, stream>>>(al, ar, rowptr, esrc, alphab, N, Etot);
    gat_agg<32><<<nodewaves, TB, 0, stream>>>(hbuf, alphab, rowptr, esrc, b2, x2, x2b, N, 0, 8, Etot);

    // --- layer 3: 256 -> 12x64 (MFMA; aggregation split by head-group) ---
    gemm_mfma<<<dim3(12, (N + 127) / 128), TB, 0, stream>>>(x2b, Wt3, hbuf, N, 256, 768);
    gat_scores<12, 64><<<(N * 12 + TB - 1) / TB, TB, 0, stream>>>(hbuf, a3s, a3d, al, ar, N);
    alpha_wave<12><<<(N * 12 * 64 + TB - 1) / TB, TB, 0, stream>>>(al, ar, rowptr, esrc, alphab, N, Etot);
    gat_agg<64><<<nodewaves, TB, 0, stream>>>(hbuf, alphab, rowptr, esrc, b3, x3, (bf16_t*)0, N, 0, 12, Etot);
    gat_agg<64><<<nodewaves, TB, 0, stream>>>(hbuf, alphab, rowptr, esrc, b3, x3, (bf16_t*)0, N, 4, 12, Etot);
    gat_agg<64><<<nodewaves, TB, 0, stream>>>(hbuf, alphab, rowptr, esrc, b3, x3, (bf16_t*)0, N, 8, 12, Etot);

    // --- final linear + MLP ---
    final_linear<<<nodewaves, TB, 0, stream>>>(x1, x2, x3, Wf, bf, out1, N);
    mlp_kernel<<<(N + 3) / 4, TB, 0, stream>>>(x, out1, M1w, M1b, M2w, M2b, M3w, M3b, out2, N);
}

// Round 5
// 405.087 us; speedup vs baseline: 1.3641x; 1.0775x over previous
//
#include <hip/hip_runtime.h>
#include <math.h>

// ---------------------------------------------------------------------------
// GATNet (3x GATConv + final linear + MLP), MI355X.
// R4 = R3 with the cursor-zeroing OOB fix (counts+cursor now one contiguous
// carve; zeroing 2N ints is exact). R3 design: L2-resident 2.56MB gather
// slices, no-max softmax, all-bf16 activations, fused final+MLP.
// ---------------------------------------------------------------------------

typedef unsigned short bf16_t;
typedef __attribute__((ext_vector_type(8))) short bf16x8;
typedef __attribute__((ext_vector_type(4))) float f32x4;

__device__ inline float bf2f(bf16_t u) {
    union { unsigned int i; float f; } v; v.i = ((unsigned int)u) << 16; return v.f;
}
__device__ inline bf16_t f2bf(float f) {
    union { float f; unsigned int i; } v; v.f = f;
    unsigned int r = v.i + 0x7FFF + ((v.i >> 16) & 1);   // round-nearest-even
    return (bf16_t)(r >> 16);
}

// ------------------------------ CSR build ----------------------------------

__global__ void zero_i32(int* p, int n) {
    int i = blockIdx.x * blockDim.x + threadIdx.x;
    if (i < n) p[i] = 0;
}

__global__ void count_edges(const int* __restrict__ ei, int E, int Nn,
                            int* __restrict__ counts) {
    int e = blockIdx.x * blockDim.x + threadIdx.x;
    if (e >= E + Nn) return;
    int dst = (e < E) ? ei[E + e] : (e - E);   // self-loops appended
    atomicAdd(&counts[dst], 1);
}

// single block, 1024 threads: serial-per-thread + shuffle block scan
__global__ __launch_bounds__(1024) void scan_rowptr(const int* __restrict__ counts,
                                                    int* __restrict__ rowptr, int n) {
    const int IPT = (n + 1023) / 1024;   // <=16
    int t = threadIdx.x;
    int base = t * IPT;
    int loc[16];
    int run = 0;
#pragma unroll
    for (int i = 0; i < 16; i++) {
        if (i >= IPT) break;
        int idx = base + i;
        int v = (idx < n) ? counts[idx] : 0;
        loc[i] = run;
        run += v;
    }
    int lane = t & 63, wid = t >> 6;
    int v = run;
    for (int off = 1; off < 64; off <<= 1) {
        int u = __shfl_up(v, off, 64);
        if (lane >= off) v += u;
    }
    __shared__ int wsum[16];
    __shared__ int woff[16];
    if (lane == 63) wsum[wid] = v;
    __syncthreads();
    if (t == 0) { int s = 0; for (int i = 0; i < 16; i++) { woff[i] = s; s += wsum[i]; } }
    __syncthreads();
    int excl = v - run + woff[wid];
#pragma unroll
    for (int i = 0; i < 16; i++) {
        if (i >= IPT) break;
        int idx = base + i;
        if (idx < n) rowptr[idx] = excl + loc[i];
    }
    if (t == 1023) rowptr[n] = excl + run;
}

__global__ void fill_edges(const int* __restrict__ ei, int E, int Nn,
                           const int* __restrict__ rowptr, int* __restrict__ cursor,
                           int* __restrict__ edge_src) {
    int e = blockIdx.x * blockDim.x + threadIdx.x;
    if (e >= E + Nn) return;
    int src, dst;
    if (e < E) { src = ei[e]; dst = ei[E + e]; }
    else       { src = e - E; dst = src; }
    int pos = atomicAdd(&cursor[dst], 1);
    edge_src[rowptr[dst] + pos] = src;
}

// ---------------------------------------------------------------------------
// Transpose + cast fp32 W[K][N] -> bf16 Wt[N][K].
// ---------------------------------------------------------------------------
__global__ __launch_bounds__(256) void transpose_cast(const float* __restrict__ W,
                                                      bf16_t* __restrict__ Wt,
                                                      int K, int Nc) {
    __shared__ float tile[16][17];
    int k0 = blockIdx.x * 16, n0 = blockIdx.y * 16;
    int tx = threadIdx.x & 15, ty = threadIdx.x >> 4;
    tile[ty][tx] = W[(size_t)(k0 + ty) * Nc + n0 + tx];
    __syncthreads();
    Wt[(size_t)(n0 + ty) * K + k0 + tx] = f2bf(tile[tx][ty]);
}

// ---------------------------------------------------------------------------
// fp32 GEMM (layer 1, K=16), bf16 out.
// ---------------------------------------------------------------------------
__global__ __launch_bounds__(256) void gemm_f32_bf16(const float* __restrict__ A,
                                                     const float* __restrict__ B,
                                                     bf16_t* __restrict__ Cm,
                                                     int M, int K, int Nc) {
    __shared__ float As[16][64];
    __shared__ float Bs[16][64];
    int t  = threadIdx.x;
    int tx = t & 15, ty = t >> 4;
    int row0 = blockIdx.y * 64, col0 = blockIdx.x * 64;
    int a_r = t >> 2, a_c = (t & 3) * 4;
    int b_r = t >> 4, b_c = (t & 15) * 4;

    float acc[4][4];
#pragma unroll
    for (int i = 0; i < 4; i++)
#pragma unroll
        for (int j = 0; j < 4; j++) acc[i][j] = 0.f;

    for (int kt = 0; kt < K; kt += 16) {
        float4 av = make_float4(0.f, 0.f, 0.f, 0.f);
        int gr = row0 + a_r;
        if (gr < M) av = *(const float4*)(A + (size_t)gr * K + kt + a_c);
        As[a_c + 0][a_r] = av.x;
        As[a_c + 1][a_r] = av.y;
        As[a_c + 2][a_r] = av.z;
        As[a_c + 3][a_r] = av.w;
        float4 bv = *(const float4*)(B + (size_t)(kt + b_r) * Nc + col0 + b_c);
        *(float4*)&Bs[b_r][b_c] = bv;
        __syncthreads();
#pragma unroll
        for (int k = 0; k < 16; k++) {
            float4 a4 = *(const float4*)&As[k][ty * 4];
            float4 b4 = *(const float4*)&Bs[k][tx * 4];
            float aa[4] = {a4.x, a4.y, a4.z, a4.w};
            float bb[4] = {b4.x, b4.y, b4.z, b4.w};
#pragma unroll
            for (int i = 0; i < 4; i++)
#pragma unroll
                for (int j = 0; j < 4; j++) acc[i][j] += aa[i] * bb[j];
        }
        __syncthreads();
    }
#pragma unroll
    for (int i = 0; i < 4; i++) {
        int gr = row0 + ty * 4 + i;
        if (gr < M) {
            ushort4 v;
            v.x = f2bf(acc[i][0]); v.y = f2bf(acc[i][1]);
            v.z = f2bf(acc[i][2]); v.w = f2bf(acc[i][3]);
            *(ushort4*)(Cm + (size_t)gr * Nc + col0 + tx * 4) = v;
        }
    }
}

// ---------------------------------------------------------------------------
// MFMA bf16 GEMM (layers 2/3): C = A[M,K] @ Bt[Nc,K]^T, frags from global.
// ---------------------------------------------------------------------------
__global__ __launch_bounds__(256) void gemm_mfma(const bf16_t* __restrict__ A,
                                                 const bf16_t* __restrict__ Bt,
                                                 bf16_t* __restrict__ Cm,
                                                 int M, int K, int Nc) {
    int wave = threadIdx.x >> 6, lane = threadIdx.x & 63;
    int quad = lane >> 4, l16 = lane & 15;
    int m0 = blockIdx.y * 128 + wave * 32;
    int n0 = blockIdx.x * 64;

    f32x4 acc[2][4];
    f32x4 z = {0.f, 0.f, 0.f, 0.f};
#pragma unroll
    for (int i = 0; i < 2; i++)
#pragma unroll
        for (int j = 0; j < 4; j++) acc[i][j] = z;

    int r0 = m0 + l16;       if (r0 >= M) r0 = M - 1;
    int r1 = m0 + 16 + l16;  if (r1 >= M) r1 = M - 1;
    const bf16_t* Ap0 = A + (size_t)r0 * K + quad * 8;
    const bf16_t* Ap1 = A + (size_t)r1 * K + quad * 8;
    const bf16_t* Bp0 = Bt + (size_t)(n0 + 0  + l16) * K + quad * 8;
    const bf16_t* Bp1 = Bt + (size_t)(n0 + 16 + l16) * K + quad * 8;
    const bf16_t* Bp2 = Bt + (size_t)(n0 + 32 + l16) * K + quad * 8;
    const bf16_t* Bp3 = Bt + (size_t)(n0 + 48 + l16) * K + quad * 8;

    for (int kt = 0; kt < K; kt += 32) {
        bf16x8 a0 = *(const bf16x8*)(Ap0 + kt);
        bf16x8 a1 = *(const bf16x8*)(Ap1 + kt);
        bf16x8 b0 = *(const bf16x8*)(Bp0 + kt);
        bf16x8 b1 = *(const bf16x8*)(Bp1 + kt);
        bf16x8 b2 = *(const bf16x8*)(Bp2 + kt);
        bf16x8 b3 = *(const bf16x8*)(Bp3 + kt);
        acc[0][0] = __builtin_amdgcn_mfma_f32_16x16x32_bf16(a0, b0, acc[0][0], 0, 0, 0);
        acc[1][0] = __builtin_amdgcn_mfma_f32_16x16x32_bf16(a1, b0, acc[1][0], 0, 0, 0);
        acc[0][1] = __builtin_amdgcn_mfma_f32_16x16x32_bf16(a0, b1, acc[0][1], 0, 0, 0);
        acc[1][1] = __builtin_amdgcn_mfma_f32_16x16x32_bf16(a1, b1, acc[1][1], 0, 0, 0);
        acc[0][2] = __builtin_amdgcn_mfma_f32_16x16x32_bf16(a0, b2, acc[0][2], 0, 0, 0);
        acc[1][2] = __builtin_amdgcn_mfma_f32_16x16x32_bf16(a1, b2, acc[1][2], 0, 0, 0);
        acc[0][3] = __builtin_amdgcn_mfma_f32_16x16x32_bf16(a0, b3, acc[0][3], 0, 0, 0);
        acc[1][3] = __builtin_amdgcn_mfma_f32_16x16x32_bf16(a1, b3, acc[1][3], 0, 0, 0);
    }
#pragma unroll
    for (int i = 0; i < 2; i++)
#pragma unroll
        for (int j = 0; j < 4; j++)
#pragma unroll
            for (int r = 0; r < 4; r++) {
                int gr = m0 + i * 16 + quad * 4 + r;
                if (gr < M) Cm[(size_t)gr * Nc + n0 + j * 16 + l16] = f2bf(acc[i][j][r]);
            }
}

// ---------------------------------------------------------------------------
// Per-(node,head) attention scores from bf16 h.
// ---------------------------------------------------------------------------
template <int H, int C>
__global__ void gat_scores(const bf16_t* __restrict__ hbuf, const float* __restrict__ a_s,
                           const float* __restrict__ a_d, float* __restrict__ al,
                           float* __restrict__ ar, int n) {
    int i = blockIdx.x * blockDim.x + threadIdx.x;
    if (i >= n * H) return;
    int node = i / H, h = i - node * H;
    const bf16_t* hr = hbuf + (size_t)node * (H * C) + h * C;
    const float* as_ = a_s + h * C;
    const float* ad_ = a_d + h * C;
    float sa = 0.f, sd = 0.f;
#pragma unroll
    for (int c = 0; c < C; c += 4) {
        ushort4 u = *(const ushort4*)(hr + c);
        float v0 = bf2f(u.x), v1 = bf2f(u.y), v2 = bf2f(u.z), v3 = bf2f(u.w);
        sa += v0 * as_[c] + v1 * as_[c + 1] + v2 * as_[c + 2] + v3 * as_[c + 3];
        sd += v0 * ad_[c] + v1 * ad_[c + 1] + v2 * ad_[c + 2] + v3 * ad_[c + 3];
    }
    al[i] = sa;
    ar[i] = sd;
}

// ---------------------------------------------------------------------------
// Wave per (node,head): alpha = exp(e)/sum (scores structurally bounded;
// clamp 60 for safety — no max pass needed). Planar [head][edge] output.
// ---------------------------------------------------------------------------
template <int H>
__global__ __launch_bounds__(256) void alpha_wave(const float* __restrict__ al,
                                                  const float* __restrict__ ar,
                                                  const int* __restrict__ rowptr,
                                                  const int* __restrict__ esrc,
                                                  float* __restrict__ alpha,
                                                  int n, int Etot) {
    int w = (blockIdx.x * blockDim.x + threadIdx.x) >> 6;
    if (w >= n * H) return;
    int node = w / H, h = w - node * H;
    int lane = threadIdx.x & 63;
    float arv = ar[node * H + h];
    int beg = rowptr[node], end = rowptr[node + 1];
    int j0 = beg + lane;
    float p0 = 0.f;
    if (j0 < end) {
        float e = al[esrc[j0] * H + h] + arv;
        e = (e > 0.f) ? e : 0.2f * e;
        p0 = __expf(fminf(e, 60.f));
    }
    float s = p0;
    for (int j = j0 + 64; j < end; j += 64) {
        float e = al[esrc[j] * H + h] + arv;
        e = (e > 0.f) ? e : 0.2f * e;
        s += __expf(fminf(e, 60.f));
    }
#pragma unroll
    for (int off = 32; off > 0; off >>= 1) s += __shfl_xor(s, off, 64);
    float inv = 1.f / s;
    float* ap = alpha + (size_t)h * Etot;
    if (j0 < end) ap[j0] = p0 * inv;
    for (int j = j0 + 64; j < end; j += 64) {
        float e = al[esrc[j] * H + h] + arv;
        e = (e > 0.f) ? e : 0.2f * e;
        ap[j] = __expf(fminf(e, 60.f)) * inv;
    }
}

// ---------------------------------------------------------------------------
// Aggregation: 128 channels per wave (ushort2/lane) -> 2.56MB L2-resident
// slice per channel-group; all groups in one dispatch (group = blockIdx.x /
// nodeblocks, sequential ordering keeps slice locality). bf16 output only.
// ---------------------------------------------------------------------------
template <int HC_, int C>
__global__ __launch_bounds__(256) void gat_agg(
    const bf16_t* __restrict__ hbuf, const float* __restrict__ alpha,
    const int* __restrict__ rowptr, const int* __restrict__ esrc,
    const float* __restrict__ bias, bf16_t* __restrict__ outb,
    int n, int Etot, int nodeblocks) {
    int group = blockIdx.x / nodeblocks;
    int nb    = blockIdx.x - group * nodeblocks;
    int node  = nb * 4 + (threadIdx.x >> 6);
    if (node >= n) return;
    int lane = threadIdx.x & 63;
    int gc   = group * 128 + lane * 2;     // global channel (2 per lane)
    int head = gc / C;
    const bf16_t* hb = hbuf + gc;
    const float*  ap = alpha + (size_t)head * Etot;

    float acc0 = 0.f, acc1 = 0.f;
    int beg = rowptr[node], end = rowptr[node + 1];
    int j = beg;
    for (; j + 8 <= end; j += 8) {
        int s[8]; float a[8]; ushort2 u[8];
#pragma unroll
        for (int q = 0; q < 8; q++) { s[q] = esrc[j + q]; a[q] = ap[j + q]; }
#pragma unroll
        for (int q = 0; q < 8; q++) u[q] = *(const ushort2*)(hb + (size_t)s[q] * HC_);
#pragma unroll
        for (int q = 0; q < 8; q++) {
            acc0 += a[q] * bf2f(u[q].x);
            acc1 += a[q] * bf2f(u[q].y);
        }
    }
    for (; j < end; j++) {
        int s0 = esrc[j];
        float a0 = ap[j];
        ushort2 u0 = *(const ushort2*)(hb + (size_t)s0 * HC_);
        acc0 += a0 * bf2f(u0.x);
        acc1 += a0 * bf2f(u0.y);
    }
    float v0 = fmaxf(acc0 + bias[gc + 0], 0.f);
    float v1 = fmaxf(acc1 + bias[gc + 1], 0.f);
    ushort2 ub;
    ub.x = f2bf(v0); ub.y = f2bf(v1);
    *(ushort2*)(outb + (size_t)node * HC_ + gc) = ub;
}

// ---------------------------------------------------------------------------
// Fused head: out1 = sigmoid(concat(x1,x2,x3).Wf + bf); then MLP -> out2.
// Wave per node (4 per block); bf16 activations in.
// ---------------------------------------------------------------------------
__global__ __launch_bounds__(256) void head_fused(
    const float* __restrict__ x, const bf16_t* __restrict__ x1b,
    const bf16_t* __restrict__ x2b, const bf16_t* __restrict__ x3b,
    const float* __restrict__ Wf, const float* __restrict__ bfc,
    const float* __restrict__ M1w, const float* __restrict__ M1b,
    const float* __restrict__ M2w, const float* __restrict__ M2b,
    const float* __restrict__ M3w, const float* __restrict__ M3b,
    float* __restrict__ out1, float* __restrict__ out2, int n) {
    __shared__ float h1s[4][128];
    int w    = threadIdx.x >> 6;
    int lane = threadIdx.x & 63;
    int node = blockIdx.x * 4 + w;
    bool valid = node < n;
    int nd = valid ? node : 0;

    float s = 0.f;
    {
        ushort4 u = *(const ushort4*)(x1b + (size_t)nd * 256 + lane * 4);
        const float* wv = Wf + lane * 4;
        s += bf2f(u.x) * wv[0] + bf2f(u.y) * wv[1] + bf2f(u.z) * wv[2] + bf2f(u.w) * wv[3];
    }
    {
        ushort4 u = *(const ushort4*)(x2b + (size_t)nd * 256 + lane * 4);
        const float* wv = Wf + 256 + lane * 4;
        s += bf2f(u.x) * wv[0] + bf2f(u.y) * wv[1] + bf2f(u.z) * wv[2] + bf2f(u.w) * wv[3];
    }
#pragma unroll
    for (int i = 0; i < 3; i++) {
        int k = i * 256 + lane * 4;
        ushort4 u = *(const ushort4*)(x3b + (size_t)nd * 768 + k);
        const float* wv = Wf + 512 + k;
        s += bf2f(u.x) * wv[0] + bf2f(u.y) * wv[1] + bf2f(u.z) * wv[2] + bf2f(u.w) * wv[3];
    }
#pragma unroll
    for (int off = 32; off > 0; off >>= 1) s += __shfl_xor(s, off, 64);
    float so = 1.f / (1.f + __expf(-(s + bfc[0])));
    if (lane == 0 && valid) out1[node] = so;

    // MLP
    float xm[17];
#pragma unroll
    for (int k = 0; k < 16; k++) xm[k] = x[nd * 16 + k];
    xm[16] = so;

    float a0 = M1b[lane], a1 = M1b[lane + 64];
#pragma unroll
    for (int k = 0; k < 17; k++) {
        a0 += xm[k] * M1w[k * 128 + lane];
        a1 += xm[k] * M1w[k * 128 + lane + 64];
    }
    h1s[w][lane]      = fmaxf(a0, 0.f);
    h1s[w][lane + 64] = fmaxf(a1, 0.f);
    __syncthreads();

    float b0 = M2b[lane];
#pragma unroll 16
    for (int k = 0; k < 128; k++) b0 += h1s[w][k] * M2w[k * 64 + lane];
    b0 = fmaxf(b0, 0.f);

    float p = b0 * M3w[lane];
#pragma unroll
    for (int off = 32; off > 0; off >>= 1) p += __shfl_xor(p, off, 64);
    if (lane == 0 && valid) out2[node] = 1.f / (1.f + __expf(-(p + M3b[0])));
}

// ---------------------------------------------------------------------------
extern "C" void kernel_launch(void* const* d_in, const int* in_sizes, int n_in,
                              void* d_out, int out_size, void* d_ws, size_t ws_size,
                              hipStream_t stream) {
    const float* x   = (const float*)d_in[0];
    const int*   ei  = (const int*)d_in[1];
    const float* W1  = (const float*)d_in[3];
    const float* a1s = (const float*)d_in[4];
    const float* a1d = (const float*)d_in[5];
    const float* b1  = (const float*)d_in[6];
    const float* W2  = (const float*)d_in[7];
    const float* a2s = (const float*)d_in[8];
    const float* a2d = (const float*)d_in[9];
    const float* b2  = (const float*)d_in[10];
    const float* W3  = (const float*)d_in[11];
    const float* a3s = (const float*)d_in[12];
    const float* a3d = (const float*)d_in[13];
    const float* b3  = (const float*)d_in[14];
    const float* Wf  = (const float*)d_in[15];
    const float* bf  = (const float*)d_in[16];
    const float* M1w = (const float*)d_in[17];
    const float* M1b = (const float*)d_in[18];
    const float* M2w = (const float*)d_in[19];
    const float* M2b = (const float*)d_in[20];
    const float* M3w = (const float*)d_in[21];
    const float* M3b = (const float*)d_in[22];

    const int N = in_sizes[0] / 16;        // 10000
    const int E = in_sizes[1] / 2;         // 320000
    const int Etot = E + N;

    char* base = (char*)d_ws;
    size_t off = 0;
    auto carve = [&](size_t bytes) {
        char* p = base + off;
        off = (off + bytes + 255) & ~(size_t)255;
        return p;
    };
    bf16_t* hbuf   = (bf16_t*)carve((size_t)N * 768 * 2);
    bf16_t* x1b    = (bf16_t*)carve((size_t)N * 256 * 2);
    bf16_t* x2b    = (bf16_t*)carve((size_t)N * 256 * 2);
    bf16_t* x3b    = (bf16_t*)carve((size_t)N * 768 * 2);
    bf16_t* Wt2    = (bf16_t*)carve((size_t)256 * 256 * 2);
    bf16_t* Wt3    = (bf16_t*)carve((size_t)256 * 768 * 2);
    float*  al     = (float*)carve((size_t)N * 12 * 4);
    float*  ar     = (float*)carve((size_t)N * 12 * 4);
    float*  alphab = (float*)carve((size_t)Etot * 12 * 4);
    int*    rowptr = (int*)carve((size_t)(N + 1) * 4);
    int*    cnt2   = (int*)carve((size_t)(2 * N) * 4);   // counts | cursor, contiguous
    int*    counts = cnt2;
    int*    cursor = cnt2 + N;
    int*    esrc   = (int*)carve((size_t)Etot * 4);
    (void)ws_size;

    float* out1 = (float*)d_out;
    float* out2 = (float*)d_out + N;

    const int TB = 256;
    int eb = (Etot + TB - 1) / TB;
    int nodeblocks = (N + 3) / 4;          // 4 node-waves per block

    // --- CSR by dst + weight prep ---
    zero_i32<<<(2 * N + TB - 1) / TB, TB, 0, stream>>>(cnt2, 2 * N);
    count_edges<<<eb, TB, 0, stream>>>(ei, E, N, counts);
    scan_rowptr<<<1, 1024, 0, stream>>>(counts, rowptr, N);
    fill_edges<<<eb, TB, 0, stream>>>(ei, E, N, rowptr, cursor, esrc);
    transpose_cast<<<dim3(16, 16), TB, 0, stream>>>(W2, Wt2, 256, 256);
    transpose_cast<<<dim3(16, 48), TB, 0, stream>>>(W3, Wt3, 256, 768);

    // --- layer 1: 16 -> 8x32 ---
    gemm_f32_bf16<<<dim3(4, (N + 63) / 64), TB, 0, stream>>>(x, W1, hbuf, N, 16, 256);
    gat_scores<8, 32><<<(N * 8 + TB - 1) / TB, TB, 0, stream>>>(hbuf, a1s, a1d, al, ar, N);
    alpha_wave<8><<<(N * 8 * 64 + TB - 1) / TB, TB, 0, stream>>>(al, ar, rowptr, esrc, alphab, N, Etot);
    gat_agg<256, 32><<<2 * nodeblocks, TB, 0, stream>>>(hbuf, alphab, rowptr, esrc, b1, x1b, N, Etot, nodeblocks);

    // --- layer 2: 256 -> 8x32 (MFMA) ---
    gemm_mfma<<<dim3(4, (N + 127) / 128), TB, 0, stream>>>(x1b, Wt2, hbuf, N, 256, 256);
    gat_scores<8, 32><<<(N * 8 + TB - 1) / TB, TB, 0, stream>>>(hbuf, a2s, a2d, al, ar, N);
    alpha_wave<8><<<(N * 8 * 64 + TB - 1) / TB, TB, 0, stream>>>(al, ar, rowptr, esrc, alphab, N, Etot);
    gat_agg<256, 32><<<2 * nodeblocks, TB, 0, stream>>>(hbuf, alphab, rowptr, esrc, b2, x2b, N, Etot, nodeblocks);

    // --- layer 3: 256 -> 12x64 (MFMA) ---
    gemm_mfma<<<dim3(12, (N + 127) / 128), TB, 0, stream>>>(x2b, Wt3, hbuf, N, 256, 768);
    gat_scores<12, 64><<<(N * 12 + TB - 1) / TB, TB, 0, stream>>>(hbuf, a3s, a3d, al, ar, N);
    alpha_wave<12><<<(N * 12 * 64 + TB - 1) / TB, TB, 0, stream>>>(al, ar, rowptr, esrc, alphab, N, Etot);
    gat_agg<768, 64><<<6 * nodeblocks, TB, 0, stream>>>(hbuf, alphab, rowptr, esrc, b3, x3b, N, Etot, nodeblocks);

    // --- fused final linear + MLP ---
    head_fused<<<nodeblocks, TB, 0, stream>>>(x, x1b, x2b, x3b, Wf, bf,
                                              M1w, M1b, M2w, M2b, M3w, M3b, out1, out2, N);
}

// Round 6
// 374.377 us; speedup vs baseline: 1.4760x; 1.0820x over previous
//
#include <hip/hip_runtime.h>
#include <math.h>

// ---------------------------------------------------------------------------
// GATNet (3x GATConv + final linear + MLP), MI355X.
// R5: agg v3 (bf16x8 16B/lane gathers, 4 edges/wave, cross-sub reduce),
// alpha v2 (wave per node, all heads, row-contiguous al reads, register p).
// Carried: MFMA GEMMs, L2-sliced groups, all-bf16 activations, fused head.
// ---------------------------------------------------------------------------

typedef unsigned short bf16_t;
typedef __attribute__((ext_vector_type(8))) short bf16x8;
typedef __attribute__((ext_vector_type(4))) float f32x4;

__device__ inline float bf2f(bf16_t u) {
    union { unsigned int i; float f; } v; v.i = ((unsigned int)u) << 16; return v.f;
}
__device__ inline float u2f(unsigned int x) {
    union { unsigned int i; float f; } v; v.i = x; return v.f;
}
__device__ inline bf16_t f2bf(float f) {
    union { float f; unsigned int i; } v; v.f = f;
    unsigned int r = v.i + 0x7FFF + ((v.i >> 16) & 1);   // round-nearest-even
    return (bf16_t)(r >> 16);
}

// ------------------------------ CSR build ----------------------------------

__global__ void zero_i32(int* p, int n) {
    int i = blockIdx.x * blockDim.x + threadIdx.x;
    if (i < n) p[i] = 0;
}

__global__ void count_edges(const int* __restrict__ ei, int E, int Nn,
                            int* __restrict__ counts) {
    int e = blockIdx.x * blockDim.x + threadIdx.x;
    if (e >= E + Nn) return;
    int dst = (e < E) ? ei[E + e] : (e - E);   // self-loops appended
    atomicAdd(&counts[dst], 1);
}

// single block, 1024 threads: serial-per-thread + shuffle block scan
__global__ __launch_bounds__(1024) void scan_rowptr(const int* __restrict__ counts,
                                                    int* __restrict__ rowptr, int n) {
    const int IPT = (n + 1023) / 1024;   // <=16
    int t = threadIdx.x;
    int base = t * IPT;
    int loc[16];
    int run = 0;
#pragma unroll
    for (int i = 0; i < 16; i++) {
        if (i >= IPT) break;
        int idx = base + i;
        int v = (idx < n) ? counts[idx] : 0;
        loc[i] = run;
        run += v;
    }
    int lane = t & 63, wid = t >> 6;
    int v = run;
    for (int off = 1; off < 64; off <<= 1) {
        int u = __shfl_up(v, off, 64);
        if (lane >= off) v += u;
    }
    __shared__ int wsum[16];
    __shared__ int woff[16];
    if (lane == 63) wsum[wid] = v;
    __syncthreads();
    if (t == 0) { int s = 0; for (int i = 0; i < 16; i++) { woff[i] = s; s += wsum[i]; } }
    __syncthreads();
    int excl = v - run + woff[wid];
#pragma unroll
    for (int i = 0; i < 16; i++) {
        if (i >= IPT) break;
        int idx = base + i;
        if (idx < n) rowptr[idx] = excl + loc[i];
    }
    if (t == 1023) rowptr[n] = excl + run;
}

__global__ void fill_edges(const int* __restrict__ ei, int E, int Nn,
                           const int* __restrict__ rowptr, int* __restrict__ cursor,
                           int* __restrict__ edge_src) {
    int e = blockIdx.x * blockDim.x + threadIdx.x;
    if (e >= E + Nn) return;
    int src, dst;
    if (e < E) { src = ei[e]; dst = ei[E + e]; }
    else       { src = e - E; dst = src; }
    int pos = atomicAdd(&cursor[dst], 1);
    edge_src[rowptr[dst] + pos] = src;
}

// ---------------------------------------------------------------------------
// Transpose + cast fp32 W[K][N] -> bf16 Wt[N][K].
// ---------------------------------------------------------------------------
__global__ __launch_bounds__(256) void transpose_cast(const float* __restrict__ W,
                                                      bf16_t* __restrict__ Wt,
                                                      int K, int Nc) {
    __shared__ float tile[16][17];
    int k0 = blockIdx.x * 16, n0 = blockIdx.y * 16;
    int tx = threadIdx.x & 15, ty = threadIdx.x >> 4;
    tile[ty][tx] = W[(size_t)(k0 + ty) * Nc + n0 + tx];
    __syncthreads();
    Wt[(size_t)(n0 + ty) * K + k0 + tx] = f2bf(tile[tx][ty]);
}

// ---------------------------------------------------------------------------
// fp32 GEMM (layer 1, K=16), bf16 out.
// ---------------------------------------------------------------------------
__global__ __launch_bounds__(256) void gemm_f32_bf16(const float* __restrict__ A,
                                                     const float* __restrict__ B,
                                                     bf16_t* __restrict__ Cm,
                                                     int M, int K, int Nc) {
    __shared__ float As[16][64];
    __shared__ float Bs[16][64];
    int t  = threadIdx.x;
    int tx = t & 15, ty = t >> 4;
    int row0 = blockIdx.y * 64, col0 = blockIdx.x * 64;
    int a_r = t >> 2, a_c = (t & 3) * 4;
    int b_r = t >> 4, b_c = (t & 15) * 4;

    float acc[4][4];
#pragma unroll
    for (int i = 0; i < 4; i++)
#pragma unroll
        for (int j = 0; j < 4; j++) acc[i][j] = 0.f;

    for (int kt = 0; kt < K; kt += 16) {
        float4 av = make_float4(0.f, 0.f, 0.f, 0.f);
        int gr = row0 + a_r;
        if (gr < M) av = *(const float4*)(A + (size_t)gr * K + kt + a_c);
        As[a_c + 0][a_r] = av.x;
        As[a_c + 1][a_r] = av.y;
        As[a_c + 2][a_r] = av.z;
        As[a_c + 3][a_r] = av.w;
        float4 bv = *(const float4*)(B + (size_t)(kt + b_r) * Nc + col0 + b_c);
        *(float4*)&Bs[b_r][b_c] = bv;
        __syncthreads();
#pragma unroll
        for (int k = 0; k < 16; k++) {
            float4 a4 = *(const float4*)&As[k][ty * 4];
            float4 b4 = *(const float4*)&Bs[k][tx * 4];
            float aa[4] = {a4.x, a4.y, a4.z, a4.w};
            float bb[4] = {b4.x, b4.y, b4.z, b4.w};
#pragma unroll
            for (int i = 0; i < 4; i++)
#pragma unroll
                for (int j = 0; j < 4; j++) acc[i][j] += aa[i] * bb[j];
        }
        __syncthreads();
    }
#pragma unroll
    for (int i = 0; i < 4; i++) {
        int gr = row0 + ty * 4 + i;
        if (gr < M) {
            ushort4 v;
            v.x = f2bf(acc[i][0]); v.y = f2bf(acc[i][1]);
            v.z = f2bf(acc[i][2]); v.w = f2bf(acc[i][3]);
            *(ushort4*)(Cm + (size_t)gr * Nc + col0 + tx * 4) = v;
        }
    }
}

// ---------------------------------------------------------------------------
// MFMA bf16 GEMM (layers 2/3): C = A[M,K] @ Bt[Nc,K]^T, frags from global.
// ---------------------------------------------------------------------------
__global__ __launch_bounds__(256) void gemm_mfma(const bf16_t* __restrict__ A,
                                                 const bf16_t* __restrict__ Bt,
                                                 bf16_t* __restrict__ Cm,
                                                 int M, int K, int Nc) {
    int wave = threadIdx.x >> 6, lane = threadIdx.x & 63;
    int quad = lane >> 4, l16 = lane & 15;
    int m0 = blockIdx.y * 128 + wave * 32;
    int n0 = blockIdx.x * 64;

    f32x4 acc[2][4];
    f32x4 z = {0.f, 0.f, 0.f, 0.f};
#pragma unroll
    for (int i = 0; i < 2; i++)
#pragma unroll
        for (int j = 0; j < 4; j++) acc[i][j] = z;

    int r0 = m0 + l16;       if (r0 >= M) r0 = M - 1;
    int r1 = m0 + 16 + l16;  if (r1 >= M) r1 = M - 1;
    const bf16_t* Ap0 = A + (size_t)r0 * K + quad * 8;
    const bf16_t* Ap1 = A + (size_t)r1 * K + quad * 8;
    const bf16_t* Bp0 = Bt + (size_t)(n0 + 0  + l16) * K + quad * 8;
    const bf16_t* Bp1 = Bt + (size_t)(n0 + 16 + l16) * K + quad * 8;
    const bf16_t* Bp2 = Bt + (size_t)(n0 + 32 + l16) * K + quad * 8;
    const bf16_t* Bp3 = Bt + (size_t)(n0 + 48 + l16) * K + quad * 8;

    for (int kt = 0; kt < K; kt += 32) {
        bf16x8 a0 = *(const bf16x8*)(Ap0 + kt);
        bf16x8 a1 = *(const bf16x8*)(Ap1 + kt);
        bf16x8 b0 = *(const bf16x8*)(Bp0 + kt);
        bf16x8 b1 = *(const bf16x8*)(Bp1 + kt);
        bf16x8 b2 = *(const bf16x8*)(Bp2 + kt);
        bf16x8 b3 = *(const bf16x8*)(Bp3 + kt);
        acc[0][0] = __builtin_amdgcn_mfma_f32_16x16x32_bf16(a0, b0, acc[0][0], 0, 0, 0);
        acc[1][0] = __builtin_amdgcn_mfma_f32_16x16x32_bf16(a1, b0, acc[1][0], 0, 0, 0);
        acc[0][1] = __builtin_amdgcn_mfma_f32_16x16x32_bf16(a0, b1, acc[0][1], 0, 0, 0);
        acc[1][1] = __builtin_amdgcn_mfma_f32_16x16x32_bf16(a1, b1, acc[1][1], 0, 0, 0);
        acc[0][2] = __builtin_amdgcn_mfma_f32_16x16x32_bf16(a0, b2, acc[0][2], 0, 0, 0);
        acc[1][2] = __builtin_amdgcn_mfma_f32_16x16x32_bf16(a1, b2, acc[1][2], 0, 0, 0);
        acc[0][3] = __builtin_amdgcn_mfma_f32_16x16x32_bf16(a0, b3, acc[0][3], 0, 0, 0);
        acc[1][3] = __builtin_amdgcn_mfma_f32_16x16x32_bf16(a1, b3, acc[1][3], 0, 0, 0);
    }
#pragma unroll
    for (int i = 0; i < 2; i++)
#pragma unroll
        for (int j = 0; j < 4; j++)
#pragma unroll
            for (int r = 0; r < 4; r++) {
                int gr = m0 + i * 16 + quad * 4 + r;
                if (gr < M) Cm[(size_t)gr * Nc + n0 + j * 16 + l16] = f2bf(acc[i][j][r]);
            }
}

// ---------------------------------------------------------------------------
// Per-(node,head) attention scores from bf16 h.
// ---------------------------------------------------------------------------
template <int H, int C>
__global__ void gat_scores(const bf16_t* __restrict__ hbuf, const float* __restrict__ a_s,
                           const float* __restrict__ a_d, float* __restrict__ al,
                           float* __restrict__ ar, int n) {
    int i = blockIdx.x * blockDim.x + threadIdx.x;
    if (i >= n * H) return;
    int node = i / H, h = i - node * H;
    const bf16_t* hr = hbuf + (size_t)node * (H * C) + h * C;
    const float* as_ = a_s + h * C;
    const float* ad_ = a_d + h * C;
    float sa = 0.f, sd = 0.f;
#pragma unroll
    for (int c = 0; c < C; c += 4) {
        ushort4 u = *(const ushort4*)(hr + c);
        float v0 = bf2f(u.x), v1 = bf2f(u.y), v2 = bf2f(u.z), v3 = bf2f(u.w);
        sa += v0 * as_[c] + v1 * as_[c + 1] + v2 * as_[c + 2] + v3 * as_[c + 3];
        sd += v0 * ad_[c] + v1 * ad_[c + 1] + v2 * ad_[c + 2] + v3 * ad_[c + 3];
    }
    al[i] = sa;
    ar[i] = sd;
}

// ---------------------------------------------------------------------------
// alpha v2: wave per node, ALL heads. Lanes parallel over edges; each lane
// reads the full al[src] row (contiguous float4s). p kept in registers for
// the first 2 iterations (deg<=128 in practice); guarded tail for the rest.
// Per-head shuffle reduce; normalized planar [head][edge] stores.
// ---------------------------------------------------------------------------
template <int H>
__global__ __launch_bounds__(256) void alpha_node(const float* __restrict__ al,
                                                  const float* __restrict__ ar,
                                                  const int* __restrict__ rowptr,
                                                  const int* __restrict__ esrc,
                                                  float* __restrict__ alpha,
                                                  int n, int Etot) {
    int node = (blockIdx.x * blockDim.x + threadIdx.x) >> 6;
    if (node >= n) return;
    int lane = threadIdx.x & 63;

    float arv[H];
#pragma unroll
    for (int h4 = 0; h4 < H; h4 += 4) {
        float4 t = *(const float4*)(ar + (size_t)node * H + h4);
        arv[h4] = t.x; arv[h4 + 1] = t.y; arv[h4 + 2] = t.z; arv[h4 + 3] = t.w;
    }
    int beg = rowptr[node], end = rowptr[node + 1];
    float p0[H], p1[H], s[H];
#pragma unroll
    for (int h = 0; h < H; h++) { p0[h] = 0.f; p1[h] = 0.f; s[h] = 0.f; }

    int j0 = beg + lane;
    if (j0 < end) {
        const float* alr = al + (size_t)esrc[j0] * H;
#pragma unroll
        for (int h4 = 0; h4 < H; h4 += 4) {
            float4 t = *(const float4*)(alr + h4);
            float e;
            e = t.x + arv[h4];     e = fmaxf(e, 0.2f * e); p0[h4]     = __expf(fminf(e, 60.f));
            e = t.y + arv[h4 + 1]; e = fmaxf(e, 0.2f * e); p0[h4 + 1] = __expf(fminf(e, 60.f));
            e = t.z + arv[h4 + 2]; e = fmaxf(e, 0.2f * e); p0[h4 + 2] = __expf(fminf(e, 60.f));
            e = t.w + arv[h4 + 3]; e = fmaxf(e, 0.2f * e); p0[h4 + 3] = __expf(fminf(e, 60.f));
        }
#pragma unroll
        for (int h = 0; h < H; h++) s[h] += p0[h];
    }
    int j1 = j0 + 64;
    if (j1 < end) {
        const float* alr = al + (size_t)esrc[j1] * H;
#pragma unroll
        for (int h4 = 0; h4 < H; h4 += 4) {
            float4 t = *(const float4*)(alr + h4);
            float e;
            e = t.x + arv[h4];     e = fmaxf(e, 0.2f * e); p1[h4]     = __expf(fminf(e, 60.f));
            e = t.y + arv[h4 + 1]; e = fmaxf(e, 0.2f * e); p1[h4 + 1] = __expf(fminf(e, 60.f));
            e = t.z + arv[h4 + 2]; e = fmaxf(e, 0.2f * e); p1[h4 + 2] = __expf(fminf(e, 60.f));
            e = t.w + arv[h4 + 3]; e = fmaxf(e, 0.2f * e); p1[h4 + 3] = __expf(fminf(e, 60.f));
        }
#pragma unroll
        for (int h = 0; h < H; h++) s[h] += p1[h];
    }
    // rare tail (deg > 128): store raw exp now, rescale after reduction
    for (int j = j0 + 128; j < end; j += 64) {
        const float* alr = al + (size_t)esrc[j] * H;
#pragma unroll
        for (int h = 0; h < H; h++) {
            float e = alr[h] + arv[h];
            e = fmaxf(e, 0.2f * e);
            float p = __expf(fminf(e, 60.f));
            alpha[(size_t)h * Etot + j] = p;
            s[h] += p;
        }
    }
    // per-head cross-lane reduction
#pragma unroll
    for (int h = 0; h < H; h++) {
        float v = s[h];
#pragma unroll
        for (int off = 32; off > 0; off >>= 1) v += __shfl_xor(v, off, 64);
        s[h] = 1.f / v;
    }
    if (j0 < end) {
#pragma unroll
        for (int h = 0; h < H; h++) alpha[(size_t)h * Etot + j0] = p0[h] * s[h];
    }
    if (j1 < end) {
#pragma unroll
        for (int h = 0; h < H; h++) alpha[(size_t)h * Etot + j1] = p1[h] * s[h];
    }
    for (int j = j0 + 128; j < end; j += 64) {
#pragma unroll
        for (int h = 0; h < H; h++) alpha[(size_t)h * Etot + j] *= s[h];
    }
}

// ---------------------------------------------------------------------------
// agg v3: wave per (node, 128-channel group). lane = (edge-sub 0..3, slot
// 0..15); each lane gathers 16 B (8 channels) of its sub-edge's h row ->
// one dwordx4 covers 4 edges x 256 B. Unroll x2 (8 edges in flight).
// Cross-sub shuffle reduce; sub==0 lanes write bias+relu bf16x8.
// ---------------------------------------------------------------------------
template <int HC_, int C>
__global__ __launch_bounds__(256) void gat_agg(
    const bf16_t* __restrict__ hbuf, const float* __restrict__ alpha,
    const int* __restrict__ rowptr, const int* __restrict__ esrc,
    const float* __restrict__ bias, bf16_t* __restrict__ outb,
    int n, int Etot, int nodeblocks) {
    int group = blockIdx.x / nodeblocks;
    int nb    = blockIdx.x - group * nodeblocks;
    int node  = nb * 4 + (threadIdx.x >> 6);
    if (node >= n) return;
    int lane = threadIdx.x & 63;
    int sub  = lane >> 4;          // edge slot 0..3
    int cl   = lane & 15;          // channel slot 0..15
    int gc   = group * 128 + cl * 8;
    int head = gc / C;
    const bf16_t* hb = hbuf + gc;
    const float*  ap = alpha + (size_t)head * Etot;

    float acc[8];
#pragma unroll
    for (int i = 0; i < 8; i++) acc[i] = 0.f;

    int beg = rowptr[node], end = rowptr[node + 1];
    for (int j0 = beg; j0 < end; j0 += 8) {
        int ja = j0 + sub, jb = j0 + 4 + sub;
        bool va = ja < end, vb = jb < end;
        int  sa = va ? esrc[ja] : 0;
        int  sb = vb ? esrc[jb] : 0;
        float aa = va ? ap[ja] : 0.f;
        float ab = vb ? ap[jb] : 0.f;
        bf16x8 ua = *(const bf16x8*)(hb + (size_t)sa * HC_);
        bf16x8 ub = *(const bf16x8*)(hb + (size_t)sb * HC_);
        const unsigned int* da = (const unsigned int*)&ua;
        const unsigned int* db = (const unsigned int*)&ub;
#pragma unroll
        for (int i = 0; i < 4; i++) {
            acc[2 * i]     += aa * u2f(da[i] << 16);
            acc[2 * i + 1] += aa * u2f(da[i] & 0xffff0000u);
        }
#pragma unroll
        for (int i = 0; i < 4; i++) {
            acc[2 * i]     += ab * u2f(db[i] << 16);
            acc[2 * i + 1] += ab * u2f(db[i] & 0xffff0000u);
        }
    }
#pragma unroll
    for (int i = 0; i < 8; i++) {
        acc[i] += __shfl_xor(acc[i], 16, 64);
        acc[i] += __shfl_xor(acc[i], 32, 64);
    }
    if (sub == 0) {
        float4 b0 = *(const float4*)(bias + gc);
        float4 b1 = *(const float4*)(bias + gc + 4);
        float bb[8] = {b0.x, b0.y, b0.z, b0.w, b1.x, b1.y, b1.z, b1.w};
        bf16x8 outv;
        unsigned short* ov = (unsigned short*)&outv;
#pragma unroll
        for (int i = 0; i < 8; i++) ov[i] = f2bf(fmaxf(acc[i] + bb[i], 0.f));
        *(bf16x8*)(outb + (size_t)node * HC_ + gc) = outv;
    }
}

// ---------------------------------------------------------------------------
// Fused head: out1 = sigmoid(concat(x1,x2,x3).Wf + bf); then MLP -> out2.
// ---------------------------------------------------------------------------
__global__ __launch_bounds__(256) void head_fused(
    const float* __restrict__ x, const bf16_t* __restrict__ x1b,
    const bf16_t* __restrict__ x2b, const bf16_t* __restrict__ x3b,
    const float* __restrict__ Wf, const float* __restrict__ bfc,
    const float* __restrict__ M1w, const float* __restrict__ M1b,
    const float* __restrict__ M2w, const float* __restrict__ M2b,
    const float* __restrict__ M3w, const float* __restrict__ M3b,
    float* __restrict__ out1, float* __restrict__ out2, int n) {
    __shared__ float h1s[4][128];
    int w    = threadIdx.x >> 6;
    int lane = threadIdx.x & 63;
    int node = blockIdx.x * 4 + w;
    bool valid = node < n;
    int nd = valid ? node : 0;

    float s = 0.f;
    {
        ushort4 u = *(const ushort4*)(x1b + (size_t)nd * 256 + lane * 4);
        const float* wv = Wf + lane * 4;
        s += bf2f(u.x) * wv[0] + bf2f(u.y) * wv[1] + bf2f(u.z) * wv[2] + bf2f(u.w) * wv[3];
    }
    {
        ushort4 u = *(const ushort4*)(x2b + (size_t)nd * 256 + lane * 4);
        const float* wv = Wf + 256 + lane * 4;
        s += bf2f(u.x) * wv[0] + bf2f(u.y) * wv[1] + bf2f(u.z) * wv[2] + bf2f(u.w) * wv[3];
    }
#pragma unroll
    for (int i = 0; i < 3; i++) {
        int k = i * 256 + lane * 4;
        ushort4 u = *(const ushort4*)(x3b + (size_t)nd * 768 + k);
        const float* wv = Wf + 512 + k;
        s += bf2f(u.x) * wv[0] + bf2f(u.y) * wv[1] + bf2f(u.z) * wv[2] + bf2f(u.w) * wv[3];
    }
#pragma unroll
    for (int off = 32; off > 0; off >>= 1) s += __shfl_xor(s, off, 64);
    float so = 1.f / (1.f + __expf(-(s + bfc[0])));
    if (lane == 0 && valid) out1[node] = so;

    float xm[17];
#pragma unroll
    for (int k = 0; k < 16; k++) xm[k] = x[nd * 16 + k];
    xm[16] = so;

    float a0 = M1b[lane], a1 = M1b[lane + 64];
#pragma unroll
    for (int k = 0; k < 17; k++) {
        a0 += xm[k] * M1w[k * 128 + lane];
        a1 += xm[k] * M1w[k * 128 + lane + 64];
    }
    h1s[w][lane]      = fmaxf(a0, 0.f);
    h1s[w][lane + 64] = fmaxf(a1, 0.f);
    __syncthreads();

    float b0 = M2b[lane];
#pragma unroll 16
    for (int k = 0; k < 128; k++) b0 += h1s[w][k] * M2w[k * 64 + lane];
    b0 = fmaxf(b0, 0.f);

    float p = b0 * M3w[lane];
#pragma unroll
    for (int off = 32; off > 0; off >>= 1) p += __shfl_xor(p, off, 64);
    if (lane == 0 && valid) out2[node] = 1.f / (1.f + __expf(-(p + M3b[0])));
}

// ---------------------------------------------------------------------------
extern "C" void kernel_launch(void* const* d_in, const int* in_sizes, int n_in,
                              void* d_out, int out_size, void* d_ws, size_t ws_size,
                              hipStream_t stream) {
    const float* x   = (const float*)d_in[0];
    const int*   ei  = (const int*)d_in[1];
    const float* W1  = (const float*)d_in[3];
    const float* a1s = (const float*)d_in[4];
    const float* a1d = (const float*)d_in[5];
    const float* b1  = (const float*)d_in[6];
    const float* W2  = (const float*)d_in[7];
    const float* a2s = (const float*)d_in[8];
    const float* a2d = (const float*)d_in[9];
    const float* b2  = (const float*)d_in[10];
    const float* W3  = (const float*)d_in[11];
    const float* a3s = (const float*)d_in[12];
    const float* a3d = (const float*)d_in[13];
    const float* b3  = (const float*)d_in[14];
    const float* Wf  = (const float*)d_in[15];
    const float* bf  = (const float*)d_in[16];
    const float* M1w = (const float*)d_in[17];
    const float* M1b = (const float*)d_in[18];
    const float* M2w = (const float*)d_in[19];
    const float* M2b = (const float*)d_in[20];
    const float* M3w = (const float*)d_in[21];
    const float* M3b = (const float*)d_in[22];

    const int N = in_sizes[0] / 16;        // 10000
    const int E = in_sizes[1] / 2;         // 320000
    const int Etot = E + N;

    char* base = (char*)d_ws;
    size_t off = 0;
    auto carve = [&](size_t bytes) {
        char* p = base + off;
        off = (off + bytes + 255) & ~(size_t)255;
        return p;
    };
    bf16_t* hbuf   = (bf16_t*)carve((size_t)N * 768 * 2);
    bf16_t* x1b    = (bf16_t*)carve((size_t)N * 256 * 2);
    bf16_t* x2b    = (bf16_t*)carve((size_t)N * 256 * 2);
    bf16_t* x3b    = (bf16_t*)carve((size_t)N * 768 * 2);
    bf16_t* Wt2    = (bf16_t*)carve((size_t)256 * 256 * 2);
    bf16_t* Wt3    = (bf16_t*)carve((size_t)256 * 768 * 2);
    float*  al     = (float*)carve((size_t)N * 12 * 4);
    float*  ar     = (float*)carve((size_t)N * 12 * 4);
    float*  alphab = (float*)carve((size_t)Etot * 12 * 4);
    int*    rowptr = (int*)carve((size_t)(N + 1) * 4);
    int*    cnt2   = (int*)carve((size_t)(2 * N) * 4);   // counts | cursor contiguous
    int*    counts = cnt2;
    int*    cursor = cnt2 + N;
    int*    esrc   = (int*)carve((size_t)Etot * 4);
    (void)ws_size;

    float* out1 = (float*)d_out;
    float* out2 = (float*)d_out + N;

    const int TB = 256;
    int eb = (Etot + TB - 1) / TB;
    int nodeblocks = (N + 3) / 4;          // 4 node-waves per block

    // --- CSR by dst + weight prep ---
    zero_i32<<<(2 * N + TB - 1) / TB, TB, 0, stream>>>(cnt2, 2 * N);
    count_edges<<<eb, TB, 0, stream>>>(ei, E, N, counts);
    scan_rowptr<<<1, 1024, 0, stream>>>(counts, rowptr, N);
    fill_edges<<<eb, TB, 0, stream>>>(ei, E, N, rowptr, cursor, esrc);
    transpose_cast<<<dim3(16, 16), TB, 0, stream>>>(W2, Wt2, 256, 256);
    transpose_cast<<<dim3(16, 48), TB, 0, stream>>>(W3, Wt3, 256, 768);

    // --- layer 1: 16 -> 8x32 ---
    gemm_f32_bf16<<<dim3(4, (N + 63) / 64), TB, 0, stream>>>(x, W1, hbuf, N, 16, 256);
    gat_scores<8, 32><<<(N * 8 + TB - 1) / TB, TB, 0, stream>>>(hbuf, a1s, a1d, al, ar, N);
    alpha_node<8><<<nodeblocks, TB, 0, stream>>>(al, ar, rowptr, esrc, alphab, N, Etot);
    gat_agg<256, 32><<<2 * nodeblocks, TB, 0, stream>>>(hbuf, alphab, rowptr, esrc, b1, x1b, N, Etot, nodeblocks);

    // --- layer 2: 256 -> 8x32 (MFMA) ---
    gemm_mfma<<<dim3(4, (N + 127) / 128), TB, 0, stream>>>(x1b, Wt2, hbuf, N, 256, 256);
    gat_scores<8, 32><<<(N * 8 + TB - 1) / TB, TB, 0, stream>>>(hbuf, a2s, a2d, al, ar, N);
    alpha_node<8><<<nodeblocks, TB, 0, stream>>>(al, ar, rowptr, esrc, alphab, N, Etot);
    gat_agg<256, 32><<<2 * nodeblocks, TB, 0, stream>>>(hbuf, alphab, rowptr, esrc, b2, x2b, N, Etot, nodeblocks);

    // --- layer 3: 256 -> 12x64 (MFMA) ---
    gemm_mfma<<<dim3(12, (N + 127) / 128), TB, 0, stream>>>(x2b, Wt3, hbuf, N, 256, 768);
    gat_scores<12, 64><<<(N * 12 + TB - 1) / TB, TB, 0, stream>>>(hbuf, a3s, a3d, al, ar, N);
    alpha_node<12><<<nodeblocks, TB, 0, stream>>>(al, ar, rowptr, esrc, alphab, N, Etot);
    gat_agg<768, 64><<<6 * nodeblocks, TB, 0, stream>>>(hbuf, alphab, rowptr, esrc, b3, x3b, N, Etot, nodeblocks);

    // --- fused final linear + MLP ---
    head_fused<<<nodeblocks, TB, 0, stream>>>(x, x1b, x2b, x3b, Wf, bf,
                                              M1w, M1b, M2w, M2b, M3w, M3b, out1, out2, N);
}

// Round 7
// 356.774 us; speedup vs baseline: 1.5489x; 1.0493x over previous
//
#include <hip/hip_runtime.h>
#include <math.h>

// ---------------------------------------------------------------------------
// GATNet (3x GATConv + final linear + MLP), MI355X.
// R6: agg v4 (guard-free 16-edge main loop, 4 gathers in flight, stride-4
// guarded tail), fused weight transpose. Carried: MFMA GEMMs, alpha v2,
// L2-sliced groups, all-bf16 activations, fused head.
// ---------------------------------------------------------------------------

typedef unsigned short bf16_t;
typedef __attribute__((ext_vector_type(8))) short bf16x8;
typedef __attribute__((ext_vector_type(4))) float f32x4;

__device__ inline float bf2f(bf16_t u) {
    union { unsigned int i; float f; } v; v.i = ((unsigned int)u) << 16; return v.f;
}
__device__ inline float u2f(unsigned int x) {
    union { unsigned int i; float f; } v; v.i = x; return v.f;
}
__device__ inline bf16_t f2bf(float f) {
    union { float f; unsigned int i; } v; v.f = f;
    unsigned int r = v.i + 0x7FFF + ((v.i >> 16) & 1);   // round-nearest-even
    return (bf16_t)(r >> 16);
}

// ------------------------------ CSR build ----------------------------------

__global__ void zero_i32(int* p, int n) {
    int i = blockIdx.x * blockDim.x + threadIdx.x;
    if (i < n) p[i] = 0;
}

__global__ void count_edges(const int* __restrict__ ei, int E, int Nn,
                            int* __restrict__ counts) {
    int e = blockIdx.x * blockDim.x + threadIdx.x;
    if (e >= E + Nn) return;
    int dst = (e < E) ? ei[E + e] : (e - E);   // self-loops appended
    atomicAdd(&counts[dst], 1);
}

// single block, 1024 threads: serial-per-thread + shuffle block scan
__global__ __launch_bounds__(1024) void scan_rowptr(const int* __restrict__ counts,
                                                    int* __restrict__ rowptr, int n) {
    const int IPT = (n + 1023) / 1024;   // <=16
    int t = threadIdx.x;
    int base = t * IPT;
    int loc[16];
    int run = 0;
#pragma unroll
    for (int i = 0; i < 16; i++) {
        if (i >= IPT) break;
        int idx = base + i;
        int v = (idx < n) ? counts[idx] : 0;
        loc[i] = run;
        run += v;
    }
    int lane = t & 63, wid = t >> 6;
    int v = run;
    for (int off = 1; off < 64; off <<= 1) {
        int u = __shfl_up(v, off, 64);
        if (lane >= off) v += u;
    }
    __shared__ int wsum[16];
    __shared__ int woff[16];
    if (lane == 63) wsum[wid] = v;
    __syncthreads();
    if (t == 0) { int s = 0; for (int i = 0; i < 16; i++) { woff[i] = s; s += wsum[i]; } }
    __syncthreads();
    int excl = v - run + woff[wid];
#pragma unroll
    for (int i = 0; i < 16; i++) {
        if (i >= IPT) break;
        int idx = base + i;
        if (idx < n) rowptr[idx] = excl + loc[i];
    }
    if (t == 1023) rowptr[n] = excl + run;
}

__global__ void fill_edges(const int* __restrict__ ei, int E, int Nn,
                           const int* __restrict__ rowptr, int* __restrict__ cursor,
                           int* __restrict__ edge_src) {
    int e = blockIdx.x * blockDim.x + threadIdx.x;
    if (e >= E + Nn) return;
    int src, dst;
    if (e < E) { src = ei[e]; dst = ei[E + e]; }
    else       { src = e - E; dst = src; }
    int pos = atomicAdd(&cursor[dst], 1);
    edge_src[rowptr[dst] + pos] = src;
}

// ---------------------------------------------------------------------------
// Fused transpose+cast for both weight matrices (K=256 each).
// blockIdx.y < 16 -> W2 (Nc=256); else W3 (Nc=768).
// ---------------------------------------------------------------------------
__global__ __launch_bounds__(256) void transpose_cast2(const float* __restrict__ W2,
                                                       bf16_t* __restrict__ Wt2,
                                                       const float* __restrict__ W3,
                                                       bf16_t* __restrict__ Wt3) {
    __shared__ float tile[16][17];
    const float* W; bf16_t* Wt; int Nc, n0;
    if (blockIdx.y < 16) { W = W2; Wt = Wt2; Nc = 256; n0 = blockIdx.y * 16; }
    else                 { W = W3; Wt = Wt3; Nc = 768; n0 = (blockIdx.y - 16) * 16; }
    int k0 = blockIdx.x * 16;
    int tx = threadIdx.x & 15, ty = threadIdx.x >> 4;
    tile[ty][tx] = W[(size_t)(k0 + ty) * Nc + n0 + tx];
    __syncthreads();
    Wt[(size_t)(n0 + ty) * 256 + k0 + tx] = f2bf(tile[tx][ty]);
}

// ---------------------------------------------------------------------------
// fp32 GEMM (layer 1, K=16), bf16 out.
// ---------------------------------------------------------------------------
__global__ __launch_bounds__(256) void gemm_f32_bf16(const float* __restrict__ A,
                                                     const float* __restrict__ B,
                                                     bf16_t* __restrict__ Cm,
                                                     int M, int K, int Nc) {
    __shared__ float As[16][64];
    __shared__ float Bs[16][64];
    int t  = threadIdx.x;
    int tx = t & 15, ty = t >> 4;
    int row0 = blockIdx.y * 64, col0 = blockIdx.x * 64;
    int a_r = t >> 2, a_c = (t & 3) * 4;
    int b_r = t >> 4, b_c = (t & 15) * 4;

    float acc[4][4];
#pragma unroll
    for (int i = 0; i < 4; i++)
#pragma unroll
        for (int j = 0; j < 4; j++) acc[i][j] = 0.f;

    for (int kt = 0; kt < K; kt += 16) {
        float4 av = make_float4(0.f, 0.f, 0.f, 0.f);
        int gr = row0 + a_r;
        if (gr < M) av = *(const float4*)(A + (size_t)gr * K + kt + a_c);
        As[a_c + 0][a_r] = av.x;
        As[a_c + 1][a_r] = av.y;
        As[a_c + 2][a_r] = av.z;
        As[a_c + 3][a_r] = av.w;
        float4 bv = *(const float4*)(B + (size_t)(kt + b_r) * Nc + col0 + b_c);
        *(float4*)&Bs[b_r][b_c] = bv;
        __syncthreads();
#pragma unroll
        for (int k = 0; k < 16; k++) {
            float4 a4 = *(const float4*)&As[k][ty * 4];
            float4 b4 = *(const float4*)&Bs[k][tx * 4];
            float aa[4] = {a4.x, a4.y, a4.z, a4.w};
            float bb[4] = {b4.x, b4.y, b4.z, b4.w};
#pragma unroll
            for (int i = 0; i < 4; i++)
#pragma unroll
                for (int j = 0; j < 4; j++) acc[i][j] += aa[i] * bb[j];
        }
        __syncthreads();
    }
#pragma unroll
    for (int i = 0; i < 4; i++) {
        int gr = row0 + ty * 4 + i;
        if (gr < M) {
            ushort4 v;
            v.x = f2bf(acc[i][0]); v.y = f2bf(acc[i][1]);
            v.z = f2bf(acc[i][2]); v.w = f2bf(acc[i][3]);
            *(ushort4*)(Cm + (size_t)gr * Nc + col0 + tx * 4) = v;
        }
    }
}

// ---------------------------------------------------------------------------
// MFMA bf16 GEMM (layers 2/3): C = A[M,K] @ Bt[Nc,K]^T, frags from global.
// ---------------------------------------------------------------------------
__global__ __launch_bounds__(256) void gemm_mfma(const bf16_t* __restrict__ A,
                                                 const bf16_t* __restrict__ Bt,
                                                 bf16_t* __restrict__ Cm,
                                                 int M, int K, int Nc) {
    int wave = threadIdx.x >> 6, lane = threadIdx.x & 63;
    int quad = lane >> 4, l16 = lane & 15;
    int m0 = blockIdx.y * 128 + wave * 32;
    int n0 = blockIdx.x * 64;

    f32x4 acc[2][4];
    f32x4 z = {0.f, 0.f, 0.f, 0.f};
#pragma unroll
    for (int i = 0; i < 2; i++)
#pragma unroll
        for (int j = 0; j < 4; j++) acc[i][j] = z;

    int r0 = m0 + l16;       if (r0 >= M) r0 = M - 1;
    int r1 = m0 + 16 + l16;  if (r1 >= M) r1 = M - 1;
    const bf16_t* Ap0 = A + (size_t)r0 * K + quad * 8;
    const bf16_t* Ap1 = A + (size_t)r1 * K + quad * 8;
    const bf16_t* Bp0 = Bt + (size_t)(n0 + 0  + l16) * K + quad * 8;
    const bf16_t* Bp1 = Bt + (size_t)(n0 + 16 + l16) * K + quad * 8;
    const bf16_t* Bp2 = Bt + (size_t)(n0 + 32 + l16) * K + quad * 8;
    const bf16_t* Bp3 = Bt + (size_t)(n0 + 48 + l16) * K + quad * 8;

    for (int kt = 0; kt < K; kt += 32) {
        bf16x8 a0 = *(const bf16x8*)(Ap0 + kt);
        bf16x8 a1 = *(const bf16x8*)(Ap1 + kt);
        bf16x8 b0 = *(const bf16x8*)(Bp0 + kt);
        bf16x8 b1 = *(const bf16x8*)(Bp1 + kt);
        bf16x8 b2 = *(const bf16x8*)(Bp2 + kt);
        bf16x8 b3 = *(const bf16x8*)(Bp3 + kt);
        acc[0][0] = __builtin_amdgcn_mfma_f32_16x16x32_bf16(a0, b0, acc[0][0], 0, 0, 0);
        acc[1][0] = __builtin_amdgcn_mfma_f32_16x16x32_bf16(a1, b0, acc[1][0], 0, 0, 0);
        acc[0][1] = __builtin_amdgcn_mfma_f32_16x16x32_bf16(a0, b1, acc[0][1], 0, 0, 0);
        acc[1][1] = __builtin_amdgcn_mfma_f32_16x16x32_bf16(a1, b1, acc[1][1], 0, 0, 0);
        acc[0][2] = __builtin_amdgcn_mfma_f32_16x16x32_bf16(a0, b2, acc[0][2], 0, 0, 0);
        acc[1][2] = __builtin_amdgcn_mfma_f32_16x16x32_bf16(a1, b2, acc[1][2], 0, 0, 0);
        acc[0][3] = __builtin_amdgcn_mfma_f32_16x16x32_bf16(a0, b3, acc[0][3], 0, 0, 0);
        acc[1][3] = __builtin_amdgcn_mfma_f32_16x16x32_bf16(a1, b3, acc[1][3], 0, 0, 0);
    }
#pragma unroll
    for (int i = 0; i < 2; i++)
#pragma unroll
        for (int j = 0; j < 4; j++)
#pragma unroll
            for (int r = 0; r < 4; r++) {
                int gr = m0 + i * 16 + quad * 4 + r;
                if (gr < M) Cm[(size_t)gr * Nc + n0 + j * 16 + l16] = f2bf(acc[i][j][r]);
            }
}

// ---------------------------------------------------------------------------
// Per-(node,head) attention scores from bf16 h.
// ---------------------------------------------------------------------------
template <int H, int C>
__global__ void gat_scores(const bf16_t* __restrict__ hbuf, const float* __restrict__ a_s,
                           const float* __restrict__ a_d, float* __restrict__ al,
                           float* __restrict__ ar, int n) {
    int i = blockIdx.x * blockDim.x + threadIdx.x;
    if (i >= n * H) return;
    int node = i / H, h = i - node * H;
    const bf16_t* hr = hbuf + (size_t)node * (H * C) + h * C;
    const float* as_ = a_s + h * C;
    const float* ad_ = a_d + h * C;
    float sa = 0.f, sd = 0.f;
#pragma unroll
    for (int c = 0; c < C; c += 4) {
        ushort4 u = *(const ushort4*)(hr + c);
        float v0 = bf2f(u.x), v1 = bf2f(u.y), v2 = bf2f(u.z), v3 = bf2f(u.w);
        sa += v0 * as_[c] + v1 * as_[c + 1] + v2 * as_[c + 2] + v3 * as_[c + 3];
        sd += v0 * ad_[c] + v1 * ad_[c + 1] + v2 * ad_[c + 2] + v3 * ad_[c + 3];
    }
    al[i] = sa;
    ar[i] = sd;
}

// ---------------------------------------------------------------------------
// alpha v2: wave per node, ALL heads; row-contiguous al reads; register p
// for deg<=128, guarded tail beyond; per-head shuffle reduce; planar stores.
// ---------------------------------------------------------------------------
template <int H>
__global__ __launch_bounds__(256) void alpha_node(const float* __restrict__ al,
                                                  const float* __restrict__ ar,
                                                  const int* __restrict__ rowptr,
                                                  const int* __restrict__ esrc,
                                                  float* __restrict__ alpha,
                                                  int n, int Etot) {
    int node = (blockIdx.x * blockDim.x + threadIdx.x) >> 6;
    if (node >= n) return;
    int lane = threadIdx.x & 63;

    float arv[H];
#pragma unroll
    for (int h4 = 0; h4 < H; h4 += 4) {
        float4 t = *(const float4*)(ar + (size_t)node * H + h4);
        arv[h4] = t.x; arv[h4 + 1] = t.y; arv[h4 + 2] = t.z; arv[h4 + 3] = t.w;
    }
    int beg = rowptr[node], end = rowptr[node + 1];
    float p0[H], p1[H], s[H];
#pragma unroll
    for (int h = 0; h < H; h++) { p0[h] = 0.f; p1[h] = 0.f; s[h] = 0.f; }

    int j0 = beg + lane;
    if (j0 < end) {
        const float* alr = al + (size_t)esrc[j0] * H;
#pragma unroll
        for (int h4 = 0; h4 < H; h4 += 4) {
            float4 t = *(const float4*)(alr + h4);
            float e;
            e = t.x + arv[h4];     e = fmaxf(e, 0.2f * e); p0[h4]     = __expf(fminf(e, 60.f));
            e = t.y + arv[h4 + 1]; e = fmaxf(e, 0.2f * e); p0[h4 + 1] = __expf(fminf(e, 60.f));
            e = t.z + arv[h4 + 2]; e = fmaxf(e, 0.2f * e); p0[h4 + 2] = __expf(fminf(e, 60.f));
            e = t.w + arv[h4 + 3]; e = fmaxf(e, 0.2f * e); p0[h4 + 3] = __expf(fminf(e, 60.f));
        }
#pragma unroll
        for (int h = 0; h < H; h++) s[h] += p0[h];
    }
    int j1 = j0 + 64;
    if (j1 < end) {
        const float* alr = al + (size_t)esrc[j1] * H;
#pragma unroll
        for (int h4 = 0; h4 < H; h4 += 4) {
            float4 t = *(const float4*)(alr + h4);
            float e;
            e = t.x + arv[h4];     e = fmaxf(e, 0.2f * e); p1[h4]     = __expf(fminf(e, 60.f));
            e = t.y + arv[h4 + 1]; e = fmaxf(e, 0.2f * e); p1[h4 + 1] = __expf(fminf(e, 60.f));
            e = t.z + arv[h4 + 2]; e = fmaxf(e, 0.2f * e); p1[h4 + 2] = __expf(fminf(e, 60.f));
            e = t.w + arv[h4 + 3]; e = fmaxf(e, 0.2f * e); p1[h4 + 3] = __expf(fminf(e, 60.f));
        }
#pragma unroll
        for (int h = 0; h < H; h++) s[h] += p1[h];
    }
    for (int j = j0 + 128; j < end; j += 64) {
        const float* alr = al + (size_t)esrc[j] * H;
#pragma unroll
        for (int h = 0; h < H; h++) {
            float e = alr[h] + arv[h];
            e = fmaxf(e, 0.2f * e);
            float p = __expf(fminf(e, 60.f));
            alpha[(size_t)h * Etot + j] = p;
            s[h] += p;
        }
    }
#pragma unroll
    for (int h = 0; h < H; h++) {
        float v = s[h];
#pragma unroll
        for (int off = 32; off > 0; off >>= 1) v += __shfl_xor(v, off, 64);
        s[h] = 1.f / v;
    }
    if (j0 < end) {
#pragma unroll
        for (int h = 0; h < H; h++) alpha[(size_t)h * Etot + j0] = p0[h] * s[h];
    }
    if (j1 < end) {
#pragma unroll
        for (int h = 0; h < H; h++) alpha[(size_t)h * Etot + j1] = p1[h] * s[h];
    }
    for (int j = j0 + 128; j < end; j += 64) {
#pragma unroll
        for (int h = 0; h < H; h++) alpha[(size_t)h * Etot + j] *= s[h];
    }
}

// ---------------------------------------------------------------------------
// agg v4: wave per (node, 128-channel group). lane = (sub 0..3, slot 0..15),
// 16 B (8 ch) per gather. Main loop: 16 edges/iter, NO bounds checks, 4
// independent gathers in flight. Guarded stride-4 tail. Cross-sub reduce.
// ---------------------------------------------------------------------------
template <int HC_, int C>
__global__ __launch_bounds__(256) void gat_agg(
    const bf16_t* __restrict__ hbuf, const float* __restrict__ alpha,
    const int* __restrict__ rowptr, const int* __restrict__ esrc,
    const float* __restrict__ bias, bf16_t* __restrict__ outb,
    int n, int Etot, int nodeblocks) {
    int group = blockIdx.x / nodeblocks;
    int nb    = blockIdx.x - group * nodeblocks;
    int node  = nb * 4 + (threadIdx.x >> 6);
    if (node >= n) return;
    int lane = threadIdx.x & 63;
    int sub  = lane >> 4;          // edge slot 0..3
    int cl   = lane & 15;          // channel slot 0..15
    int gc   = group * 128 + cl * 8;
    int head = gc / C;
    const bf16_t* hb = hbuf + gc;
    const float*  ap = alpha + (size_t)head * Etot;

    float acc[8];
#pragma unroll
    for (int i = 0; i < 8; i++) acc[i] = 0.f;

    int beg = rowptr[node], end = rowptr[node + 1];
    int deg = end - beg;
    int j = beg + sub;
    int nfull = deg >> 4;
    for (int it = 0; it < nfull; ++it, j += 16) {
        int s0 = esrc[j], s1 = esrc[j + 4], s2 = esrc[j + 8], s3 = esrc[j + 12];
        float a0 = ap[j], a1 = ap[j + 4], a2 = ap[j + 8], a3 = ap[j + 12];
        bf16x8 u0 = *(const bf16x8*)(hb + (size_t)s0 * HC_);
        bf16x8 u1 = *(const bf16x8*)(hb + (size_t)s1 * HC_);
        bf16x8 u2 = *(const bf16x8*)(hb + (size_t)s2 * HC_);
        bf16x8 u3 = *(const bf16x8*)(hb + (size_t)s3 * HC_);
        const unsigned int* d0 = (const unsigned int*)&u0;
        const unsigned int* d1 = (const unsigned int*)&u1;
        const unsigned int* d2 = (const unsigned int*)&u2;
        const unsigned int* d3 = (const unsigned int*)&u3;
#pragma unroll
        for (int i = 0; i < 4; i++) {
            acc[2 * i]     += a0 * u2f(d0[i] << 16);
            acc[2 * i + 1] += a0 * u2f(d0[i] & 0xffff0000u);
            acc[2 * i]     += a1 * u2f(d1[i] << 16);
            acc[2 * i + 1] += a1 * u2f(d1[i] & 0xffff0000u);
            acc[2 * i]     += a2 * u2f(d2[i] << 16);
            acc[2 * i + 1] += a2 * u2f(d2[i] & 0xffff0000u);
            acc[2 * i]     += a3 * u2f(d3[i] << 16);
            acc[2 * i + 1] += a3 * u2f(d3[i] & 0xffff0000u);
        }
    }
    for (; j < end; j += 4) {
        int s0 = esrc[j];
        float a0 = ap[j];
        bf16x8 u0 = *(const bf16x8*)(hb + (size_t)s0 * HC_);
        const unsigned int* d0 = (const unsigned int*)&u0;
#pragma unroll
        for (int i = 0; i < 4; i++) {
            acc[2 * i]     += a0 * u2f(d0[i] << 16);
            acc[2 * i + 1] += a0 * u2f(d0[i] & 0xffff0000u);
        }
    }
#pragma unroll
    for (int i = 0; i < 8; i++) {
        acc[i] += __shfl_xor(acc[i], 16, 64);
        acc[i] += __shfl_xor(acc[i], 32, 64);
    }
    if (sub == 0) {
        float4 b0 = *(const float4*)(bias + gc);
        float4 b1 = *(const float4*)(bias + gc + 4);
        float bb[8] = {b0.x, b0.y, b0.z, b0.w, b1.x, b1.y, b1.z, b1.w};
        bf16x8 outv;
        unsigned short* ov = (unsigned short*)&outv;
#pragma unroll
        for (int i = 0; i < 8; i++) ov[i] = f2bf(fmaxf(acc[i] + bb[i], 0.f));
        *(bf16x8*)(outb + (size_t)node * HC_ + gc) = outv;
    }
}

// ---------------------------------------------------------------------------
// Fused head: out1 = sigmoid(concat(x1,x2,x3).Wf + bf); then MLP -> out2.
// ---------------------------------------------------------------------------
__global__ __launch_bounds__(256) void head_fused(
    const float* __restrict__ x, const bf16_t* __restrict__ x1b,
    const bf16_t* __restrict__ x2b, const bf16_t* __restrict__ x3b,
    const float* __restrict__ Wf, const float* __restrict__ bfc,
    const float* __restrict__ M1w, const float* __restrict__ M1b,
    const float* __restrict__ M2w, const float* __restrict__ M2b,
    const float* __restrict__ M3w, const float* __restrict__ M3b,
    float* __restrict__ out1, float* __restrict__ out2, int n) {
    __shared__ float h1s[4][128];
    int w    = threadIdx.x >> 6;
    int lane = threadIdx.x & 63;
    int node = blockIdx.x * 4 + w;
    bool valid = node < n;
    int nd = valid ? node : 0;

    float s = 0.f;
    {
        ushort4 u = *(const ushort4*)(x1b + (size_t)nd * 256 + lane * 4);
        const float* wv = Wf + lane * 4;
        s += bf2f(u.x) * wv[0] + bf2f(u.y) * wv[1] + bf2f(u.z) * wv[2] + bf2f(u.w) * wv[3];
    }
    {
        ushort4 u = *(const ushort4*)(x2b + (size_t)nd * 256 + lane * 4);
        const float* wv = Wf + 256 + lane * 4;
        s += bf2f(u.x) * wv[0] + bf2f(u.y) * wv[1] + bf2f(u.z) * wv[2] + bf2f(u.w) * wv[3];
    }
#pragma unroll
    for (int i = 0; i < 3; i++) {
        int k = i * 256 + lane * 4;
        ushort4 u = *(const ushort4*)(x3b + (size_t)nd * 768 + k);
        const float* wv = Wf + 512 + k;
        s += bf2f(u.x) * wv[0] + bf2f(u.y) * wv[1] + bf2f(u.z) * wv[2] + bf2f(u.w) * wv[3];
    }
#pragma unroll
    for (int off = 32; off > 0; off >>= 1) s += __shfl_xor(s, off, 64);
    float so = 1.f / (1.f + __expf(-(s + bfc[0])));
    if (lane == 0 && valid) out1[node] = so;

    float xm[17];
#pragma unroll
    for (int k = 0; k < 16; k++) xm[k] = x[nd * 16 + k];
    xm[16] = so;

    float a0 = M1b[lane], a1 = M1b[lane + 64];
#pragma unroll
    for (int k = 0; k < 17; k++) {
        a0 += xm[k] * M1w[k * 128 + lane];
        a1 += xm[k] * M1w[k * 128 + lane + 64];
    }
    h1s[w][lane]      = fmaxf(a0, 0.f);
    h1s[w][lane + 64] = fmaxf(a1, 0.f);
    __syncthreads();

    float b0 = M2b[lane];
#pragma unroll 16
    for (int k = 0; k < 128; k++) b0 += h1s[w][k] * M2w[k * 64 + lane];
    b0 = fmaxf(b0, 0.f);

    float p = b0 * M3w[lane];
#pragma unroll
    for (int off = 32; off > 0; off >>= 1) p += __shfl_xor(p, off, 64);
    if (lane == 0 && valid) out2[node] = 1.f / (1.f + __expf(-(p + M3b[0])));
}

// ---------------------------------------------------------------------------
extern "C" void kernel_launch(void* const* d_in, const int* in_sizes, int n_in,
                              void* d_out, int out_size, void* d_ws, size_t ws_size,
                              hipStream_t stream) {
    const float* x   = (const float*)d_in[0];
    const int*   ei  = (const int*)d_in[1];
    const float* W1  = (const float*)d_in[3];
    const float* a1s = (const float*)d_in[4];
    const float* a1d = (const float*)d_in[5];
    const float* b1  = (const float*)d_in[6];
    const float* W2  = (const float*)d_in[7];
    const float* a2s = (const float*)d_in[8];
    const float* a2d = (const float*)d_in[9];
    const float* b2  = (const float*)d_in[10];
    const float* W3  = (const float*)d_in[11];
    const float* a3s = (const float*)d_in[12];
    const float* a3d = (const float*)d_in[13];
    const float* b3  = (const float*)d_in[14];
    const float* Wf  = (const float*)d_in[15];
    const float* bf  = (const float*)d_in[16];
    const float* M1w = (const float*)d_in[17];
    const float* M1b = (const float*)d_in[18];
    const float* M2w = (const float*)d_in[19];
    const float* M2b = (const float*)d_in[20];
    const float* M3w = (const float*)d_in[21];
    const float* M3b = (const float*)d_in[22];

    const int N = in_sizes[0] / 16;        // 10000
    const int E = in_sizes[1] / 2;         // 320000
    const int Etot = E + N;

    char* base = (char*)d_ws;
    size_t off = 0;
    auto carve = [&](size_t bytes) {
        char* p = base + off;
        off = (off + bytes + 255) & ~(size_t)255;
        return p;
    };
    bf16_t* hbuf   = (bf16_t*)carve((size_t)N * 768 * 2);
    bf16_t* x1b    = (bf16_t*)carve((size_t)N * 256 * 2);
    bf16_t* x2b    = (bf16_t*)carve((size_t)N * 256 * 2);
    bf16_t* x3b    = (bf16_t*)carve((size_t)N * 768 * 2);
    bf16_t* Wt2    = (bf16_t*)carve((size_t)256 * 256 * 2);
    bf16_t* Wt3    = (bf16_t*)carve((size_t)256 * 768 * 2);
    float*  al     = (float*)carve((size_t)N * 12 * 4);
    float*  ar     = (float*)carve((size_t)N * 12 * 4);
    float*  alphab = (float*)carve((size_t)Etot * 12 * 4);
    int*    rowptr = (int*)carve((size_t)(N + 1) * 4);
    int*    cnt2   = (int*)carve((size_t)(2 * N) * 4);   // counts | cursor contiguous
    int*    counts = cnt2;
    int*    cursor = cnt2 + N;
    int*    esrc   = (int*)carve((size_t)Etot * 4);
    (void)ws_size;

    float* out1 = (float*)d_out;
    float* out2 = (float*)d_out + N;

    const int TB = 256;
    int eb = (Etot + TB - 1) / TB;
    int nodeblocks = (N + 3) / 4;          // 4 node-waves per block

    // --- CSR by dst + weight prep ---
    zero_i32<<<(2 * N + TB - 1) / TB, TB, 0, stream>>>(cnt2, 2 * N);
    count_edges<<<eb, TB, 0, stream>>>(ei, E, N, counts);
    scan_rowptr<<<1, 1024, 0, stream>>>(counts, rowptr, N);
    fill_edges<<<eb, TB, 0, stream>>>(ei, E, N, rowptr, cursor, esrc);
    transpose_cast2<<<dim3(16, 64), TB, 0, stream>>>(W2, Wt2, W3, Wt3);

    // --- layer 1: 16 -> 8x32 ---
    gemm_f32_bf16<<<dim3(4, (N + 63) / 64), TB, 0, stream>>>(x, W1, hbuf, N, 16, 256);
    gat_scores<8, 32><<<(N * 8 + TB - 1) / TB, TB, 0, stream>>>(hbuf, a1s, a1d, al, ar, N);
    alpha_node<8><<<nodeblocks, TB, 0, stream>>>(al, ar, rowptr, esrc, alphab, N, Etot);
    gat_agg<256, 32><<<2 * nodeblocks, TB, 0, stream>>>(hbuf, alphab, rowptr, esrc, b1, x1b, N, Etot, nodeblocks);

    // --- layer 2: 256 -> 8x32 (MFMA) ---
    gemm_mfma<<<dim3(4, (N + 127) / 128), TB, 0, stream>>>(x1b, Wt2, hbuf, N, 256, 256);
    gat_scores<8, 32><<<(N * 8 + TB - 1) / TB, TB, 0, stream>>>(hbuf, a2s, a2d, al, ar, N);
    alpha_node<8><<<nodeblocks, TB, 0, stream>>>(al, ar, rowptr, esrc, alphab, N, Etot);
    gat_agg<256, 32><<<2 * nodeblocks, TB, 0, stream>>>(hbuf, alphab, rowptr, esrc, b2, x2b, N, Etot, nodeblocks);

    // --- layer 3: 256 -> 12x64 (MFMA) ---
    gemm_mfma<<<dim3(12, (N + 127) / 128), TB, 0, stream>>>(x2b, Wt3, hbuf, N, 256, 768);
    gat_scores<12, 64><<<(N * 12 + TB - 1) / TB, TB, 0, stream>>>(hbuf, a3s, a3d, al, ar, N);
    alpha_node<12><<<nodeblocks, TB, 0, stream>>>(al, ar, rowptr, esrc, alphab, N, Etot);
    gat_agg<768, 64><<<6 * nodeblocks, TB, 0, stream>>>(hbuf, alphab, rowptr, esrc, b3, x3b, N, Etot, nodeblocks);

    // --- fused final linear + MLP ---
    head_fused<<<nodeblocks, TB, 0, stream>>>(x, x1b, x2b, x3b, Wf, bf,
                                              M1w, M1b, M2w, M2b, M3w, M3b, out1, out2, N);
}

// Round 8
// 349.450 us; speedup vs baseline: 1.5813x; 1.0210x over previous
//
#include <hip/hip_runtime.h>
#include <math.h>

// ---------------------------------------------------------------------------
// GATNet (3x GATConv + final linear + MLP), MI355X.
// R7: agg v5 — software-pipelined gather loop (depth-2: idx+gathers for the
// next 8-edge pack issued while accumulating the current pack), stride-4
// guarded tail. Carried: MFMA GEMMs, alpha v2, L2-sliced groups, all-bf16
// activations, fused head, fused weight transpose.
// ---------------------------------------------------------------------------

typedef unsigned short bf16_t;
typedef __attribute__((ext_vector_type(8))) short bf16x8;
typedef __attribute__((ext_vector_type(4))) float f32x4;

__device__ inline float bf2f(bf16_t u) {
    union { unsigned int i; float f; } v; v.i = ((unsigned int)u) << 16; return v.f;
}
__device__ inline float u2f(unsigned int x) {
    union { unsigned int i; float f; } v; v.i = x; return v.f;
}
__device__ inline bf16_t f2bf(float f) {
    union { float f; unsigned int i; } v; v.f = f;
    unsigned int r = v.i + 0x7FFF + ((v.i >> 16) & 1);   // round-nearest-even
    return (bf16_t)(r >> 16);
}

// ------------------------------ CSR build ----------------------------------

__global__ void zero_i32(int* p, int n) {
    int i = blockIdx.x * blockDim.x + threadIdx.x;
    if (i < n) p[i] = 0;
}

__global__ void count_edges(const int* __restrict__ ei, int E, int Nn,
                            int* __restrict__ counts) {
    int e = blockIdx.x * blockDim.x + threadIdx.x;
    if (e >= E + Nn) return;
    int dst = (e < E) ? ei[E + e] : (e - E);   // self-loops appended
    atomicAdd(&counts[dst], 1);
}

// single block, 1024 threads: serial-per-thread + shuffle block scan
__global__ __launch_bounds__(1024) void scan_rowptr(const int* __restrict__ counts,
                                                    int* __restrict__ rowptr, int n) {
    const int IPT = (n + 1023) / 1024;   // <=16
    int t = threadIdx.x;
    int base = t * IPT;
    int loc[16];
    int run = 0;
#pragma unroll
    for (int i = 0; i < 16; i++) {
        if (i >= IPT) break;
        int idx = base + i;
        int v = (idx < n) ? counts[idx] : 0;
        loc[i] = run;
        run += v;
    }
    int lane = t & 63, wid = t >> 6;
    int v = run;
    for (int off = 1; off < 64; off <<= 1) {
        int u = __shfl_up(v, off, 64);
        if (lane >= off) v += u;
    }
    __shared__ int wsum[16];
    __shared__ int woff[16];
    if (lane == 63) wsum[wid] = v;
    __syncthreads();
    if (t == 0) { int s = 0; for (int i = 0; i < 16; i++) { woff[i] = s; s += wsum[i]; } }
    __syncthreads();
    int excl = v - run + woff[wid];
#pragma unroll
    for (int i = 0; i < 16; i++) {
        if (i >= IPT) break;
        int idx = base + i;
        if (idx < n) rowptr[idx] = excl + loc[i];
    }
    if (t == 1023) rowptr[n] = excl + run;
}

__global__ void fill_edges(const int* __restrict__ ei, int E, int Nn,
                           const int* __restrict__ rowptr, int* __restrict__ cursor,
                           int* __restrict__ edge_src) {
    int e = blockIdx.x * blockDim.x + threadIdx.x;
    if (e >= E + Nn) return;
    int src, dst;
    if (e < E) { src = ei[e]; dst = ei[E + e]; }
    else       { src = e - E; dst = src; }
    int pos = atomicAdd(&cursor[dst], 1);
    edge_src[rowptr[dst] + pos] = src;
}

// ---------------------------------------------------------------------------
// Fused transpose+cast for both weight matrices (K=256 each).
// ---------------------------------------------------------------------------
__global__ __launch_bounds__(256) void transpose_cast2(const float* __restrict__ W2,
                                                       bf16_t* __restrict__ Wt2,
                                                       const float* __restrict__ W3,
                                                       bf16_t* __restrict__ Wt3) {
    __shared__ float tile[16][17];
    const float* W; bf16_t* Wt; int Nc, n0;
    if (blockIdx.y < 16) { W = W2; Wt = Wt2; Nc = 256; n0 = blockIdx.y * 16; }
    else                 { W = W3; Wt = Wt3; Nc = 768; n0 = (blockIdx.y - 16) * 16; }
    int k0 = blockIdx.x * 16;
    int tx = threadIdx.x & 15, ty = threadIdx.x >> 4;
    tile[ty][tx] = W[(size_t)(k0 + ty) * Nc + n0 + tx];
    __syncthreads();
    Wt[(size_t)(n0 + ty) * 256 + k0 + tx] = f2bf(tile[tx][ty]);
}

// ---------------------------------------------------------------------------
// fp32 GEMM (layer 1, K=16), bf16 out.
// ---------------------------------------------------------------------------
__global__ __launch_bounds__(256) void gemm_f32_bf16(const float* __restrict__ A,
                                                     const float* __restrict__ B,
                                                     bf16_t* __restrict__ Cm,
                                                     int M, int K, int Nc) {
    __shared__ float As[16][64];
    __shared__ float Bs[16][64];
    int t  = threadIdx.x;
    int tx = t & 15, ty = t >> 4;
    int row0 = blockIdx.y * 64, col0 = blockIdx.x * 64;
    int a_r = t >> 2, a_c = (t & 3) * 4;
    int b_r = t >> 4, b_c = (t & 15) * 4;

    float acc[4][4];
#pragma unroll
    for (int i = 0; i < 4; i++)
#pragma unroll
        for (int j = 0; j < 4; j++) acc[i][j] = 0.f;

    for (int kt = 0; kt < K; kt += 16) {
        float4 av = make_float4(0.f, 0.f, 0.f, 0.f);
        int gr = row0 + a_r;
        if (gr < M) av = *(const float4*)(A + (size_t)gr * K + kt + a_c);
        As[a_c + 0][a_r] = av.x;
        As[a_c + 1][a_r] = av.y;
        As[a_c + 2][a_r] = av.z;
        As[a_c + 3][a_r] = av.w;
        float4 bv = *(const float4*)(B + (size_t)(kt + b_r) * Nc + col0 + b_c);
        *(float4*)&Bs[b_r][b_c] = bv;
        __syncthreads();
#pragma unroll
        for (int k = 0; k < 16; k++) {
            float4 a4 = *(const float4*)&As[k][ty * 4];
            float4 b4 = *(const float4*)&Bs[k][tx * 4];
            float aa[4] = {a4.x, a4.y, a4.z, a4.w};
            float bb[4] = {b4.x, b4.y, b4.z, b4.w};
#pragma unroll
            for (int i = 0; i < 4; i++)
#pragma unroll
                for (int j = 0; j < 4; j++) acc[i][j] += aa[i] * bb[j];
        }
        __syncthreads();
    }
#pragma unroll
    for (int i = 0; i < 4; i++) {
        int gr = row0 + ty * 4 + i;
        if (gr < M) {
            ushort4 v;
            v.x = f2bf(acc[i][0]); v.y = f2bf(acc[i][1]);
            v.z = f2bf(acc[i][2]); v.w = f2bf(acc[i][3]);
            *(ushort4*)(Cm + (size_t)gr * Nc + col0 + tx * 4) = v;
        }
    }
}

// ---------------------------------------------------------------------------
// MFMA bf16 GEMM (layers 2/3): C = A[M,K] @ Bt[Nc,K]^T, frags from global.
// ---------------------------------------------------------------------------
__global__ __launch_bounds__(256) void gemm_mfma(const bf16_t* __restrict__ A,
                                                 const bf16_t* __restrict__ Bt,
                                                 bf16_t* __restrict__ Cm,
                                                 int M, int K, int Nc) {
    int wave = threadIdx.x >> 6, lane = threadIdx.x & 63;
    int quad = lane >> 4, l16 = lane & 15;
    int m0 = blockIdx.y * 128 + wave * 32;
    int n0 = blockIdx.x * 64;

    f32x4 acc[2][4];
    f32x4 z = {0.f, 0.f, 0.f, 0.f};
#pragma unroll
    for (int i = 0; i < 2; i++)
#pragma unroll
        for (int j = 0; j < 4; j++) acc[i][j] = z;

    int r0 = m0 + l16;       if (r0 >= M) r0 = M - 1;
    int r1 = m0 + 16 + l16;  if (r1 >= M) r1 = M - 1;
    const bf16_t* Ap0 = A + (size_t)r0 * K + quad * 8;
    const bf16_t* Ap1 = A + (size_t)r1 * K + quad * 8;
    const bf16_t* Bp0 = Bt + (size_t)(n0 + 0  + l16) * K + quad * 8;
    const bf16_t* Bp1 = Bt + (size_t)(n0 + 16 + l16) * K + quad * 8;
    const bf16_t* Bp2 = Bt + (size_t)(n0 + 32 + l16) * K + quad * 8;
    const bf16_t* Bp3 = Bt + (size_t)(n0 + 48 + l16) * K + quad * 8;

    for (int kt = 0; kt < K; kt += 32) {
        bf16x8 a0 = *(const bf16x8*)(Ap0 + kt);
        bf16x8 a1 = *(const bf16x8*)(Ap1 + kt);
        bf16x8 b0 = *(const bf16x8*)(Bp0 + kt);
        bf16x8 b1 = *(const bf16x8*)(Bp1 + kt);
        bf16x8 b2 = *(const bf16x8*)(Bp2 + kt);
        bf16x8 b3 = *(const bf16x8*)(Bp3 + kt);
        acc[0][0] = __builtin_amdgcn_mfma_f32_16x16x32_bf16(a0, b0, acc[0][0], 0, 0, 0);
        acc[1][0] = __builtin_amdgcn_mfma_f32_16x16x32_bf16(a1, b0, acc[1][0], 0, 0, 0);
        acc[0][1] = __builtin_amdgcn_mfma_f32_16x16x32_bf16(a0, b1, acc[0][1], 0, 0, 0);
        acc[1][1] = __builtin_amdgcn_mfma_f32_16x16x32_bf16(a1, b1, acc[1][1], 0, 0, 0);
        acc[0][2] = __builtin_amdgcn_mfma_f32_16x16x32_bf16(a0, b2, acc[0][2], 0, 0, 0);
        acc[1][2] = __builtin_amdgcn_mfma_f32_16x16x32_bf16(a1, b2, acc[1][2], 0, 0, 0);
        acc[0][3] = __builtin_amdgcn_mfma_f32_16x16x32_bf16(a0, b3, acc[0][3], 0, 0, 0);
        acc[1][3] = __builtin_amdgcn_mfma_f32_16x16x32_bf16(a1, b3, acc[1][3], 0, 0, 0);
    }
#pragma unroll
    for (int i = 0; i < 2; i++)
#pragma unroll
        for (int j = 0; j < 4; j++)
#pragma unroll
            for (int r = 0; r < 4; r++) {
                int gr = m0 + i * 16 + quad * 4 + r;
                if (gr < M) Cm[(size_t)gr * Nc + n0 + j * 16 + l16] = f2bf(acc[i][j][r]);
            }
}

// ---------------------------------------------------------------------------
// Per-(node,head) attention scores from bf16 h.
// ---------------------------------------------------------------------------
template <int H, int C>
__global__ void gat_scores(const bf16_t* __restrict__ hbuf, const float* __restrict__ a_s,
                           const float* __restrict__ a_d, float* __restrict__ al,
                           float* __restrict__ ar, int n) {
    int i = blockIdx.x * blockDim.x + threadIdx.x;
    if (i >= n * H) return;
    int node = i / H, h = i - node * H;
    const bf16_t* hr = hbuf + (size_t)node * (H * C) + h * C;
    const float* as_ = a_s + h * C;
    const float* ad_ = a_d + h * C;
    float sa = 0.f, sd = 0.f;
#pragma unroll
    for (int c = 0; c < C; c += 4) {
        ushort4 u = *(const ushort4*)(hr + c);
        float v0 = bf2f(u.x), v1 = bf2f(u.y), v2 = bf2f(u.z), v3 = bf2f(u.w);
        sa += v0 * as_[c] + v1 * as_[c + 1] + v2 * as_[c + 2] + v3 * as_[c + 3];
        sd += v0 * ad_[c] + v1 * ad_[c + 1] + v2 * ad_[c + 2] + v3 * ad_[c + 3];
    }
    al[i] = sa;
    ar[i] = sd;
}

// ---------------------------------------------------------------------------
// alpha v2: wave per node, ALL heads; row-contiguous al reads; register p
// for deg<=128, guarded tail beyond; per-head shuffle reduce; planar stores.
// ---------------------------------------------------------------------------
template <int H>
__global__ __launch_bounds__(256) void alpha_node(const float* __restrict__ al,
                                                  const float* __restrict__ ar,
                                                  const int* __restrict__ rowptr,
                                                  const int* __restrict__ esrc,
                                                  float* __restrict__ alpha,
                                                  int n, int Etot) {
    int node = (blockIdx.x * blockDim.x + threadIdx.x) >> 6;
    if (node >= n) return;
    int lane = threadIdx.x & 63;

    float arv[H];
#pragma unroll
    for (int h4 = 0; h4 < H; h4 += 4) {
        float4 t = *(const float4*)(ar + (size_t)node * H + h4);
        arv[h4] = t.x; arv[h4 + 1] = t.y; arv[h4 + 2] = t.z; arv[h4 + 3] = t.w;
    }
    int beg = rowptr[node], end = rowptr[node + 1];
    float p0[H], p1[H], s[H];
#pragma unroll
    for (int h = 0; h < H; h++) { p0[h] = 0.f; p1[h] = 0.f; s[h] = 0.f; }

    int j0 = beg + lane;
    if (j0 < end) {
        const float* alr = al + (size_t)esrc[j0] * H;
#pragma unroll
        for (int h4 = 0; h4 < H; h4 += 4) {
            float4 t = *(const float4*)(alr + h4);
            float e;
            e = t.x + arv[h4];     e = fmaxf(e, 0.2f * e); p0[h4]     = __expf(fminf(e, 60.f));
            e = t.y + arv[h4 + 1]; e = fmaxf(e, 0.2f * e); p0[h4 + 1] = __expf(fminf(e, 60.f));
            e = t.z + arv[h4 + 2]; e = fmaxf(e, 0.2f * e); p0[h4 + 2] = __expf(fminf(e, 60.f));
            e = t.w + arv[h4 + 3]; e = fmaxf(e, 0.2f * e); p0[h4 + 3] = __expf(fminf(e, 60.f));
        }
#pragma unroll
        for (int h = 0; h < H; h++) s[h] += p0[h];
    }
    int j1 = j0 + 64;
    if (j1 < end) {
        const float* alr = al + (size_t)esrc[j1] * H;
#pragma unroll
        for (int h4 = 0; h4 < H; h4 += 4) {
            float4 t = *(const float4*)(alr + h4);
            float e;
            e = t.x + arv[h4];     e = fmaxf(e, 0.2f * e); p1[h4]     = __expf(fminf(e, 60.f));
            e = t.y + arv[h4 + 1]; e = fmaxf(e, 0.2f * e); p1[h4 + 1] = __expf(fminf(e, 60.f));
            e = t.z + arv[h4 + 2]; e = fmaxf(e, 0.2f * e); p1[h4 + 2] = __expf(fminf(e, 60.f));
            e = t.w + arv[h4 + 3]; e = fmaxf(e, 0.2f * e); p1[h4 + 3] = __expf(fminf(e, 60.f));
        }
#pragma unroll
        for (int h = 0; h < H; h++) s[h] += p1[h];
    }
    for (int j = j0 + 128; j < end; j += 64) {
        const float* alr = al + (size_t)esrc[j] * H;
#pragma unroll
        for (int h = 0; h < H; h++) {
            float e = alr[h] + arv[h];
            e = fmaxf(e, 0.2f * e);
            float p = __expf(fminf(e, 60.f));
            alpha[(size_t)h * Etot + j] = p;
            s[h] += p;
        }
    }
#pragma unroll
    for (int h = 0; h < H; h++) {
        float v = s[h];
#pragma unroll
        for (int off = 32; off > 0; off >>= 1) v += __shfl_xor(v, off, 64);
        s[h] = 1.f / v;
    }
    if (j0 < end) {
#pragma unroll
        for (int h = 0; h < H; h++) alpha[(size_t)h * Etot + j0] = p0[h] * s[h];
    }
    if (j1 < end) {
#pragma unroll
        for (int h = 0; h < H; h++) alpha[(size_t)h * Etot + j1] = p1[h] * s[h];
    }
    for (int j = j0 + 128; j < end; j += 64) {
#pragma unroll
        for (int h = 0; h < H; h++) alpha[(size_t)h * Etot + j] *= s[h];
    }
}

// ---------------------------------------------------------------------------
// agg v5: wave per (node, 128-ch group); lane = (sub 0..3, slot 0..15),
// 16 B/lane gathers. Software-pipelined 8-edge main loop: next pack's
// esrc/alpha/gathers issued while accumulating the current pack (depth 2,
// 4 gathers in flight). Guarded stride-4 tail. Cross-sub shuffle reduce.
// ---------------------------------------------------------------------------
template <int HC_, int C>
__global__ __launch_bounds__(256) void gat_agg(
    const bf16_t* __restrict__ hbuf, const float* __restrict__ alpha,
    const int* __restrict__ rowptr, const int* __restrict__ esrc,
    const float* __restrict__ bias, bf16_t* __restrict__ outb,
    int n, int Etot, int nodeblocks) {
    int group = blockIdx.x / nodeblocks;
    int nb    = blockIdx.x - group * nodeblocks;
    int node  = nb * 4 + (threadIdx.x >> 6);
    if (node >= n) return;
    int lane = threadIdx.x & 63;
    int sub  = lane >> 4;          // edge slot 0..3
    int cl   = lane & 15;          // channel slot 0..15
    int gc   = group * 128 + cl * 8;
    int head = gc / C;
    const bf16_t* hb = hbuf + gc;
    const float*  ap = alpha + (size_t)head * Etot;

    float acc[8];
#pragma unroll
    for (int i = 0; i < 8; i++) acc[i] = 0.f;

    int beg = rowptr[node], end = rowptr[node + 1];
    int deg = end - beg;
    int j = beg + sub;
    int nfull = deg >> 3;          // 8-edge packs

    if (nfull > 0) {
        // prologue: pack 0 in flight
        int s0 = esrc[j], s1 = esrc[j + 4];
        float a0 = ap[j], a1 = ap[j + 4];
        bf16x8 u0 = *(const bf16x8*)(hb + (size_t)s0 * HC_);
        bf16x8 u1 = *(const bf16x8*)(hb + (size_t)s1 * HC_);
        j += 8;
        for (int it = 1; it < nfull; ++it, j += 8) {
            // issue next pack's idx/alpha/gathers
            int t0 = esrc[j], t1 = esrc[j + 4];
            float b0 = ap[j], b1 = ap[j + 4];
            bf16x8 v0 = *(const bf16x8*)(hb + (size_t)t0 * HC_);
            bf16x8 v1 = *(const bf16x8*)(hb + (size_t)t1 * HC_);
            // accumulate current pack (overlaps with v/t in flight)
            const unsigned int* d0 = (const unsigned int*)&u0;
            const unsigned int* d1 = (const unsigned int*)&u1;
#pragma unroll
            for (int i = 0; i < 4; i++) {
                acc[2 * i]     += a0 * u2f(d0[i] << 16);
                acc[2 * i + 1] += a0 * u2f(d0[i] & 0xffff0000u);
                acc[2 * i]     += a1 * u2f(d1[i] << 16);
                acc[2 * i + 1] += a1 * u2f(d1[i] & 0xffff0000u);
            }
            u0 = v0; u1 = v1; a0 = b0; a1 = b1;
        }
        // drain
        const unsigned int* d0 = (const unsigned int*)&u0;
        const unsigned int* d1 = (const unsigned int*)&u1;
#pragma unroll
        for (int i = 0; i < 4; i++) {
            acc[2 * i]     += a0 * u2f(d0[i] << 16);
            acc[2 * i + 1] += a0 * u2f(d0[i] & 0xffff0000u);
            acc[2 * i]     += a1 * u2f(d1[i] << 16);
            acc[2 * i + 1] += a1 * u2f(d1[i] & 0xffff0000u);
        }
    }
    // tail (deg & 7 edges), stride 4, guarded
    for (; j < end; j += 4) {
        int s0 = esrc[j];
        float a0 = ap[j];
        bf16x8 u0 = *(const bf16x8*)(hb + (size_t)s0 * HC_);
        const unsigned int* d0 = (const unsigned int*)&u0;
#pragma unroll
        for (int i = 0; i < 4; i++) {
            acc[2 * i]     += a0 * u2f(d0[i] << 16);
            acc[2 * i + 1] += a0 * u2f(d0[i] & 0xffff0000u);
        }
    }
#pragma unroll
    for (int i = 0; i < 8; i++) {
        acc[i] += __shfl_xor(acc[i], 16, 64);
        acc[i] += __shfl_xor(acc[i], 32, 64);
    }
    if (sub == 0) {
        float4 b0 = *(const float4*)(bias + gc);
        float4 b1 = *(const float4*)(bias + gc + 4);
        float bb[8] = {b0.x, b0.y, b0.z, b0.w, b1.x, b1.y, b1.z, b1.w};
        bf16x8 outv;
        unsigned short* ov = (unsigned short*)&outv;
#pragma unroll
        for (int i = 0; i < 8; i++) ov[i] = f2bf(fmaxf(acc[i] + bb[i], 0.f));
        *(bf16x8*)(outb + (size_t)node * HC_ + gc) = outv;
    }
}

// ---------------------------------------------------------------------------
// Fused head: out1 = sigmoid(concat(x1,x2,x3).Wf + bf); then MLP -> out2.
// ---------------------------------------------------------------------------
__global__ __launch_bounds__(256) void head_fused(
    const float* __restrict__ x, const bf16_t* __restrict__ x1b,
    const bf16_t* __restrict__ x2b, const bf16_t* __restrict__ x3b,
    const float* __restrict__ Wf, const float* __restrict__ bfc,
    const float* __restrict__ M1w, const float* __restrict__ M1b,
    const float* __restrict__ M2w, const float* __restrict__ M2b,
    const float* __restrict__ M3w, const float* __restrict__ M3b,
    float* __restrict__ out1, float* __restrict__ out2, int n) {
    __shared__ float h1s[4][128];
    int w    = threadIdx.x >> 6;
    int lane = threadIdx.x & 63;
    int node = blockIdx.x * 4 + w;
    bool valid = node < n;
    int nd = valid ? node : 0;

    float s = 0.f;
    {
        ushort4 u = *(const ushort4*)(x1b + (size_t)nd * 256 + lane * 4);
        const float* wv = Wf + lane * 4;
        s += bf2f(u.x) * wv[0] + bf2f(u.y) * wv[1] + bf2f(u.z) * wv[2] + bf2f(u.w) * wv[3];
    }
    {
        ushort4 u = *(const ushort4*)(x2b + (size_t)nd * 256 + lane * 4);
        const float* wv = Wf + 256 + lane * 4;
        s += bf2f(u.x) * wv[0] + bf2f(u.y) * wv[1] + bf2f(u.z) * wv[2] + bf2f(u.w) * wv[3];
    }
#pragma unroll
    for (int i = 0; i < 3; i++) {
        int k = i * 256 + lane * 4;
        ushort4 u = *(const ushort4*)(x3b + (size_t)nd * 768 + k);
        const float* wv = Wf + 512 + k;
        s += bf2f(u.x) * wv[0] + bf2f(u.y) * wv[1] + bf2f(u.z) * wv[2] + bf2f(u.w) * wv[3];
    }
#pragma unroll
    for (int off = 32; off > 0; off >>= 1) s += __shfl_xor(s, off, 64);
    float so = 1.f / (1.f + __expf(-(s + bfc[0])));
    if (lane == 0 && valid) out1[node] = so;

    float xm[17];
#pragma unroll
    for (int k = 0; k < 16; k++) xm[k] = x[nd * 16 + k];
    xm[16] = so;

    float a0 = M1b[lane], a1 = M1b[lane + 64];
#pragma unroll
    for (int k = 0; k < 17; k++) {
        a0 += xm[k] * M1w[k * 128 + lane];
        a1 += xm[k] * M1w[k * 128 + lane + 64];
    }
    h1s[w][lane]      = fmaxf(a0, 0.f);
    h1s[w][lane + 64] = fmaxf(a1, 0.f);
    __syncthreads();

    float b0 = M2b[lane];
#pragma unroll 16
    for (int k = 0; k < 128; k++) b0 += h1s[w][k] * M2w[k * 64 + lane];
    b0 = fmaxf(b0, 0.f);

    float p = b0 * M3w[lane];
#pragma unroll
    for (int off = 32; off > 0; off >>= 1) p += __shfl_xor(p, off, 64);
    if (lane == 0 && valid) out2[node] = 1.f / (1.f + __expf(-(p + M3b[0])));
}

// ---------------------------------------------------------------------------
extern "C" void kernel_launch(void* const* d_in, const int* in_sizes, int n_in,
                              void* d_out, int out_size, void* d_ws, size_t ws_size,
                              hipStream_t stream) {
    const float* x   = (const float*)d_in[0];
    const int*   ei  = (const int*)d_in[1];
    const float* W1  = (const float*)d_in[3];
    const float* a1s = (const float*)d_in[4];
    const float* a1d = (const float*)d_in[5];
    const float* b1  = (const float*)d_in[6];
    const float* W2  = (const float*)d_in[7];
    const float* a2s = (const float*)d_in[8];
    const float* a2d = (const float*)d_in[9];
    const float* b2  = (const float*)d_in[10];
    const float* W3  = (const float*)d_in[11];
    const float* a3s = (const float*)d_in[12];
    const float* a3d = (const float*)d_in[13];
    const float* b3  = (const float*)d_in[14];
    const float* Wf  = (const float*)d_in[15];
    const float* bf  = (const float*)d_in[16];
    const float* M1w = (const float*)d_in[17];
    const float* M1b = (const float*)d_in[18];
    const float* M2w = (const float*)d_in[19];
    const float* M2b = (const float*)d_in[20];
    const float* M3w = (const float*)d_in[21];
    const float* M3b = (const float*)d_in[22];

    const int N = in_sizes[0] / 16;        // 10000
    const int E = in_sizes[1] / 2;         // 320000
    const int Etot = E + N;

    char* base = (char*)d_ws;
    size_t off = 0;
    auto carve = [&](size_t bytes) {
        char* p = base + off;
        off = (off + bytes + 255) & ~(size_t)255;
        return p;
    };
    bf16_t* hbuf   = (bf16_t*)carve((size_t)N * 768 * 2);
    bf16_t* x1b    = (bf16_t*)carve((size_t)N * 256 * 2);
    bf16_t* x2b    = (bf16_t*)carve((size_t)N * 256 * 2);
    bf16_t* x3b    = (bf16_t*)carve((size_t)N * 768 * 2);
    bf16_t* Wt2    = (bf16_t*)carve((size_t)256 * 256 * 2);
    bf16_t* Wt3    = (bf16_t*)carve((size_t)256 * 768 * 2);
    float*  al     = (float*)carve((size_t)N * 12 * 4);
    float*  ar     = (float*)carve((size_t)N * 12 * 4);
    float*  alphab = (float*)carve((size_t)Etot * 12 * 4);
    int*    rowptr = (int*)carve((size_t)(N + 1) * 4);
    int*    cnt2   = (int*)carve((size_t)(2 * N) * 4);   // counts | cursor contiguous
    int*    counts = cnt2;
    int*    cursor = cnt2 + N;
    int*    esrc   = (int*)carve((size_t)Etot * 4);
    (void)ws_size;

    float* out1 = (float*)d_out;
    float* out2 = (float*)d_out + N;

    const int TB = 256;
    int eb = (Etot + TB - 1) / TB;
    int nodeblocks = (N + 3) / 4;          // 4 node-waves per block

    // --- CSR by dst + weight prep ---
    zero_i32<<<(2 * N + TB - 1) / TB, TB, 0, stream>>>(cnt2, 2 * N);
    count_edges<<<eb, TB, 0, stream>>>(ei, E, N, counts);
    scan_rowptr<<<1, 1024, 0, stream>>>(counts, rowptr, N);
    fill_edges<<<eb, TB, 0, stream>>>(ei, E, N, rowptr, cursor, esrc);
    transpose_cast2<<<dim3(16, 64), TB, 0, stream>>>(W2, Wt2, W3, Wt3);

    // --- layer 1: 16 -> 8x32 ---
    gemm_f32_bf16<<<dim3(4, (N + 63) / 64), TB, 0, stream>>>(x, W1, hbuf, N, 16, 256);
    gat_scores<8, 32><<<(N * 8 + TB - 1) / TB, TB, 0, stream>>>(hbuf, a1s, a1d, al, ar, N);
    alpha_node<8><<<nodeblocks, TB, 0, stream>>>(al, ar, rowptr, esrc, alphab, N, Etot);
    gat_agg<256, 32><<<2 * nodeblocks, TB, 0, stream>>>(hbuf, alphab, rowptr, esrc, b1, x1b, N, Etot, nodeblocks);

    // --- layer 2: 256 -> 8x32 (MFMA) ---
    gemm_mfma<<<dim3(4, (N + 127) / 128), TB, 0, stream>>>(x1b, Wt2, hbuf, N, 256, 256);
    gat_scores<8, 32><<<(N * 8 + TB - 1) / TB, TB, 0, stream>>>(hbuf, a2s, a2d, al, ar, N);
    alpha_node<8><<<nodeblocks, TB, 0, stream>>>(al, ar, rowptr, esrc, alphab, N, Etot);
    gat_agg<256, 32><<<2 * nodeblocks, TB, 0, stream>>>(hbuf, alphab, rowptr, esrc, b2, x2b, N, Etot, nodeblocks);

    // --- layer 3: 256 -> 12x64 (MFMA) ---
    gemm_mfma<<<dim3(12, (N + 127) / 128), TB, 0, stream>>>(x2b, Wt3, hbuf, N, 256, 768);
    gat_scores<12, 64><<<(N * 12 + TB - 1) / TB, TB, 0, stream>>>(hbuf, a3s, a3d, al, ar, N);
    alpha_node<12><<<nodeblocks, TB, 0, stream>>>(al, ar, rowptr, esrc, alphab, N, Etot);
    gat_agg<768, 64><<<6 * nodeblocks, TB, 0, stream>>>(hbuf, alphab, rowptr, esrc, b3, x3b, N, Etot, nodeblocks);

    // --- fused final linear + MLP ---
    head_fused<<<nodeblocks, TB, 0, stream>>>(x, x1b, x2b, x3b, Wf, bf,
                                              M1w, M1b, M2w, M2b, M3w, M3b, out1, out2, N);
}

// Round 9
// 348.032 us; speedup vs baseline: 1.5878x; 1.0041x over previous
//
#include <hip/hip_runtime.h>
#include <math.h>

// ---------------------------------------------------------------------------
// GATNet (3x GATConv + final linear + MLP), MI355X.
// R8: agg v6 — edge indices preloaded into registers (2 coalesced loads,
// deg<=128) and distributed via ds_bpermute shuffles, removing the
// esrc-load -> gather serial chain; depth-2 gather pipeline kept.
// Carried: MFMA GEMMs, alpha v2, L2-sliced groups, all-bf16, fused head.
// ---------------------------------------------------------------------------

typedef unsigned short bf16_t;
typedef __attribute__((ext_vector_type(8))) short bf16x8;
typedef __attribute__((ext_vector_type(4))) float f32x4;

__device__ inline float bf2f(bf16_t u) {
    union { unsigned int i; float f; } v; v.i = ((unsigned int)u) << 16; return v.f;
}
__device__ inline float u2f(unsigned int x) {
    union { unsigned int i; float f; } v; v.i = x; return v.f;
}
__device__ inline bf16_t f2bf(float f) {
    union { float f; unsigned int i; } v; v.f = f;
    unsigned int r = v.i + 0x7FFF + ((v.i >> 16) & 1);   // round-nearest-even
    return (bf16_t)(r >> 16);
}

// ------------------------------ CSR build ----------------------------------

__global__ void zero_i32(int* p, int n) {
    int i = blockIdx.x * blockDim.x + threadIdx.x;
    if (i < n) p[i] = 0;
}

__global__ void count_edges(const int* __restrict__ ei, int E, int Nn,
                            int* __restrict__ counts) {
    int e = blockIdx.x * blockDim.x + threadIdx.x;
    if (e >= E + Nn) return;
    int dst = (e < E) ? ei[E + e] : (e - E);   // self-loops appended
    atomicAdd(&counts[dst], 1);
}

// single block, 1024 threads: serial-per-thread + shuffle block scan
__global__ __launch_bounds__(1024) void scan_rowptr(const int* __restrict__ counts,
                                                    int* __restrict__ rowptr, int n) {
    const int IPT = (n + 1023) / 1024;   // <=16
    int t = threadIdx.x;
    int base = t * IPT;
    int loc[16];
    int run = 0;
#pragma unroll
    for (int i = 0; i < 16; i++) {
        if (i >= IPT) break;
        int idx = base + i;
        int v = (idx < n) ? counts[idx] : 0;
        loc[i] = run;
        run += v;
    }
    int lane = t & 63, wid = t >> 6;
    int v = run;
    for (int off = 1; off < 64; off <<= 1) {
        int u = __shfl_up(v, off, 64);
        if (lane >= off) v += u;
    }
    __shared__ int wsum[16];
    __shared__ int woff[16];
    if (lane == 63) wsum[wid] = v;
    __syncthreads();
    if (t == 0) { int s = 0; for (int i = 0; i < 16; i++) { woff[i] = s; s += wsum[i]; } }
    __syncthreads();
    int excl = v - run + woff[wid];
#pragma unroll
    for (int i = 0; i < 16; i++) {
        if (i >= IPT) break;
        int idx = base + i;
        if (idx < n) rowptr[idx] = excl + loc[i];
    }
    if (t == 1023) rowptr[n] = excl + run;
}

__global__ void fill_edges(const int* __restrict__ ei, int E, int Nn,
                           const int* __restrict__ rowptr, int* __restrict__ cursor,
                           int* __restrict__ edge_src) {
    int e = blockIdx.x * blockDim.x + threadIdx.x;
    if (e >= E + Nn) return;
    int src, dst;
    if (e < E) { src = ei[e]; dst = ei[E + e]; }
    else       { src = e - E; dst = src; }
    int pos = atomicAdd(&cursor[dst], 1);
    edge_src[rowptr[dst] + pos] = src;
}

// ---------------------------------------------------------------------------
// Fused transpose+cast for both weight matrices (K=256 each).
// ---------------------------------------------------------------------------
__global__ __launch_bounds__(256) void transpose_cast2(const float* __restrict__ W2,
                                                       bf16_t* __restrict__ Wt2,
                                                       const float* __restrict__ W3,
                                                       bf16_t* __restrict__ Wt3) {
    __shared__ float tile[16][17];
    const float* W; bf16_t* Wt; int Nc, n0;
    if (blockIdx.y < 16) { W = W2; Wt = Wt2; Nc = 256; n0 = blockIdx.y * 16; }
    else                 { W = W3; Wt = Wt3; Nc = 768; n0 = (blockIdx.y - 16) * 16; }
    int k0 = blockIdx.x * 16;
    int tx = threadIdx.x & 15, ty = threadIdx.x >> 4;
    tile[ty][tx] = W[(size_t)(k0 + ty) * Nc + n0 + tx];
    __syncthreads();
    Wt[(size_t)(n0 + ty) * 256 + k0 + tx] = f2bf(tile[tx][ty]);
}

// ---------------------------------------------------------------------------
// fp32 GEMM (layer 1, K=16), bf16 out.
// ---------------------------------------------------------------------------
__global__ __launch_bounds__(256) void gemm_f32_bf16(const float* __restrict__ A,
                                                     const float* __restrict__ B,
                                                     bf16_t* __restrict__ Cm,
                                                     int M, int K, int Nc) {
    __shared__ float As[16][64];
    __shared__ float Bs[16][64];
    int t  = threadIdx.x;
    int tx = t & 15, ty = t >> 4;
    int row0 = blockIdx.y * 64, col0 = blockIdx.x * 64;
    int a_r = t >> 2, a_c = (t & 3) * 4;
    int b_r = t >> 4, b_c = (t & 15) * 4;

    float acc[4][4];
#pragma unroll
    for (int i = 0; i < 4; i++)
#pragma unroll
        for (int j = 0; j < 4; j++) acc[i][j] = 0.f;

    for (int kt = 0; kt < K; kt += 16) {
        float4 av = make_float4(0.f, 0.f, 0.f, 0.f);
        int gr = row0 + a_r;
        if (gr < M) av = *(const float4*)(A + (size_t)gr * K + kt + a_c);
        As[a_c + 0][a_r] = av.x;
        As[a_c + 1][a_r] = av.y;
        As[a_c + 2][a_r] = av.z;
        As[a_c + 3][a_r] = av.w;
        float4 bv = *(const float4*)(B + (size_t)(kt + b_r) * Nc + col0 + b_c);
        *(float4*)&Bs[b_r][b_c] = bv;
        __syncthreads();
#pragma unroll
        for (int k = 0; k < 16; k++) {
            float4 a4 = *(const float4*)&As[k][ty * 4];
            float4 b4 = *(const float4*)&Bs[k][tx * 4];
            float aa[4] = {a4.x, a4.y, a4.z, a4.w};
            float bb[4] = {b4.x, b4.y, b4.z, b4.w};
#pragma unroll
            for (int i = 0; i < 4; i++)
#pragma unroll
                for (int j = 0; j < 4; j++) acc[i][j] += aa[i] * bb[j];
        }
        __syncthreads();
    }
#pragma unroll
    for (int i = 0; i < 4; i++) {
        int gr = row0 + ty * 4 + i;
        if (gr < M) {
            ushort4 v;
            v.x = f2bf(acc[i][0]); v.y = f2bf(acc[i][1]);
            v.z = f2bf(acc[i][2]); v.w = f2bf(acc[i][3]);
            *(ushort4*)(Cm + (size_t)gr * Nc + col0 + tx * 4) = v;
        }
    }
}

// ---------------------------------------------------------------------------
// MFMA bf16 GEMM (layers 2/3): C = A[M,K] @ Bt[Nc,K]^T, frags from global.
// ---------------------------------------------------------------------------
__global__ __launch_bounds__(256) void gemm_mfma(const bf16_t* __restrict__ A,
                                                 const bf16_t* __restrict__ Bt,
                                                 bf16_t* __restrict__ Cm,
                                                 int M, int K, int Nc) {
    int wave = threadIdx.x >> 6, lane = threadIdx.x & 63;
    int quad = lane >> 4, l16 = lane & 15;
    int m0 = blockIdx.y * 128 + wave * 32;
    int n0 = blockIdx.x * 64;

    f32x4 acc[2][4];
    f32x4 z = {0.f, 0.f, 0.f, 0.f};
#pragma unroll
    for (int i = 0; i < 2; i++)
#pragma unroll
        for (int j = 0; j < 4; j++) acc[i][j] = z;

    int r0 = m0 + l16;       if (r0 >= M) r0 = M - 1;
    int r1 = m0 + 16 + l16;  if (r1 >= M) r1 = M - 1;
    const bf16_t* Ap0 = A + (size_t)r0 * K + quad * 8;
    const bf16_t* Ap1 = A + (size_t)r1 * K + quad * 8;
    const bf16_t* Bp0 = Bt + (size_t)(n0 + 0  + l16) * K + quad * 8;
    const bf16_t* Bp1 = Bt + (size_t)(n0 + 16 + l16) * K + quad * 8;
    const bf16_t* Bp2 = Bt + (size_t)(n0 + 32 + l16) * K + quad * 8;
    const bf16_t* Bp3 = Bt + (size_t)(n0 + 48 + l16) * K + quad * 8;

    for (int kt = 0; kt < K; kt += 32) {
        bf16x8 a0 = *(const bf16x8*)(Ap0 + kt);
        bf16x8 a1 = *(const bf16x8*)(Ap1 + kt);
        bf16x8 b0 = *(const bf16x8*)(Bp0 + kt);
        bf16x8 b1 = *(const bf16x8*)(Bp1 + kt);
        bf16x8 b2 = *(const bf16x8*)(Bp2 + kt);
        bf16x8 b3 = *(const bf16x8*)(Bp3 + kt);
        acc[0][0] = __builtin_amdgcn_mfma_f32_16x16x32_bf16(a0, b0, acc[0][0], 0, 0, 0);
        acc[1][0] = __builtin_amdgcn_mfma_f32_16x16x32_bf16(a1, b0, acc[1][0], 0, 0, 0);
        acc[0][1] = __builtin_amdgcn_mfma_f32_16x16x32_bf16(a0, b1, acc[0][1], 0, 0, 0);
        acc[1][1] = __builtin_amdgcn_mfma_f32_16x16x32_bf16(a1, b1, acc[1][1], 0, 0, 0);
        acc[0][2] = __builtin_amdgcn_mfma_f32_16x16x32_bf16(a0, b2, acc[0][2], 0, 0, 0);
        acc[1][2] = __builtin_amdgcn_mfma_f32_16x16x32_bf16(a1, b2, acc[1][2], 0, 0, 0);
        acc[0][3] = __builtin_amdgcn_mfma_f32_16x16x32_bf16(a0, b3, acc[0][3], 0, 0, 0);
        acc[1][3] = __builtin_amdgcn_mfma_f32_16x16x32_bf16(a1, b3, acc[1][3], 0, 0, 0);
    }
#pragma unroll
    for (int i = 0; i < 2; i++)
#pragma unroll
        for (int j = 0; j < 4; j++)
#pragma unroll
            for (int r = 0; r < 4; r++) {
                int gr = m0 + i * 16 + quad * 4 + r;
                if (gr < M) Cm[(size_t)gr * Nc + n0 + j * 16 + l16] = f2bf(acc[i][j][r]);
            }
}

// ---------------------------------------------------------------------------
// Per-(node,head) attention scores from bf16 h.
// ---------------------------------------------------------------------------
template <int H, int C>
__global__ void gat_scores(const bf16_t* __restrict__ hbuf, const float* __restrict__ a_s,
                           const float* __restrict__ a_d, float* __restrict__ al,
                           float* __restrict__ ar, int n) {
    int i = blockIdx.x * blockDim.x + threadIdx.x;
    if (i >= n * H) return;
    int node = i / H, h = i - node * H;
    const bf16_t* hr = hbuf + (size_t)node * (H * C) + h * C;
    const float* as_ = a_s + h * C;
    const float* ad_ = a_d + h * C;
    float sa = 0.f, sd = 0.f;
#pragma unroll
    for (int c = 0; c < C; c += 4) {
        ushort4 u = *(const ushort4*)(hr + c);
        float v0 = bf2f(u.x), v1 = bf2f(u.y), v2 = bf2f(u.z), v3 = bf2f(u.w);
        sa += v0 * as_[c] + v1 * as_[c + 1] + v2 * as_[c + 2] + v3 * as_[c + 3];
        sd += v0 * ad_[c] + v1 * ad_[c + 1] + v2 * ad_[c + 2] + v3 * ad_[c + 3];
    }
    al[i] = sa;
    ar[i] = sd;
}

// ---------------------------------------------------------------------------
// alpha v2: wave per node, ALL heads; row-contiguous al reads; register p
// for deg<=128, guarded tail beyond; per-head shuffle reduce; planar stores.
// ---------------------------------------------------------------------------
template <int H>
__global__ __launch_bounds__(256) void alpha_node(const float* __restrict__ al,
                                                  const float* __restrict__ ar,
                                                  const int* __restrict__ rowptr,
                                                  const int* __restrict__ esrc,
                                                  float* __restrict__ alpha,
                                                  int n, int Etot) {
    int node = (blockIdx.x * blockDim.x + threadIdx.x) >> 6;
    if (node >= n) return;
    int lane = threadIdx.x & 63;

    float arv[H];
#pragma unroll
    for (int h4 = 0; h4 < H; h4 += 4) {
        float4 t = *(const float4*)(ar + (size_t)node * H + h4);
        arv[h4] = t.x; arv[h4 + 1] = t.y; arv[h4 + 2] = t.z; arv[h4 + 3] = t.w;
    }
    int beg = rowptr[node], end = rowptr[node + 1];
    float p0[H], p1[H], s[H];
#pragma unroll
    for (int h = 0; h < H; h++) { p0[h] = 0.f; p1[h] = 0.f; s[h] = 0.f; }

    int j0 = beg + lane;
    if (j0 < end) {
        const float* alr = al + (size_t)esrc[j0] * H;
#pragma unroll
        for (int h4 = 0; h4 < H; h4 += 4) {
            float4 t = *(const float4*)(alr + h4);
            float e;
            e = t.x + arv[h4];     e = fmaxf(e, 0.2f * e); p0[h4]     = __expf(fminf(e, 60.f));
            e = t.y + arv[h4 + 1]; e = fmaxf(e, 0.2f * e); p0[h4 + 1] = __expf(fminf(e, 60.f));
            e = t.z + arv[h4 + 2]; e = fmaxf(e, 0.2f * e); p0[h4 + 2] = __expf(fminf(e, 60.f));
            e = t.w + arv[h4 + 3]; e = fmaxf(e, 0.2f * e); p0[h4 + 3] = __expf(fminf(e, 60.f));
        }
#pragma unroll
        for (int h = 0; h < H; h++) s[h] += p0[h];
    }
    int j1 = j0 + 64;
    if (j1 < end) {
        const float* alr = al + (size_t)esrc[j1] * H;
#pragma unroll
        for (int h4 = 0; h4 < H; h4 += 4) {
            float4 t = *(const float4*)(alr + h4);
            float e;
            e = t.x + arv[h4];     e = fmaxf(e, 0.2f * e); p1[h4]     = __expf(fminf(e, 60.f));
            e = t.y + arv[h4 + 1]; e = fmaxf(e, 0.2f * e); p1[h4 + 1] = __expf(fminf(e, 60.f));
            e = t.z + arv[h4 + 2]; e = fmaxf(e, 0.2f * e); p1[h4 + 2] = __expf(fminf(e, 60.f));
            e = t.w + arv[h4 + 3]; e = fmaxf(e, 0.2f * e); p1[h4 + 3] = __expf(fminf(e, 60.f));
        }
#pragma unroll
        for (int h = 0; h < H; h++) s[h] += p1[h];
    }
    for (int j = j0 + 128; j < end; j += 64) {
        const float* alr = al + (size_t)esrc[j] * H;
#pragma unroll
        for (int h = 0; h < H; h++) {
            float e = alr[h] + arv[h];
            e = fmaxf(e, 0.2f * e);
            float p = __expf(fminf(e, 60.f));
            alpha[(size_t)h * Etot + j] = p;
            s[h] += p;
        }
    }
#pragma unroll
    for (int h = 0; h < H; h++) {
        float v = s[h];
#pragma unroll
        for (int off = 32; off > 0; off >>= 1) v += __shfl_xor(v, off, 64);
        s[h] = 1.f / v;
    }
    if (j0 < end) {
#pragma unroll
        for (int h = 0; h < H; h++) alpha[(size_t)h * Etot + j0] = p0[h] * s[h];
    }
    if (j1 < end) {
#pragma unroll
        for (int h = 0; h < H; h++) alpha[(size_t)h * Etot + j1] = p1[h] * s[h];
    }
    for (int j = j0 + 128; j < end; j += 64) {
#pragma unroll
        for (int h = 0; h < H; h++) alpha[(size_t)h * Etot + j] *= s[h];
    }
}

// ---------------------------------------------------------------------------
// agg v6: wave per (node, 128-ch group); lane = (sub 0..3, slot 0..15),
// 16 B/lane gathers. Edge indices for deg<=128 preloaded into 2 registers
// (coalesced) and distributed by ds_bpermute — no L2 latency in the address
// chain. 8-edge packs never straddle the 64-edge register boundary, so the
// e0/e1 select is loop-uniform. Depth-2 gather pipeline; direct-load tail.
// ---------------------------------------------------------------------------
template <int HC_, int C>
__global__ __launch_bounds__(256) void gat_agg(
    const bf16_t* __restrict__ hbuf, const float* __restrict__ alpha,
    const int* __restrict__ rowptr, const int* __restrict__ esrc,
    const float* __restrict__ bias, bf16_t* __restrict__ outb,
    int n, int Etot, int nodeblocks) {
    int group = blockIdx.x / nodeblocks;
    int nb    = blockIdx.x - group * nodeblocks;
    int node  = nb * 4 + (threadIdx.x >> 6);
    if (node >= n) return;
    int lane = threadIdx.x & 63;
    int sub  = lane >> 4;          // edge slot 0..3
    int cl   = lane & 15;          // channel slot 0..15
    int gc   = group * 128 + cl * 8;
    int head = gc / C;
    const bf16_t* hb = hbuf + gc;
    const float*  ap = alpha + (size_t)head * Etot;

    float acc[8];
#pragma unroll
    for (int i = 0; i < 8; i++) acc[i] = 0.f;

    int beg = rowptr[node], end = rowptr[node + 1];
    int deg = end - beg;

    // preload first min(deg,128) edge indices, coalesced
    int e0 = 0, e1 = 0;
    {
        int i0 = beg + lane;
        if (i0 < end) e0 = esrc[i0];
        int i1 = beg + 64 + lane;
        if (i1 < end) e1 = esrc[i1];
    }
    int npre  = deg < 128 ? deg : 128;
    int nfull = npre >> 3;         // 8-edge packs from preloaded region

    if (nfull > 0) {
        int esel0 = e0;            // pack 0 entirely in [0,64)
        int s0 = __shfl(esel0, sub, 64);
        int s1 = __shfl(esel0, sub + 4, 64);
        float a0 = ap[beg + sub], a1 = ap[beg + sub + 4];
        bf16x8 u0 = *(const bf16x8*)(hb + (size_t)s0 * HC_);
        bf16x8 u1 = *(const bf16x8*)(hb + (size_t)s1 * HC_);
        for (int it = 1; it < nfull; ++it) {
            int kb = it * 8;
            int esel = (kb < 64) ? e0 : e1;      // loop-uniform select
            int t0 = __shfl(esel, (kb + sub) & 63, 64);
            int t1 = __shfl(esel, (kb + sub + 4) & 63, 64);
            float b0v = ap[beg + kb + sub], b1v = ap[beg + kb + sub + 4];
            bf16x8 v0 = *(const bf16x8*)(hb + (size_t)t0 * HC_);
            bf16x8 v1 = *(const bf16x8*)(hb + (size_t)t1 * HC_);
            const unsigned int* d0 = (const unsigned int*)&u0;
            const unsigned int* d1 = (const unsigned int*)&u1;
#pragma unroll
            for (int i = 0; i < 4; i++) {
                acc[2 * i]     += a0 * u2f(d0[i] << 16);
                acc[2 * i + 1] += a0 * u2f(d0[i] & 0xffff0000u);
                acc[2 * i]     += a1 * u2f(d1[i] << 16);
                acc[2 * i + 1] += a1 * u2f(d1[i] & 0xffff0000u);
            }
            u0 = v0; u1 = v1; a0 = b0v; a1 = b1v;
        }
        const unsigned int* d0 = (const unsigned int*)&u0;
        const unsigned int* d1 = (const unsigned int*)&u1;
#pragma unroll
        for (int i = 0; i < 4; i++) {
            acc[2 * i]     += a0 * u2f(d0[i] << 16);
            acc[2 * i + 1] += a0 * u2f(d0[i] & 0xffff0000u);
            acc[2 * i]     += a1 * u2f(d1[i] << 16);
            acc[2 * i + 1] += a1 * u2f(d1[i] & 0xffff0000u);
        }
    }
    // tail: remaining edges (pack remainder, plus deg>128 overflow), stride 4
    for (int j = beg + (nfull << 3) + sub; j < end; j += 4) {
        int s0 = esrc[j];
        float a0 = ap[j];
        bf16x8 u0 = *(const bf16x8*)(hb + (size_t)s0 * HC_);
        const unsigned int* d0 = (const unsigned int*)&u0;
#pragma unroll
        for (int i = 0; i < 4; i++) {
            acc[2 * i]     += a0 * u2f(d0[i] << 16);
            acc[2 * i + 1] += a0 * u2f(d0[i] & 0xffff0000u);
        }
    }
#pragma unroll
    for (int i = 0; i < 8; i++) {
        acc[i] += __shfl_xor(acc[i], 16, 64);
        acc[i] += __shfl_xor(acc[i], 32, 64);
    }
    if (sub == 0) {
        float4 b0 = *(const float4*)(bias + gc);
        float4 b1 = *(const float4*)(bias + gc + 4);
        float bb[8] = {b0.x, b0.y, b0.z, b0.w, b1.x, b1.y, b1.z, b1.w};
        bf16x8 outv;
        unsigned short* ov = (unsigned short*)&outv;
#pragma unroll
        for (int i = 0; i < 8; i++) ov[i] = f2bf(fmaxf(acc[i] + bb[i], 0.f));
        *(bf16x8*)(outb + (size_t)node * HC_ + gc) = outv;
    }
}

// ---------------------------------------------------------------------------
// Fused head: out1 = sigmoid(concat(x1,x2,x3).Wf + bf); then MLP -> out2.
// ---------------------------------------------------------------------------
__global__ __launch_bounds__(256) void head_fused(
    const float* __restrict__ x, const bf16_t* __restrict__ x1b,
    const bf16_t* __restrict__ x2b, const bf16_t* __restrict__ x3b,
    const float* __restrict__ Wf, const float* __restrict__ bfc,
    const float* __restrict__ M1w, const float* __restrict__ M1b,
    const float* __restrict__ M2w, const float* __restrict__ M2b,
    const float* __restrict__ M3w, const float* __restrict__ M3b,
    float* __restrict__ out1, float* __restrict__ out2, int n) {
    __shared__ float h1s[4][128];
    int w    = threadIdx.x >> 6;
    int lane = threadIdx.x & 63;
    int node = blockIdx.x * 4 + w;
    bool valid = node < n;
    int nd = valid ? node : 0;

    float s = 0.f;
    {
        ushort4 u = *(const ushort4*)(x1b + (size_t)nd * 256 + lane * 4);
        const float* wv = Wf + lane * 4;
        s += bf2f(u.x) * wv[0] + bf2f(u.y) * wv[1] + bf2f(u.z) * wv[2] + bf2f(u.w) * wv[3];
    }
    {
        ushort4 u = *(const ushort4*)(x2b + (size_t)nd * 256 + lane * 4);
        const float* wv = Wf + 256 + lane * 4;
        s += bf2f(u.x) * wv[0] + bf2f(u.y) * wv[1] + bf2f(u.z) * wv[2] + bf2f(u.w) * wv[3];
    }
#pragma unroll
    for (int i = 0; i < 3; i++) {
        int k = i * 256 + lane * 4;
        ushort4 u = *(const ushort4*)(x3b + (size_t)nd * 768 + k);
        const float* wv = Wf + 512 + k;
        s += bf2f(u.x) * wv[0] + bf2f(u.y) * wv[1] + bf2f(u.z) * wv[2] + bf2f(u.w) * wv[3];
    }
#pragma unroll
    for (int off = 32; off > 0; off >>= 1) s += __shfl_xor(s, off, 64);
    float so = 1.f / (1.f + __expf(-(s + bfc[0])));
    if (lane == 0 && valid) out1[node] = so;

    float xm[17];
#pragma unroll
    for (int k = 0; k < 16; k++) xm[k] = x[nd * 16 + k];
    xm[16] = so;

    float a0 = M1b[lane], a1 = M1b[lane + 64];
#pragma unroll
    for (int k = 0; k < 17; k++) {
        a0 += xm[k] * M1w[k * 128 + lane];
        a1 += xm[k] * M1w[k * 128 + lane + 64];
    }
    h1s[w][lane]      = fmaxf(a0, 0.f);
    h1s[w][lane + 64] = fmaxf(a1, 0.f);
    __syncthreads();

    float b0 = M2b[lane];
#pragma unroll 16
    for (int k = 0; k < 128; k++) b0 += h1s[w][k] * M2w[k * 64 + lane];
    b0 = fmaxf(b0, 0.f);

    float p = b0 * M3w[lane];
#pragma unroll
    for (int off = 32; off > 0; off >>= 1) p += __shfl_xor(p, off, 64);
    if (lane == 0 && valid) out2[node] = 1.f / (1.f + __expf(-(p + M3b[0])));
}

// ---------------------------------------------------------------------------
extern "C" void kernel_launch(void* const* d_in, const int* in_sizes, int n_in,
                              void* d_out, int out_size, void* d_ws, size_t ws_size,
                              hipStream_t stream) {
    const float* x   = (const float*)d_in[0];
    const int*   ei  = (const int*)d_in[1];
    const float* W1  = (const float*)d_in[3];
    const float* a1s = (const float*)d_in[4];
    const float* a1d = (const float*)d_in[5];
    const float* b1  = (const float*)d_in[6];
    const float* W2  = (const float*)d_in[7];
    const float* a2s = (const float*)d_in[8];
    const float* a2d = (const float*)d_in[9];
    const float* b2  = (const float*)d_in[10];
    const float* W3  = (const float*)d_in[11];
    const float* a3s = (const float*)d_in[12];
    const float* a3d = (const float*)d_in[13];
    const float* b3  = (const float*)d_in[14];
    const float* Wf  = (const float*)d_in[15];
    const float* bf  = (const float*)d_in[16];
    const float* M1w = (const float*)d_in[17];
    const float* M1b = (const float*)d_in[18];
    const float* M2w = (const float*)d_in[19];
    const float* M2b = (const float*)d_in[20];
    const float* M3w = (const float*)d_in[21];
    const float* M3b = (const float*)d_in[22];

    const int N = in_sizes[0] / 16;        // 10000
    const int E = in_sizes[1] / 2;         // 320000
    const int Etot = E + N;

    char* base = (char*)d_ws;
    size_t off = 0;
    auto carve = [&](size_t bytes) {
        char* p = base + off;
        off = (off + bytes + 255) & ~(size_t)255;
        return p;
    };
    bf16_t* hbuf   = (bf16_t*)carve((size_t)N * 768 * 2);
    bf16_t* x1b    = (bf16_t*)carve((size_t)N * 256 * 2);
    bf16_t* x2b    = (bf16_t*)carve((size_t)N * 256 * 2);
    bf16_t* x3b    = (bf16_t*)carve((size_t)N * 768 * 2);
    bf16_t* Wt2    = (bf16_t*)carve((size_t)256 * 256 * 2);
    bf16_t* Wt3    = (bf16_t*)carve((size_t)256 * 768 * 2);
    float*  al     = (float*)carve((size_t)N * 12 * 4);
    float*  ar     = (float*)carve((size_t)N * 12 * 4);
    float*  alphab = (float*)carve((size_t)Etot * 12 * 4);
    int*    rowptr = (int*)carve((size_t)(N + 1) * 4);
    int*    cnt2   = (int*)carve((size_t)(2 * N) * 4);   // counts | cursor contiguous
    int*    counts = cnt2;
    int*    cursor = cnt2 + N;
    int*    esrc   = (int*)carve((size_t)Etot * 4);
    (void)ws_size;

    float* out1 = (float*)d_out;
    float* out2 = (float*)d_out + N;

    const int TB = 256;
    int eb = (Etot + TB - 1) / TB;
    int nodeblocks = (N + 3) / 4;          // 4 node-waves per block

    // --- CSR by dst + weight prep ---
    zero_i32<<<(2 * N + TB - 1) / TB, TB, 0, stream>>>(cnt2, 2 * N);
    count_edges<<<eb, TB, 0, stream>>>(ei, E, N, counts);
    scan_rowptr<<<1, 1024, 0, stream>>>(counts, rowptr, N);
    fill_edges<<<eb, TB, 0, stream>>>(ei, E, N, rowptr, cursor, esrc);
    transpose_cast2<<<dim3(16, 64), TB, 0, stream>>>(W2, Wt2, W3, Wt3);

    // --- layer 1: 16 -> 8x32 ---
    gemm_f32_bf16<<<dim3(4, (N + 63) / 64), TB, 0, stream>>>(x, W1, hbuf, N, 16, 256);
    gat_scores<8, 32><<<(N * 8 + TB - 1) / TB, TB, 0, stream>>>(hbuf, a1s, a1d, al, ar, N);
    alpha_node<8><<<nodeblocks, TB, 0, stream>>>(al, ar, rowptr, esrc, alphab, N, Etot);
    gat_agg<256, 32><<<2 * nodeblocks, TB, 0, stream>>>(hbuf, alphab, rowptr, esrc, b1, x1b, N, Etot, nodeblocks);

    // --- layer 2: 256 -> 8x32 (MFMA) ---
    gemm_mfma<<<dim3(4, (N + 127) / 128), TB, 0, stream>>>(x1b, Wt2, hbuf, N, 256, 256);
    gat_scores<8, 32><<<(N * 8 + TB - 1) / TB, TB, 0, stream>>>(hbuf, a2s, a2d, al, ar, N);
    alpha_node<8><<<nodeblocks, TB, 0, stream>>>(al, ar, rowptr, esrc, alphab, N, Etot);
    gat_agg<256, 32><<<2 * nodeblocks, TB, 0, stream>>>(hbuf, alphab, rowptr, esrc, b2, x2b, N, Etot, nodeblocks);

    // --- layer 3: 256 -> 12x64 (MFMA) ---
    gemm_mfma<<<dim3(12, (N + 127) / 128), TB, 0, stream>>>(x2b, Wt3, hbuf, N, 256, 768);
    gat_scores<12, 64><<<(N * 12 + TB - 1) / TB, TB, 0, stream>>>(hbuf, a3s, a3d, al, ar, N);
    alpha_node<12><<<nodeblocks, TB, 0, stream>>>(al, ar, rowptr, esrc, alphab, N, Etot);
    gat_agg<768, 64><<<6 * nodeblocks, TB, 0, stream>>>(hbuf, alphab, rowptr, esrc, b3, x3b, N, Etot, nodeblocks);

    // --- fused final linear + MLP ---
    head_fused<<<nodeblocks, TB, 0, stream>>>(x, x1b, x2b, x3b, Wf, bf,
                                              M1w, M1b, M2w, M2b, M3w, M3b, out1, out2, N);
}